// Round 8
// baseline (704.464 us; speedup 1.0000x reference)
//
#include <hip/hip_runtime.h>
#include <hip/hip_bf16.h>
#include <math.h>

// Perceiver: B=4,C=3,N=4096,E=256,H=8,FFE=1024,L=512,D=4,NCLS=1000,HS=2048
// bf16 MFMA everywhere GEMM-shaped; fp32 accum; fp32 LN/residual spine.

typedef __attribute__((ext_vector_type(8))) short s8v;    // 8 bf16 = 4 VGPR
typedef __attribute__((ext_vector_type(4))) float f32x4;  // 16x16 MFMA accum
typedef __attribute__((ext_vector_type(16))) float f32x16;// 32x32 MFMA accum
typedef __attribute__((ext_vector_type(4))) unsigned u32x4;

__device__ __forceinline__ short f2b(float f) {
  union { float f; unsigned u; } a; a.f = f;
  unsigned r = a.u + 0x7fff + ((a.u >> 16) & 1);
  return (short)(r >> 16);
}
__device__ __forceinline__ float b2f(short s) {
  union { unsigned u; float f; } a; a.u = ((unsigned)(unsigned short)s) << 16;
  return a.f;
}
__device__ __forceinline__ unsigned cvtpk(float lo, float hi) {
  unsigned r;
  asm("v_cvt_pk_bf16_f32 %0, %1, %2" : "=v"(r) : "v"(lo), "v"(hi));
  return r;
}

// async global->LDS, 16B per lane; LDS dest = uniform base + lane*16
__device__ __forceinline__ void gl16(const void* gp, void* lp) {
  __builtin_amdgcn_global_load_lds(
      (const __attribute__((address_space(1))) unsigned int*)gp,
      (__attribute__((address_space(3))) unsigned int*)lp, 16, 0, 0);
}

// ------- tokens(bf16) = conv1x1(x)+bias+pos, writes tok AND tokT ---------
__global__ __launch_bounds__(256) void k_tokens2(
    const float* __restrict__ x, const float* __restrict__ cw,
    const float* __restrict__ cb, const float* __restrict__ pe,
    short* __restrict__ tok, short* __restrict__ tokT)
{
  int b = blockIdx.y, n0 = blockIdx.x * 32;
  int e = threadIdx.x;
  float c0 = cw[e * 3], c1 = cw[e * 3 + 1], c2 = cw[e * 3 + 2], cbv = cb[e];
  const float* xb = x + b * 12288 + n0;
  short acc[32];
#pragma unroll
  for (int i = 0; i < 32; ++i) {
    int n = n0 + i;
    float s = cbv + pe[n * 256 + e] + xb[i] * c0 + xb[4096 + i] * c1 + xb[8192 + i] * c2;
    short v = f2b(s);
    tok[((long)b * 4096 + n) * 256 + e] = v;
    acc[i] = v;
  }
  short* tr = tokT + ((long)b * 256 + e) * 4096 + n0;
#pragma unroll
  for (int i = 0; i < 4; ++i)
    *reinterpret_cast<s8v*>(tr + i * 8) = *reinterpret_cast<s8v*>(acc + i * 8);
}

// ---------------- batched weight prep: transposes + flat converts --------
struct TrJob {
  const float* src; short* dst;
  int R, C; long sIn, sOut;
  int mode, tilesPerZ, z, tileBase;
  float scale;
};
struct TrJobs { TrJob j[11]; };

__global__ __launch_bounds__(256) void k_trbatch(TrJobs jb, int njobs)
{
  __shared__ float t[32][33];
  int tb = blockIdx.x, ji = 0;
#pragma unroll
  for (int k = 1; k < 11; ++k)
    if (k < njobs && tb >= jb.j[k].tileBase) ji = k;
  TrJob J = jb.j[ji];
  int local = tb - J.tileBase;
  if (J.mode == 1) {          // flat fp32 -> bf16 (*scale)
    long o = (long)local * 8192 + threadIdx.x;
#pragma unroll
    for (int k = 0; k < 32; ++k)
      J.dst[o + k * 256] = f2b(J.src[o + k * 256] * J.scale);
    return;
  }
  int zi = local / J.tilesPerZ, ti = local - zi * J.tilesPerZ;
  int ntx = J.C >> 5;
  int tx = ti % ntx, ty = ti / ntx;
  const float* ib = J.src + (long)zi * J.sIn;
  short* ob = J.dst + (long)zi * J.sOut;
  int c0 = tx * 32, r0 = ty * 32;
  int lx = threadIdx.x & 31, ly = threadIdx.x >> 5;
#pragma unroll
  for (int i = 0; i < 4; ++i)
    t[ly * 4 + i][lx] = ib[(long)(r0 + ly * 4 + i) * J.C + c0 + lx];
  __syncthreads();
#pragma unroll
  for (int i = 0; i < 4; ++i)
    ob[(long)(c0 + ly * 4 + i) * J.R + r0 + lx] = f2b(t[lx][ly * 4 + i] * J.scale);
}

// ------------- multi-job bf16 MFMA BT-GEMM: C = A(MxK) @ Bt(NxK)^T -------
// 128x128 tile, BK=32, 256 thr, prefetch pipeline. K % 64 == 0.
// epi: 0 = bf16 out, 1 = bias+exact-gelu bf16 out, 2 = fp32 out (partials).
struct GJob {
  const short* A; const short* Bt; void* C; const float* bias;
  int K, lda, ldb, ldc;
  long sA, sB, sC;
  int zdA, zmA, zdB, zmB;
  int epi, gx, gy, blockBase;
};
struct GJobs { GJob j[4]; };

__global__ __launch_bounds__(256) void k_gemm_m(GJobs jb, int njobs)
{
  __shared__ char As[8192];
  __shared__ char Bs[8192];
  int bid = blockIdx.x, ji = 0;
#pragma unroll
  for (int k = 1; k < 4; ++k)
    if (k < njobs && bid >= jb.j[k].blockBase) ji = k;
  GJob J = jb.j[ji];
  int local = bid - J.blockBase;
  int bx = local % J.gx, rest = local / J.gx;
  int by = rest % J.gy, bz = rest / J.gy;
  const short* Ab = J.A + ((long)((bz / J.zdA) % J.zmA)) * J.sA;
  const short* Bb = J.Bt + ((long)((bz / J.zdB) % J.zmB)) * J.sB;
  int lda = J.lda, ldb = J.ldb;
  int t = threadIdx.x;
  int lane = t & 63, w = t >> 6;
  int wr = w >> 1, wc = w & 1;
  int g = lane >> 4, l15 = lane & 15;
  long row0 = (long)by * 128, col0 = (long)bx * 128;
  const f32x4 zz = {0.f, 0.f, 0.f, 0.f};
  f32x4 acc[4][4];
#pragma unroll
  for (int m = 0; m < 4; ++m)
#pragma unroll
    for (int n = 0; n < 4; ++n) acc[m][n] = zz;

  auto mload = [&](s8v* aa, s8v* bb, int kk) {
#pragma unroll
    for (int i = 0; i < 2; ++i) {
      int r = i * 64 + (t >> 2), c = t & 3;
      aa[i] = *(const s8v*)&Ab[(row0 + r) * (long)lda + kk + c * 8];
      bb[i] = *(const s8v*)&Bb[(col0 + r) * (long)ldb + kk + c * 8];
    }
  };
  auto mstore = [&](s8v* aa, s8v* bb) {
#pragma unroll
    for (int i = 0; i < 2; ++i) {
      int r = i * 64 + (t >> 2), c = t & 3;
      int off = (r * 64 + c * 16) ^ ((r & 7) << 4);
      *(s8v*)&As[off] = aa[i];
      *(s8v*)&Bs[off] = bb[i];
    }
  };
  auto mcomp = [&]() {
    s8v af[4], bfr[4];
#pragma unroll
    for (int m = 0; m < 4; ++m) {
      int r = wr * 64 + m * 16 + l15;
      af[m] = *(const s8v*)&As[(r * 64 + g * 16) ^ ((r & 7) << 4)];
    }
#pragma unroll
    for (int n = 0; n < 4; ++n) {
      int r = wc * 64 + n * 16 + l15;
      bfr[n] = *(const s8v*)&Bs[(r * 64 + g * 16) ^ ((r & 7) << 4)];
    }
#pragma unroll
    for (int m = 0; m < 4; ++m)
#pragma unroll
      for (int n = 0; n < 4; ++n)
        acc[m][n] = __builtin_amdgcn_mfma_f32_16x16x32_bf16(af[m], bfr[n], acc[m][n], 0, 0, 0);
  };

  s8v a0[2], b0[2], a1[2], b1[2];
  mload(a0, b0, 0);
  for (int k0 = 0; k0 < J.K; k0 += 64) {
    __syncthreads(); mstore(a0, b0); __syncthreads();
    mload(a1, b1, k0 + 32);
    mcomp();
    __syncthreads(); mstore(a1, b1); __syncthreads();
    if (k0 + 64 < J.K) mload(a0, b0, k0 + 64);
    mcomp();
  }

  long zo = (long)bz * J.sC;
#pragma unroll
  for (int m = 0; m < 4; ++m)
#pragma unroll
    for (int n = 0; n < 4; ++n)
#pragma unroll
      for (int r = 0; r < 4; ++r) {
        long rr = row0 + wr * 64 + m * 16 + g * 4 + r;
        long cc = col0 + wc * 64 + n * 16 + l15;
        float v = acc[m][n][r];
        if (J.epi == 1) {
          v += J.bias[cc];
          v = 0.5f * v * (1.f + erff(v * 0.70710678118654752f));
        }
        if (J.epi == 2)
          ((float*)J.C)[zo + rr * J.ldc + cc] = v;
        else
          ((short*)J.C)[zo + rr * J.ldc + cc] = f2b(v);
      }
}

// ---------------- MFMA flash attention v7 (head dim 256, 32x32 MFMA) -----
// 8 waves x 32 q-rows, KVBLK=64, swapped QK^T, in-register softmax,
// P->PV frags via cvt_pk + cross-half shfl. kv-split x4 to partials.
// TRUE counted-vmcnt pipeline: RAW s_barrier (no compiler vmcnt(0) drain) +
// explicit counted waits -> prefetched loads stay in flight across barriers.
__global__ __launch_bounds__(512, 2) void k_mflash7(
    const short* __restrict__ Qp, const short* __restrict__ Kp,
    const short* __restrict__ Vtp, short* __restrict__ Opart,
    float* __restrict__ MLp,
    int nk, int ldq, int ldk, int ldvt,
    long qh, long qb, long kh, long kb, long vh, long vb)
{
  __shared__ char pool[131072];  // 2 x (K 32KB + V 32KB)
  int t = threadIdx.x, lane = t & 63, w = t >> 6;
  int l31 = lane & 31, hi = lane >> 5;
  int h = blockIdx.y, b = blockIdx.z;
  int kv = blockIdx.x & 3, qblk = blockIdx.x >> 2;
  const short* Q  = Qp  + (long)h * qh + (long)b * qb;
  const short* Kg = Kp  + (long)h * kh + (long)b * kb;
  const short* Vg = Vtp + (long)h * vh + (long)b * vb;
  int q0w = qblk * 256 + w * 32;
  int nkq = nk >> 2;
  int NIT = nkq >> 6;           // KVBLK = 64
  long k0 = (long)kv * nkq;

  // Q B-frags: lane = q-col (l31), k = hi*8+j within d-slice s
  s8v qf[16];
  {
    const short* Qrow = Q + (long)(q0w + l31) * ldq + hi * 8;
#pragma unroll
    for (int s = 0; s < 16; ++s) qf[s] = *(const s8v*)(Qrow + s * 16);
  }

  // staging byte-offsets (linear LDS dest + inverse-swizzled source)
  const char* KgB = (const char*)Kg;
  const char* VgB = (const char*)Vg;
  unsigned koff[4], voff[4];
#pragma unroll
  for (int c = 0; c < 4; ++c) {
    int r = 8 * w + 2 * c + hi;                 // K tile row 0..63
    koff[c] = (unsigned)((k0 + r) * (long)ldk * 2) + ((l31 ^ (r & 31)) << 4);
    int rv = 32 * w + 8 * c + (lane >> 3);      // V tile row 0..255
    voff[c] = (unsigned)(((long)rv * ldvt + k0) * 2) + (((lane & 7) ^ (lane >> 3)) << 4);
  }
  const unsigned kStep = (unsigned)(64 * ldk * 2);

  auto stage = [&](int bsel) {   // K loads first, V loads last (vmcnt order)
    char* kd = pool + bsel * 65536 + (w << 12);
    char* vd = kd + 32768;
#pragma unroll
    for (int c = 0; c < 4; ++c) { gl16(KgB + koff[c], kd + c * 1024); koff[c] += kStep; }
#pragma unroll
    for (int c = 0; c < 4; ++c) { gl16(VgB + voff[c], vd + c * 1024); voff[c] += 128; }
  };

  f32x16 accO[8];
#pragma unroll
  for (int n = 0; n < 8; ++n)
#pragma unroll
    for (int i = 0; i < 16; ++i) accO[n][i] = 0.f;
  float mrow = -1e30f, lrow = 0.f;

  stage(0);

  for (int it = 0; it < NIT; ++it) {
    int cur = it & 1;
    // own K loads of cur done (V still in flight); raw barrier: NO full drain
    asm volatile("s_waitcnt vmcnt(4) lgkmcnt(0)" ::: "memory");
    __builtin_amdgcn_s_barrier();
    __builtin_amdgcn_sched_barrier(0);
    if (it + 1 < NIT) stage(cur ^ 1);   // stays in flight through this iter
    const char* kls = pool + cur * 65536;
    const char* vls = kls + 32768;

    // S^T = mfma(K, Q): 2 M-tiles (k) x 16 d-slices; C col = q, row = k
    f32x16 sacc[2];
#pragma unroll
    for (int i = 0; i < 16; ++i) { sacc[0][i] = 0.f; sacc[1][i] = 0.f; }
    __builtin_amdgcn_s_setprio(1);
#pragma unroll
    for (int tt = 0; tt < 2; ++tt) {
      int r = tt * 32 + l31;
#pragma unroll
      for (int s = 0; s < 16; ++s) {
        s8v kf = *(const s8v*)&kls[r * 512 + (((2 * s + hi) ^ l31) << 4)];
        sacc[tt] = __builtin_amdgcn_mfma_f32_32x32x16_bf16(kf, qf[s], sacc[tt], 0, 0, 0);
      }
    }
    __builtin_amdgcn_s_setprio(0);

    // in-register softmax over 64 k (32 local + 32 in partner half)
    float mt = sacc[0][0];
#pragma unroll
    for (int i = 1; i < 16; ++i) mt = fmaxf(mt, sacc[0][i]);
#pragma unroll
    for (int i = 0; i < 16; ++i) mt = fmaxf(mt, sacc[1][i]);
    mt = fmaxf(mt, __shfl_xor(mt, 32));
    if (__any(mt - mrow > 8.f)) {       // defer-max (T13)
      float mn = fmaxf(mrow, mt);
      float al = __expf(mrow - mn);
      mrow = mn; lrow *= al;
#pragma unroll
      for (int r = 0; r < 16; ++r) {
        float alr = __shfl(al, (r & 3) + 8 * (r >> 2) + 4 * hi);
#pragma unroll
        for (int n = 0; n < 8; ++n) accO[n][r] *= alr;
      }
    }
    float ls = 0.f;
#pragma unroll
    for (int tt = 0; tt < 2; ++tt)
#pragma unroll
      for (int i = 0; i < 16; ++i) {
        float p = __expf(sacc[tt][i] - mrow);
        sacc[tt][i] = p; ls += p;
      }
    ls += __shfl_xor(ls, 32);
    lrow += ls;

    // PV A-frags via cvt_pk + cross-half exchange
    s8v pa[4];
#pragma unroll
    for (int s = 0; s < 4; ++s) {
      int tt = s >> 1, r0 = (s & 1) * 8;
      unsigned w0 = cvtpk(sacc[tt][r0 + 0], sacc[tt][r0 + 1]);
      unsigned w1 = cvtpk(sacc[tt][r0 + 2], sacc[tt][r0 + 3]);
      unsigned w2 = cvtpk(sacc[tt][r0 + 4], sacc[tt][r0 + 5]);
      unsigned w3 = cvtpk(sacc[tt][r0 + 6], sacc[tt][r0 + 7]);
      unsigned x0 = (unsigned)__shfl_xor((int)w0, 32);
      unsigned x1 = (unsigned)__shfl_xor((int)w1, 32);
      unsigned x2 = (unsigned)__shfl_xor((int)w2, 32);
      unsigned x3 = (unsigned)__shfl_xor((int)w3, 32);
      u32x4 pw;
      pw.x = hi ? x2 : w0;
      pw.y = hi ? x3 : w1;
      pw.z = hi ? w2 : x0;
      pw.w = hi ? w3 : x1;
      pa[s] = *(s8v*)&pw;
    }

    // own V loads of cur done; next tile's 8 loads stay in flight
    if (it + 1 < NIT) { asm volatile("s_waitcnt vmcnt(8) lgkmcnt(0)" ::: "memory"); }
    else              { asm volatile("s_waitcnt vmcnt(0) lgkmcnt(0)" ::: "memory"); }
    __builtin_amdgcn_s_barrier();
    __builtin_amdgcn_sched_barrier(0);

    // O += P @ V: 8 d-tiles x 4 k-slices; B = Vt (col = d, k = hi*8+j)
    __builtin_amdgcn_s_setprio(1);
#pragma unroll
    for (int n = 0; n < 8; ++n) {
      int rv = n * 32 + l31;
#pragma unroll
      for (int s2 = 0; s2 < 4; ++s2) {
        s8v vf = *(const s8v*)&vls[rv * 128 + (((2 * s2 + hi) ^ (l31 & 7)) << 4)];
        accO[n] = __builtin_amdgcn_mfma_f32_32x32x16_bf16(pa[s2], vf, accO[n], 0, 0, 0);
      }
    }
    __builtin_amdgcn_s_setprio(0);
  }

  // write partials: O unnormalized bf16, (m,l) fp32
  long prow = (((long)kv * 4 + b) * 8 + h) * 512;
  short* Ob = Opart + prow * 256;
  float* MLb = MLp + prow * 2;
  if (lane < 32) {
    MLb[(q0w + l31) * 2] = mrow;
    MLb[(q0w + l31) * 2 + 1] = lrow;
  }
#pragma unroll
  for (int n = 0; n < 8; ++n)
#pragma unroll
    for (int r = 0; r < 16; ++r) {
      int q = q0w + (r & 3) + 8 * (r >> 2) + 4 * hi;
      Ob[(long)q * 256 + n * 32 + l31] = f2b(accO[n][r]);
    }
}

// ---------------- combine 4 kv partials -> bufO bf16 ----------------
__global__ __launch_bounds__(512) void k_fcomb(
    const short* __restrict__ Op, const float* __restrict__ ML,
    short* __restrict__ O)
{
  int d = threadIdx.x & 255;
  int q = blockIdx.x * 2 + (threadIdx.x >> 8);
  int h = blockIdx.y, b = blockIdx.z;
  const long kvs = 4L * 8 * 512;  // rows per kv slice
  long r0 = ((long)b * 8 + h) * 512 + q;
  float mm[4], ll[4], m = -1e30f;
#pragma unroll
  for (int kv = 0; kv < 4; ++kv) {
    mm[kv] = ML[(kv * kvs + r0) * 2];
    ll[kv] = ML[(kv * kvs + r0) * 2 + 1];
    m = fmaxf(m, mm[kv]);
  }
  float wv[4], lsum = 0.f;
#pragma unroll
  for (int kv = 0; kv < 4; ++kv) { wv[kv] = __expf(mm[kv] - m); lsum += ll[kv] * wv[kv]; }
  float inv = 1.f / lsum, acc = 0.f;
#pragma unroll
  for (int kv = 0; kv < 4; ++kv)
    acc += b2f(Op[(kv * kvs + r0) * 256 + d]) * wv[kv];
  O[(long)b * 1048576 + (long)q * 2048 + h * 256 + d] = f2b(acc * inv);
}

// ---------------- z = LN(sum(Ypart) + bias + res) ----------------
__global__ __launch_bounds__(256) void k_bias_res_ln(
    const float* __restrict__ Yp, int nPart, long pStride,
    const float* __restrict__ bias,
    const float* __restrict__ res, int resMod,
    const float* __restrict__ g, const float* __restrict__ bta,
    float* __restrict__ out, short* __restrict__ out_bf)
{
  __shared__ float red[4];
  int row = blockIdx.x, e = threadIdx.x;
  float v = bias[e] + res[(long)(row % resMod) * 256 + e];
  for (int s = 0; s < nPart; ++s) v += Yp[s * pStride + (long)row * 256 + e];
  float s1 = v;
#pragma unroll
  for (int o = 32; o > 0; o >>= 1) s1 += __shfl_down(s1, o);
  if ((e & 63) == 0) red[e >> 6] = s1;
  __syncthreads();
  float mean = (red[0] + red[1] + red[2] + red[3]) * (1.f / 256.f);
  float d = v - mean;
  __syncthreads();
  float s2 = d * d;
#pragma unroll
  for (int o = 32; o > 0; o >>= 1) s2 += __shfl_down(s2, o);
  if ((e & 63) == 0) red[e >> 6] = s2;
  __syncthreads();
  float var = (red[0] + red[1] + red[2] + red[3]) * (1.f / 256.f);
  float o = g[e] * d * rsqrtf(var + 1e-5f) + bta[e];
  out[(long)row * 256 + e] = o;
  out_bf[(long)row * 256 + e] = f2b(o);
}

// ---------------- fused mean-over-latents + classifier ----------------
__global__ __launch_bounds__(256) void k_meancls(
    const float* __restrict__ z, const float* __restrict__ w,
    const float* __restrict__ bias, float* __restrict__ out)
{
  __shared__ float zms[256];
  int b = blockIdx.y, e = threadIdx.x;
  float s = 0.f;
  for (int l = 0; l < 512; ++l) s += z[((long)b * 512 + l) * 256 + e];
  zms[e] = s * (1.f / 512.f);
  __syncthreads();
  int j = blockIdx.x * 256 + e;
  if (j >= 1000) return;
  float acc = bias[j];
  for (int e2 = 0; e2 < 256; ++e2) acc += zms[e2] * w[e2 * 1000 + j];
  out[b * 1000 + j] = acc;
}

extern "C" void kernel_launch(void* const* d_in, const int* in_sizes, int n_in,
                              void* d_out, int out_size, void* d_ws, size_t ws_size,
                              hipStream_t stream)
{
  (void)in_sizes; (void)n_in; (void)out_size; (void)ws_size;
  const float* x       = (const float*)d_in[0];
  const float* conv_w  = (const float*)d_in[1];
  const float* conv_b  = (const float*)d_in[2];
  const float* pos_emb = (const float*)d_in[3];
  const float* latents = (const float*)d_in[4];
  const float* ca_wq   = (const float*)d_in[5];
  const float* ca_wk   = (const float*)d_in[6];
  const float* ca_wv   = (const float*)d_in[7];
  const float* ca_wu   = (const float*)d_in[8];
  const float* ca_bu   = (const float*)d_in[9];
  const float* ca_ln_g = (const float*)d_in[10];
  const float* ca_ln_b = (const float*)d_in[11];
  const float* blk_wq  = (const float*)d_in[12];
  const float* blk_wk  = (const float*)d_in[13];
  const float* blk_wv  = (const float*)d_in[14];
  const float* blk_wu  = (const float*)d_in[15];
  const float* blk_bu  = (const float*)d_in[16];
  const float* blk_ln1_g = (const float*)d_in[17];
  const float* blk_ln1_b = (const float*)d_in[18];
  const float* blk_w1  = (const float*)d_in[19];
  const float* blk_b1  = (const float*)d_in[20];
  const float* blk_w2  = (const float*)d_in[21];
  const float* blk_b2  = (const float*)d_in[22];
  const float* blk_ln2_g = (const float*)d_in[23];
  const float* blk_ln2_b = (const float*)d_in[24];
  const float* cls_w   = (const float*)d_in[25];
  const float* cls_b   = (const float*)d_in[26];
  float* out = (float*)d_out;

  // ---- workspace layout (bf16 as short) ----
  short* wq_bf  = (short*)d_ws;            // 256x2048 (scaled)
  short* wk_bf  = wq_bf + 524288;          // 256x2048
  short* wuT_ca = wk_bf + 524288;          // 256x2048
  short* wv_ca  = wuT_ca + 524288;         // 256x2048
  short* lat_bf = wv_ca + 524288;          // 512x256
  short* wqkT   = lat_bf + 131072;         // 4 x (4096x256)
  short* wvT    = wqkT + 4194304;          // 4 x (2048x256)
  short* wuT_b  = wvT + 2097152;           // 4 x (256x2048)
  short* w1T    = wuT_b + 2097152;         // 4 x (1024x256)
  short* w2T    = w1T + 1048576;           // 4 x (256x1024)
  short* tok_bf = w2T + 1048576;           // 4 x 4096x256
  short* tokT   = tok_bf + 4194304;        // 4 x 256x4096
  short* WqkT   = tokT + 4194304;          // 8 x 256x256
  short* qtil   = WqkT + 524288;           // 8 x 512x256
  short* MstT   = qtil + 1048576;          // 256x2048
  short* VtB    = MstT + 524288;           // 32 x 256x512
  short* bufO   = VtB + 4194304;           // 4 x 512x2048
  short* h1     = bufO + 4194304;          // 2048x1024
  short* z_bf   = h1 + 2097152;            // 2048x256
  float* z      = (float*)(z_bf + 524288); // 2048x256 fp32
  float* Ypart  = z + 524288;              // 4 x 2048x256 fp32 (split-K partials)
  short* Opart  = (short*)(Ypart + 4194304); // 4 x (4x8x512x256) bf16 kv-partials
  float* MLp    = (float*)(Opart + 16777216); // 4 x (4x8x512x2) fp32
  short* QKb    = tok_bf;                  // alias: 2048x4096 (after CA)
  const int BIG = 1 << 30;

  const float scale = 0.17677669529663687f; // 1/sqrt(32), folded into Wq

  // ---- weight prep: one batched dispatch ----
  TrJobs JB; int nj = 0, base = 0;
  auto addT = [&](const float* s, short* d, int R, int C, long sIn, long sOut,
                  int zc, float sc) {
    int tpz = (C >> 5) * (R >> 5);
    JB.j[nj] = {s, d, R, C, sIn, sOut, 0, tpz, zc, base, sc};
    base += tpz * zc; ++nj;
  };
  auto addC = [&](const float* s, short* d, int nelem, float sc) {
    int tpz = nelem >> 13;
    JB.j[nj] = {s, d, 0, 0, 0, 0, 1, tpz, 1, base, sc};
    base += tpz; ++nj;
  };
  addT(ca_wu, wuT_ca, 2048, 256, 0, 0, 1, 1.f);
  addT(blk_wq, wqkT, 256, 2048, 524288, 1048576, 4, scale);
  addT(blk_wk, wqkT + 524288, 256, 2048, 524288, 1048576, 4, 1.f);
  addT(blk_wv, wvT, 256, 2048, 524288, 524288, 4, 1.f);
  addT(blk_wu, wuT_b, 2048, 256, 524288, 524288, 4, 1.f);
  addT(blk_w1, w1T, 256, 1024, 262144, 262144, 4, 1.f);
  addT(blk_w2, w2T, 1024, 256, 262144, 262144, 4, 1.f);
  addC(ca_wv, wv_ca, 524288, 1.f);
  addC(latents, lat_bf, 131072, 1.f);
  addC(ca_wq, wq_bf, 524288, scale);
  addC(ca_wk, wk_bf, 524288, 1.f);
  k_trbatch<<<base, 256, 0, stream>>>(JB, nj);

  // ---- tokens (both layouts, one pass; packed 16B tokT stores) ----
  k_tokens2<<<dim3(128, 4), 256, 0, stream>>>(x, conv_w, conv_b, pos_emb,
                                              tok_bf, tokT);

  // ---- CA prep: WqkT_h = Wk_h @ (scale*Wq_h)^T ; MstT_h = Wu_h^T @ Wv_h^T
  {
    GJobs G;
    G.j[0] = {wk_bf, wq_bf, WqkT, nullptr, 256, 2048, 2048, 256,
              256, 256, 65536, 1, 8, 1, 8, 0, 2, 2, 0};
    G.j[1] = {wuT_ca, wv_ca, MstT, nullptr, 256, 2048, 2048, 2048,
              256, 256, 256, 1, 8, 1, 8, 0, 2, 2, 32};
    k_gemm_m<<<64, 256, 0, stream>>>(G, 2);
  }
  // qtil_h = latents @ Wqk_h
  {
    GJobs G;
    G.j[0] = {lat_bf, WqkT, qtil, nullptr, 256, 256, 256, 256,
              0, 65536, 131072, 1, 1, 1, 8, 0, 2, 4, 0};
    k_gemm_m<<<64, 256, 0, stream>>>(G, 1);
  }
  // CA flash: Q=qtilde(h) [pre-scaled], K=tokens(b), Vt=tokensT(b)
  k_mflash7<<<dim3(8, 8, 4), 512, 0, stream>>>(
      qtil, tok_bf, tokT, Opart, MLp, 4096, 256, 256, 4096,
      131072L, 0L, 0L, 1048576L, 0L, 1048576L);
  k_fcomb<<<dim3(256, 8, 4), 512, 0, stream>>>(Opart, MLp, bufO);
  // Y = bufO(2048x2048) @ MstT^T, split-K x4 -> fp32 partials
  {
    GJobs G;
    G.j[0] = {bufO, MstT, Ypart, nullptr, 512, 2048, 2048, 256,
              512, 512, 524288, 1, 4, 1, 4, 2, 2, 16, 0};
    k_gemm_m<<<128, 256, 0, stream>>>(G, 1);
  }
  k_bias_res_ln<<<2048, 256, 0, stream>>>(Ypart, 4, 524288L, ca_bu, latents, 512,
                                          ca_ln_g, ca_ln_b, z, z_bf);

  // ---- transformer blocks ----
  for (int d = 0; d < 4; ++d) {
    // [Q|K] = z @ [scale*wq wk] -> QKb ; Vt(b,h) = wvT_h @ z_b^T  (merged)
    {
      GJobs G;
      G.j[0] = {z_bf, wqkT + (long)d * 1048576, QKb, nullptr,
                256, 256, 256, 4096, 0, 0, 0, 1, 1, 1, 1, 0, 32, 16, 0};
      G.j[1] = {wvT + (long)d * 524288, z_bf, VtB, nullptr,
                256, 256, 256, 512, 65536, 131072, 131072,
                1, 8, 8, BIG, 0, 4, 2, 512};
      k_gemm_m<<<768, 256, 0, stream>>>(G, 2);
    }
    // self flash
    k_mflash7<<<dim3(8, 8, 4), 512, 0, stream>>>(
        QKb, QKb + 2048, VtB, Opart, MLp, 512, 4096, 4096, 512,
        256L, 2097152L, 256L, 2097152L, 131072L, 1048576L);
    k_fcomb<<<dim3(256, 8, 4), 512, 0, stream>>>(Opart, MLp, bufO);
    // Y = bufO @ wu^T, split-K x4 -> fp32 partials
    {
      GJobs G;
      G.j[0] = {bufO, wuT_b + (long)d * 524288, Ypart, nullptr,
                512, 2048, 2048, 256, 512, 512, 524288, 1, 4, 1, 4, 2, 2, 16, 0};
      k_gemm_m<<<128, 256, 0, stream>>>(G, 1);
    }
    k_bias_res_ln<<<2048, 256, 0, stream>>>(Ypart, 4, 524288L, blk_bu + d * 256, z, 2048,
        blk_ln1_g + d * 256, blk_ln1_b + d * 256, z, z_bf);
    // h1 = gelu(z @ w1 + b1)
    {
      GJobs G;
      G.j[0] = {z_bf, w1T + (long)d * 262144, h1, blk_b1 + d * 1024,
                256, 256, 256, 1024, 0, 0, 0, 1, 1, 1, 1, 1, 8, 16, 0};
      k_gemm_m<<<128, 256, 0, stream>>>(G, 1);
    }
    // Y = h1 @ w2, split-K x4 (Ksub=256) -> fp32 partials
    {
      GJobs G;
      G.j[0] = {h1, w2T + (long)d * 262144, Ypart, nullptr,
                256, 1024, 1024, 256, 256, 256, 524288, 1, 4, 1, 4, 2, 2, 16, 0};
      k_gemm_m<<<128, 256, 0, stream>>>(G, 1);
    }
    k_bias_res_ln<<<2048, 256, 0, stream>>>(Ypart, 4, 524288L, blk_b2 + d * 256, z, 2048,
        blk_ln2_g + d * 256, blk_ln2_b + d * 256, z, z_bf);
  }

  k_meancls<<<dim3(4, 4), 256, 0, stream>>>(z, cls_w, cls_b, out);
}

// Round 9
// 639.549 us; speedup vs baseline: 1.1015x; 1.1015x over previous
//
#include <hip/hip_runtime.h>
#include <hip/hip_bf16.h>
#include <math.h>

// Perceiver: B=4,C=3,N=4096,E=256,H=8,FFE=1024,L=512,D=4,NCLS=1000,HS=2048
// bf16 MFMA everywhere GEMM-shaped; fp32 accum; fp32 LN/residual spine.

typedef __attribute__((ext_vector_type(8))) short s8v;    // 8 bf16 = 4 VGPR
typedef __attribute__((ext_vector_type(4))) float f32x4;  // 16x16 MFMA accum
typedef __attribute__((ext_vector_type(16))) float f32x16;// 32x32 MFMA accum
typedef __attribute__((ext_vector_type(4))) unsigned u32x4;

__device__ __forceinline__ short f2b(float f) {
  union { float f; unsigned u; } a; a.f = f;
  unsigned r = a.u + 0x7fff + ((a.u >> 16) & 1);
  return (short)(r >> 16);
}
__device__ __forceinline__ float b2f(short s) {
  union { unsigned u; float f; } a; a.u = ((unsigned)(unsigned short)s) << 16;
  return a.f;
}
__device__ __forceinline__ unsigned cvtpk(float lo, float hi) {
  unsigned r;
  asm("v_cvt_pk_bf16_f32 %0, %1, %2" : "=v"(r) : "v"(lo), "v"(hi));
  return r;
}

// async global->LDS, 16B per lane; LDS dest = uniform base + lane*16
__device__ __forceinline__ void gl16(const void* gp, void* lp) {
  __builtin_amdgcn_global_load_lds(
      (const __attribute__((address_space(1))) unsigned int*)gp,
      (__attribute__((address_space(3))) unsigned int*)lp, 16, 0, 0);
}

// ------- tokens(bf16) = conv1x1(x)+bias+pos, writes tok AND tokT ---------
__global__ __launch_bounds__(256) void k_tokens2(
    const float* __restrict__ x, const float* __restrict__ cw,
    const float* __restrict__ cb, const float* __restrict__ pe,
    short* __restrict__ tok, short* __restrict__ tokT)
{
  int b = blockIdx.y, n0 = blockIdx.x * 32;
  int e = threadIdx.x;
  float c0 = cw[e * 3], c1 = cw[e * 3 + 1], c2 = cw[e * 3 + 2], cbv = cb[e];
  const float* xb = x + b * 12288 + n0;
  short acc[32];
#pragma unroll
  for (int i = 0; i < 32; ++i) {
    int n = n0 + i;
    float s = cbv + pe[n * 256 + e] + xb[i] * c0 + xb[4096 + i] * c1 + xb[8192 + i] * c2;
    short v = f2b(s);
    tok[((long)b * 4096 + n) * 256 + e] = v;
    acc[i] = v;
  }
  short* tr = tokT + ((long)b * 256 + e) * 4096 + n0;
#pragma unroll
  for (int i = 0; i < 4; ++i)
    *reinterpret_cast<s8v*>(tr + i * 8) = *reinterpret_cast<s8v*>(acc + i * 8);
}

// ---------------- batched weight prep: transposes + flat converts --------
struct TrJob {
  const float* src; short* dst;
  int R, C; long sIn, sOut;
  int mode, tilesPerZ, z, tileBase;
  float scale;
};
struct TrJobs { TrJob j[11]; };

__global__ __launch_bounds__(256) void k_trbatch(TrJobs jb, int njobs)
{
  __shared__ float t[32][33];
  int tb = blockIdx.x, ji = 0;
#pragma unroll
  for (int k = 1; k < 11; ++k)
    if (k < njobs && tb >= jb.j[k].tileBase) ji = k;
  TrJob J = jb.j[ji];
  int local = tb - J.tileBase;
  if (J.mode == 1) {          // flat fp32 -> bf16 (*scale)
    long o = (long)local * 8192 + threadIdx.x;
#pragma unroll
    for (int k = 0; k < 32; ++k)
      J.dst[o + k * 256] = f2b(J.src[o + k * 256] * J.scale);
    return;
  }
  int zi = local / J.tilesPerZ, ti = local - zi * J.tilesPerZ;
  int ntx = J.C >> 5;
  int tx = ti % ntx, ty = ti / ntx;
  const float* ib = J.src + (long)zi * J.sIn;
  short* ob = J.dst + (long)zi * J.sOut;
  int c0 = tx * 32, r0 = ty * 32;
  int lx = threadIdx.x & 31, ly = threadIdx.x >> 5;
#pragma unroll
  for (int i = 0; i < 4; ++i)
    t[ly * 4 + i][lx] = ib[(long)(r0 + ly * 4 + i) * J.C + c0 + lx];
  __syncthreads();
#pragma unroll
  for (int i = 0; i < 4; ++i)
    ob[(long)(c0 + ly * 4 + i) * J.R + r0 + lx] = f2b(t[lx][ly * 4 + i] * J.scale);
}

// ---------------- bf16 MFMA BT-GEMM: C = A(MxK) @ Bt(NxK)^T ----------------
// 128x128 tile, BK=32, 256 thr. Prefetch pipeline. Requires K % 64 == 0.
// EPI: 0 = bf16 out, 1 = bias+exact-gelu bf16 out, 2 = fp32 out (partials).
template<int EPI>
__global__ __launch_bounds__(256) void k_mgemm(
    const short* __restrict__ A, const short* __restrict__ Bt,
    void* __restrict__ Cv, const float* __restrict__ bias,
    int K, int lda, int ldb, int ldc,
    long sA, long sB, long sC, int zdA, int zmA, int zdB, int zmB)
{
  __shared__ char As[8192];
  __shared__ char Bs[8192];
  int z = blockIdx.z;
  const short* Ab = A + ((long)((z / zdA) % zmA)) * sA;
  const short* Bb = Bt + ((long)((z / zdB) % zmB)) * sB;
  int t = threadIdx.x;
  int lane = t & 63, w = t >> 6;
  int wr = w >> 1, wc = w & 1;
  int g = lane >> 4, l15 = lane & 15;
  long row0 = (long)blockIdx.y * 128, col0 = (long)blockIdx.x * 128;
  const f32x4 zz = {0.f, 0.f, 0.f, 0.f};
  f32x4 acc[4][4];
#pragma unroll
  for (int m = 0; m < 4; ++m)
#pragma unroll
    for (int n = 0; n < 4; ++n) acc[m][n] = zz;

  auto mload = [&](s8v* aa, s8v* bb, int kk) {
#pragma unroll
    for (int i = 0; i < 2; ++i) {
      int r = i * 64 + (t >> 2), c = t & 3;
      aa[i] = *(const s8v*)&Ab[(row0 + r) * (long)lda + kk + c * 8];
      bb[i] = *(const s8v*)&Bb[(col0 + r) * (long)ldb + kk + c * 8];
    }
  };
  auto mstore = [&](s8v* aa, s8v* bb) {
#pragma unroll
    for (int i = 0; i < 2; ++i) {
      int r = i * 64 + (t >> 2), c = t & 3;
      int off = (r * 64 + c * 16) ^ ((r & 7) << 4);
      *(s8v*)&As[off] = aa[i];
      *(s8v*)&Bs[off] = bb[i];
    }
  };
  auto mcomp = [&]() {
    s8v af[4], bfr[4];
#pragma unroll
    for (int m = 0; m < 4; ++m) {
      int r = wr * 64 + m * 16 + l15;
      af[m] = *(const s8v*)&As[(r * 64 + g * 16) ^ ((r & 7) << 4)];
    }
#pragma unroll
    for (int n = 0; n < 4; ++n) {
      int r = wc * 64 + n * 16 + l15;
      bfr[n] = *(const s8v*)&Bs[(r * 64 + g * 16) ^ ((r & 7) << 4)];
    }
#pragma unroll
    for (int m = 0; m < 4; ++m)
#pragma unroll
      for (int n = 0; n < 4; ++n)
        acc[m][n] = __builtin_amdgcn_mfma_f32_16x16x32_bf16(af[m], bfr[n], acc[m][n], 0, 0, 0);
  };

  s8v a0[2], b0[2], a1[2], b1[2];
  mload(a0, b0, 0);
  for (int k0 = 0; k0 < K; k0 += 64) {
    __syncthreads(); mstore(a0, b0); __syncthreads();
    mload(a1, b1, k0 + 32);
    mcomp();
    __syncthreads(); mstore(a1, b1); __syncthreads();
    if (k0 + 64 < K) mload(a0, b0, k0 + 64);
    mcomp();
  }

  long zo = (long)z * sC;
#pragma unroll
  for (int m = 0; m < 4; ++m)
#pragma unroll
    for (int n = 0; n < 4; ++n)
#pragma unroll
      for (int r = 0; r < 4; ++r) {
        long rr = row0 + wr * 64 + m * 16 + g * 4 + r;
        long cc = col0 + wc * 64 + n * 16 + l15;
        float v = acc[m][n][r];
        if (EPI == 1) {
          v += bias[cc];
          v = 0.5f * v * (1.f + erff(v * 0.70710678118654752f));
        }
        if (EPI == 2)
          ((float*)Cv)[zo + rr * ldc + cc] = v;
        else
          ((short*)Cv)[zo + rr * ldc + cc] = f2b(v);
      }
}

// ---------------- MFMA flash attention v8 (head dim 256, 32x32 MFMA) -----
// 8 waves x 32 q-rows = 256 q/block, KVBLK=64, swapped QK^T (mfma(K,Q)),
// in-register softmax, P->PV A-frags via cvt_pk + cross-half shfl.
// kv-split x4 to partials. Epilogue: coalesced Opart stores via LDS bounce
// through the dead K/V buffer (wave-private region, parity-safe).
__global__ __launch_bounds__(512, 2) void k_mflash8(
    const short* __restrict__ Qp, const short* __restrict__ Kp,
    const short* __restrict__ Vtp, short* __restrict__ Opart,
    float* __restrict__ MLp,
    int nk, int ldq, int ldk, int ldvt,
    long qh, long qb, long kh, long kb, long vh, long vb)
{
  __shared__ char pool[131072];  // 2 x (K 32KB + V 32KB)
  int t = threadIdx.x, lane = t & 63, w = t >> 6;
  int l31 = lane & 31, hi = lane >> 5;
  int h = blockIdx.y, b = blockIdx.z;
  int kv = blockIdx.x & 3, qblk = blockIdx.x >> 2;
  const short* Q  = Qp  + (long)h * qh + (long)b * qb;
  const short* Kg = Kp  + (long)h * kh + (long)b * kb;
  const short* Vg = Vtp + (long)h * vh + (long)b * vb;
  int q0w = qblk * 256 + w * 32;
  int nkq = nk >> 2;
  int NIT = nkq >> 6;           // KVBLK = 64
  long k0 = (long)kv * nkq;

  // Q B-frags: lane = q-col (l31), k = hi*8+j within d-slice s
  s8v qf[16];
  {
    const short* Qrow = Q + (long)(q0w + l31) * ldq + hi * 8;
#pragma unroll
    for (int s = 0; s < 16; ++s) qf[s] = *(const s8v*)(Qrow + s * 16);
  }

  // staging byte-offsets (32-bit; linear LDS dest + inverse-swizzled source)
  const char* KgB = (const char*)Kg;
  const char* VgB = (const char*)Vg;
  unsigned koff[4], voff[4];
#pragma unroll
  for (int c = 0; c < 4; ++c) {
    int r = 8 * w + 2 * c + hi;                 // K tile row 0..63
    koff[c] = (unsigned)((k0 + r) * (long)ldk * 2) + ((l31 ^ (r & 31)) << 4);
    int rv = 32 * w + 8 * c + (lane >> 3);      // V tile row 0..255
    voff[c] = (unsigned)(((long)rv * ldvt + k0) * 2) + (((lane & 7) ^ (lane >> 3)) << 4);
  }
  const unsigned kStep = (unsigned)(64 * ldk * 2);

  auto stage = [&](int bsel) {
    char* kd = pool + bsel * 65536 + (w << 12);
    char* vd = kd + 32768;
#pragma unroll
    for (int c = 0; c < 4; ++c) { gl16(KgB + koff[c], kd + c * 1024); koff[c] += kStep; }
#pragma unroll
    for (int c = 0; c < 4; ++c) { gl16(VgB + voff[c], vd + c * 1024); voff[c] += 128; }
  };

  f32x16 accO[8];
#pragma unroll
  for (int n = 0; n < 8; ++n)
#pragma unroll
    for (int i = 0; i < 16; ++i) accO[n][i] = 0.f;
  float mrow = -1e30f, lrow = 0.f;

  stage(0);

  for (int it = 0; it < NIT; ++it) {
    int cur = it & 1;
    asm volatile("s_waitcnt vmcnt(0)" ::: "memory");
    __syncthreads();
    if (it + 1 < NIT) stage(cur ^ 1);
    const char* kls = pool + cur * 65536;
    const char* vls = kls + 32768;

    // S^T = mfma(K, Q): 2 M-tiles (k) x 16 d-slices; C col = q, row = k
    f32x16 sacc[2];
#pragma unroll
    for (int i = 0; i < 16; ++i) { sacc[0][i] = 0.f; sacc[1][i] = 0.f; }
    __builtin_amdgcn_s_setprio(1);
#pragma unroll
    for (int tt = 0; tt < 2; ++tt) {
      int r = tt * 32 + l31;
#pragma unroll
      for (int s = 0; s < 16; ++s) {
        s8v kf = *(const s8v*)&kls[r * 512 + (((2 * s + hi) ^ l31) << 4)];
        sacc[tt] = __builtin_amdgcn_mfma_f32_32x32x16_bf16(kf, qf[s], sacc[tt], 0, 0, 0);
      }
    }
    __builtin_amdgcn_s_setprio(0);

    // in-register softmax over 64 k (32 local + 32 in partner half)
    float mt = sacc[0][0];
#pragma unroll
    for (int i = 1; i < 16; ++i) mt = fmaxf(mt, sacc[0][i]);
#pragma unroll
    for (int i = 0; i < 16; ++i) mt = fmaxf(mt, sacc[1][i]);
    mt = fmaxf(mt, __shfl_xor(mt, 32));
    if (__any(mt - mrow > 8.f)) {       // defer-max (T13)
      float mn = fmaxf(mrow, mt);
      float al = __expf(mrow - mn);
      mrow = mn; lrow *= al;
#pragma unroll
      for (int r = 0; r < 16; ++r) {
        float alr = __shfl(al, (r & 3) + 8 * (r >> 2) + 4 * hi);
#pragma unroll
        for (int n = 0; n < 8; ++n) accO[n][r] *= alr;
      }
    }
    float ls = 0.f;
#pragma unroll
    for (int tt = 0; tt < 2; ++tt)
#pragma unroll
      for (int i = 0; i < 16; ++i) {
        float p = __expf(sacc[tt][i] - mrow);
        sacc[tt][i] = p; ls += p;
      }
    ls += __shfl_xor(ls, 32);
    lrow += ls;

    // PV A-frags: cvt_pk + cross-half exchange
    s8v pa[4];
#pragma unroll
    for (int s = 0; s < 4; ++s) {
      int tt = s >> 1, r0 = (s & 1) * 8;
      unsigned w0 = cvtpk(sacc[tt][r0 + 0], sacc[tt][r0 + 1]);
      unsigned w1 = cvtpk(sacc[tt][r0 + 2], sacc[tt][r0 + 3]);
      unsigned w2 = cvtpk(sacc[tt][r0 + 4], sacc[tt][r0 + 5]);
      unsigned w3 = cvtpk(sacc[tt][r0 + 6], sacc[tt][r0 + 7]);
      unsigned x0 = (unsigned)__shfl_xor((int)w0, 32);
      unsigned x1 = (unsigned)__shfl_xor((int)w1, 32);
      unsigned x2 = (unsigned)__shfl_xor((int)w2, 32);
      unsigned x3 = (unsigned)__shfl_xor((int)w3, 32);
      u32x4 pw;
      pw.x = hi ? x2 : w0;
      pw.y = hi ? x3 : w1;
      pw.z = hi ? w2 : x0;
      pw.w = hi ? w3 : x1;
      pa[s] = *(s8v*)&pw;
    }

    // O += P @ V: 8 d-tiles x 4 k-slices; B = Vt (col = d, k = hi*8+j)
    __builtin_amdgcn_s_setprio(1);
#pragma unroll
    for (int n = 0; n < 8; ++n) {
      int rv = n * 32 + l31;
#pragma unroll
      for (int s2 = 0; s2 < 4; ++s2) {
        s8v vf = *(const s8v*)&vls[rv * 128 + (((2 * s2 + hi) ^ (l31 & 7)) << 4)];
        accO[n] = __builtin_amdgcn_mfma_f32_32x32x16_bf16(pa[s2], vf, accO[n], 0, 0, 0);
      }
    }
    __builtin_amdgcn_s_setprio(0);
  }

  // ---- epilogue: ML + coalesced Opart via LDS bounce (dead K/V buffer) ----
  long prow = (((long)kv * 4 + b) * 8 + h) * 512;
  short* Ob = Opart + prow * 256;
  float* MLb = MLp + prow * 2;
  if (lane < 32) {
    MLb[(q0w + l31) * 2] = mrow;
    MLb[(q0w + l31) * 2 + 1] = lrow;
  }
  // free buffer = the one NOT used by the last iteration (parity-safe)
  char* freebuf = pool + ((((NIT - 1) & 1) ^ 1) << 16);
  float* st = (float*)(freebuf + w * 4096);   // wave-private 4KB
  int orow = lane >> 1, ohalf = lane & 1;
#pragma unroll
  for (int n = 0; n < 8; ++n) {
#pragma unroll
    for (int r = 0; r < 16; ++r) {
      int ql = (r & 3) + 8 * (r >> 2) + 4 * hi;
      st[ql * 32 + l31] = accO[n][r];
    }
    short obuf[16];
#pragma unroll
    for (int jj = 0; jj < 4; ++jj) {
      f32x4 v = *(const f32x4*)&st[orow * 32 + ohalf * 16 + jj * 4];
      obuf[jj * 4 + 0] = f2b(v.x); obuf[jj * 4 + 1] = f2b(v.y);
      obuf[jj * 4 + 2] = f2b(v.z); obuf[jj * 4 + 3] = f2b(v.w);
    }
    short* dst = Ob + (long)(q0w + orow) * 256 + n * 32 + ohalf * 16;
    *(s8v*)(dst) = *(s8v*)&obuf[0];
    *(s8v*)(dst + 8) = *(s8v*)&obuf[8];
  }
}

// ---------------- combine 4 kv partials -> bufO bf16 ----------------
__global__ __launch_bounds__(512) void k_fcomb(
    const short* __restrict__ Op, const float* __restrict__ ML,
    short* __restrict__ O)
{
  int d = threadIdx.x & 255;
  int q = blockIdx.x * 2 + (threadIdx.x >> 8);
  int h = blockIdx.y, b = blockIdx.z;
  const long kvs = 4L * 8 * 512;  // rows per kv slice
  long r0 = ((long)b * 8 + h) * 512 + q;
  float mm[4], ll[4], m = -1e30f;
#pragma unroll
  for (int kv = 0; kv < 4; ++kv) {
    mm[kv] = ML[(kv * kvs + r0) * 2];
    ll[kv] = ML[(kv * kvs + r0) * 2 + 1];
    m = fmaxf(m, mm[kv]);
  }
  float wv[4], lsum = 0.f;
#pragma unroll
  for (int kv = 0; kv < 4; ++kv) { wv[kv] = __expf(mm[kv] - m); lsum += ll[kv] * wv[kv]; }
  float inv = 1.f / lsum, acc = 0.f;
#pragma unroll
  for (int kv = 0; kv < 4; ++kv)
    acc += b2f(Op[(kv * kvs + r0) * 256 + d]) * wv[kv];
  O[(long)b * 1048576 + (long)q * 2048 + h * 256 + d] = f2b(acc * inv);
}

// ---------------- z = LN(sum(Ypart) + bias + res) ----------------
__global__ __launch_bounds__(256) void k_bias_res_ln(
    const float* __restrict__ Yp, int nPart, long pStride,
    const float* __restrict__ bias,
    const float* __restrict__ res, int resMod,
    const float* __restrict__ g, const float* __restrict__ bta,
    float* __restrict__ out, short* __restrict__ out_bf)
{
  __shared__ float red[4];
  int row = blockIdx.x, e = threadIdx.x;
  float v = bias[e] + res[(long)(row % resMod) * 256 + e];
  for (int s = 0; s < nPart; ++s) v += Yp[s * pStride + (long)row * 256 + e];
  float s1 = v;
#pragma unroll
  for (int o = 32; o > 0; o >>= 1) s1 += __shfl_down(s1, o);
  if ((e & 63) == 0) red[e >> 6] = s1;
  __syncthreads();
  float mean = (red[0] + red[1] + red[2] + red[3]) * (1.f / 256.f);
  float d = v - mean;
  __syncthreads();
  float s2 = d * d;
#pragma unroll
  for (int o = 32; o > 0; o >>= 1) s2 += __shfl_down(s2, o);
  if ((e & 63) == 0) red[e >> 6] = s2;
  __syncthreads();
  float var = (red[0] + red[1] + red[2] + red[3]) * (1.f / 256.f);
  float o = g[e] * d * rsqrtf(var + 1e-5f) + bta[e];
  out[(long)row * 256 + e] = o;
  out_bf[(long)row * 256 + e] = f2b(o);
}

// ---------------- fused mean-over-latents + classifier ----------------
__global__ __launch_bounds__(256) void k_meancls(
    const float* __restrict__ z, const float* __restrict__ w,
    const float* __restrict__ bias, float* __restrict__ out)
{
  __shared__ float zms[256];
  int b = blockIdx.y, e = threadIdx.x;
  float s = 0.f;
  for (int l = 0; l < 512; ++l) s += z[((long)b * 512 + l) * 256 + e];
  zms[e] = s * (1.f / 512.f);
  __syncthreads();
  int j = blockIdx.x * 256 + e;
  if (j >= 1000) return;
  float acc = bias[j];
  for (int e2 = 0; e2 < 256; ++e2) acc += zms[e2] * w[e2 * 1000 + j];
  out[b * 1000 + j] = acc;
}

extern "C" void kernel_launch(void* const* d_in, const int* in_sizes, int n_in,
                              void* d_out, int out_size, void* d_ws, size_t ws_size,
                              hipStream_t stream)
{
  (void)in_sizes; (void)n_in; (void)out_size; (void)ws_size;
  const float* x       = (const float*)d_in[0];
  const float* conv_w  = (const float*)d_in[1];
  const float* conv_b  = (const float*)d_in[2];
  const float* pos_emb = (const float*)d_in[3];
  const float* latents = (const float*)d_in[4];
  const float* ca_wq   = (const float*)d_in[5];
  const float* ca_wk   = (const float*)d_in[6];
  const float* ca_wv   = (const float*)d_in[7];
  const float* ca_wu   = (const float*)d_in[8];
  const float* ca_bu   = (const float*)d_in[9];
  const float* ca_ln_g = (const float*)d_in[10];
  const float* ca_ln_b = (const float*)d_in[11];
  const float* blk_wq  = (const float*)d_in[12];
  const float* blk_wk  = (const float*)d_in[13];
  const float* blk_wv  = (const float*)d_in[14];
  const float* blk_wu  = (const float*)d_in[15];
  const float* blk_bu  = (const float*)d_in[16];
  const float* blk_ln1_g = (const float*)d_in[17];
  const float* blk_ln1_b = (const float*)d_in[18];
  const float* blk_w1  = (const float*)d_in[19];
  const float* blk_b1  = (const float*)d_in[20];
  const float* blk_w2  = (const float*)d_in[21];
  const float* blk_b2  = (const float*)d_in[22];
  const float* blk_ln2_g = (const float*)d_in[23];
  const float* blk_ln2_b = (const float*)d_in[24];
  const float* cls_w   = (const float*)d_in[25];
  const float* cls_b   = (const float*)d_in[26];
  float* out = (float*)d_out;

  // ---- workspace layout (bf16 as short) ----
  short* wqT_ca = (short*)d_ws;            // 2048x256 (scaled)
  short* wkT_ca = wqT_ca + 524288;         // 2048x256
  short* wuT_ca = wkT_ca + 524288;         // 256x2048
  short* wv_ca  = wuT_ca + 524288;         // 256x2048
  short* lat_bf = wv_ca + 524288;          // 512x256
  short* wqkT   = lat_bf + 131072;         // 4 x (4096x256)
  short* wvT    = wqkT + 4194304;          // 4 x (2048x256)
  short* wuT_b  = wvT + 2097152;           // 4 x (256x2048)
  short* w1T    = wuT_b + 2097152;         // 4 x (1024x256)
  short* w2T    = w1T + 1048576;           // 4 x (256x1024)
  short* tok_bf = w2T + 1048576;           // 4 x 4096x256
  short* tokT   = tok_bf + 4194304;        // 4 x 256x4096
  short* qCA    = tokT + 4194304;          // 512x2048
  short* qtil   = qCA + 1048576;           // 8 x 512x256
  short* MstT   = qtil + 1048576;          // 256x2048
  short* VtB    = MstT + 524288;           // 32 x 256x512
  short* bufO   = VtB + 4194304;           // 4 x 512x2048
  short* h1     = bufO + 4194304;          // 2048x1024
  short* z_bf   = h1 + 2097152;            // 2048x256
  float* z      = (float*)(z_bf + 524288); // 2048x256 fp32
  float* zm     = z + 524288;              // spare
  float* Ypart  = zm + 1024;               // 8 x 2048x256 fp32 (split-K partials)
  short* Opart  = (short*)(Ypart + 4194304); // 4 x (4x8x512x256) bf16 kv-partials
  float* MLp    = (float*)(Opart + 16777216); // 4 x (4x8x512x2) fp32
  short* QKb    = tok_bf;                  // alias: 2048x4096 (after CA)

  const float scale = 0.17677669529663687f; // 1/sqrt(32), folded into Wq
  const int BIG = 1 << 30;

  // ---- weight prep: one batched dispatch (Wq pre-scaled) ----
  TrJobs JB; int nj = 0, base = 0;
  auto addT = [&](const float* s, short* d, int R, int C, long sIn, long sOut,
                  int zc, float sc) {
    int tpz = (C >> 5) * (R >> 5);
    JB.j[nj] = {s, d, R, C, sIn, sOut, 0, tpz, zc, base, sc};
    base += tpz * zc; ++nj;
  };
  auto addC = [&](const float* s, short* d, int nelem) {
    int tpz = nelem >> 13;
    JB.j[nj] = {s, d, 0, 0, 0, 0, 1, tpz, 1, base, 1.f};
    base += tpz; ++nj;
  };
  addT(ca_wq, wqT_ca, 256, 2048, 0, 0, 1, scale);
  addT(ca_wk, wkT_ca, 256, 2048, 0, 0, 1, 1.f);
  addT(ca_wu, wuT_ca, 2048, 256, 0, 0, 1, 1.f);
  addT(blk_wq, wqkT, 256, 2048, 524288, 1048576, 4, scale);
  addT(blk_wk, wqkT + 524288, 256, 2048, 524288, 1048576, 4, 1.f);
  addT(blk_wv, wvT, 256, 2048, 524288, 524288, 4, 1.f);
  addT(blk_wu, wuT_b, 2048, 256, 524288, 524288, 4, 1.f);
  addT(blk_w1, w1T, 256, 1024, 262144, 262144, 4, 1.f);
  addT(blk_w2, w2T, 1024, 256, 262144, 262144, 4, 1.f);
  addC(ca_wv, wv_ca, 524288);
  addC(latents, lat_bf, 131072);
  k_trbatch<<<base, 256, 0, stream>>>(JB, nj);

  // ---- tokens (both layouts, one pass) ----
  k_tokens2<<<dim3(128, 4), 256, 0, stream>>>(x, conv_w, conv_b, pos_emb,
                                              tok_bf, tokT);

  // ---- cross-attention (W_K folded into Q; W_V*W_U folded into MstT) ----
  k_mgemm<0><<<dim3(16, 4, 1), 256, 0, stream>>>(
      lat_bf, wqT_ca, qCA, nullptr, 256, 256, 256, 2048, 0, 0, 0, 1, BIG, 1, BIG);
  k_mgemm<0><<<dim3(2, 4, 8), 256, 0, stream>>>(
      qCA, wkT_ca, qtil, nullptr, 256, 2048, 256, 256, 256, 65536, 131072, 1, 8, 1, 8);
  k_mgemm<0><<<dim3(2, 2, 8), 256, 0, stream>>>(
      wuT_ca, wv_ca, MstT, nullptr, 256, 2048, 2048, 2048, 256, 256, 256, 1, 8, 1, 8);
  // CA flash: Q=qtilde(h) [pre-scaled], K=tokens(b), Vt=tokensT(b)
  k_mflash8<<<dim3(8, 8, 4), 512, 0, stream>>>(
      qtil, tok_bf, tokT, Opart, MLp, 4096, 256, 256, 4096,
      131072L, 0L, 0L, 1048576L, 0L, 1048576L);
  k_fcomb<<<dim3(256, 8, 4), 512, 0, stream>>>(Opart, MLp, bufO);
  // Y = bufO(2048x2048) @ MstT^T, split-K x8 -> fp32 partials
  k_mgemm<2><<<dim3(2, 16, 8), 256, 0, stream>>>(
      bufO, MstT, Ypart, nullptr, 256, 2048, 2048, 256, 256, 256, 524288, 1, 8, 1, 8);
  k_bias_res_ln<<<2048, 256, 0, stream>>>(Ypart, 8, 524288L, ca_bu, latents, 512,
                                          ca_ln_g, ca_ln_b, z, z_bf);

  // ---- transformer blocks ----
  for (int d = 0; d < 4; ++d) {
    // [Q|K] = z @ [scale*wq wk]  -> QKb (2048 x 4096) bf16
    k_mgemm<0><<<dim3(32, 16, 1), 256, 0, stream>>>(
        z_bf, wqkT + (long)d * 1048576, QKb, nullptr,
        256, 256, 256, 4096, 0, 0, 0, 1, BIG, 1, BIG);
    // Vt(b,h) = wvT_h @ z_b^T  (256 x 512)
    k_mgemm<0><<<dim3(4, 2, 32), 256, 0, stream>>>(
        wvT + (long)d * 524288, z_bf, VtB, nullptr,
        256, 256, 256, 512, 65536, 131072, 131072, 1, 8, 8, BIG);
    // self flash
    k_mflash8<<<dim3(8, 8, 4), 512, 0, stream>>>(
        QKb, QKb + 2048, VtB, Opart, MLp, 512, 4096, 4096, 512,
        256L, 2097152L, 256L, 2097152L, 131072L, 1048576L);
    k_fcomb<<<dim3(256, 8, 4), 512, 0, stream>>>(Opart, MLp, bufO);
    // Y = bufO @ wu^T, split-K x8 -> fp32 partials
    k_mgemm<2><<<dim3(2, 16, 8), 256, 0, stream>>>(
        bufO, wuT_b + (long)d * 524288, Ypart, nullptr,
        256, 2048, 2048, 256, 256, 256, 524288, 1, 8, 1, 8);
    k_bias_res_ln<<<2048, 256, 0, stream>>>(Ypart, 8, 524288L, blk_bu + d * 256, z, 2048,
        blk_ln1_g + d * 256, blk_ln1_b + d * 256, z, z_bf);
    // h1 = gelu(z @ w1 + b1)
    k_mgemm<1><<<dim3(8, 16, 1), 256, 0, stream>>>(
        z_bf, w1T + (long)d * 262144, h1, blk_b1 + d * 1024,
        256, 256, 256, 1024, 0, 0, 0, 1, BIG, 1, BIG);
    // Y = h1 @ w2, split-K x8 (Ksub=128) -> fp32 partials
    k_mgemm<2><<<dim3(2, 16, 8), 256, 0, stream>>>(
        h1, w2T + (long)d * 262144, Ypart, nullptr,
        128, 1024, 1024, 256, 128, 128, 524288, 1, 8, 1, 8);
    k_bias_res_ln<<<2048, 256, 0, stream>>>(Ypart, 8, 524288L, blk_b2 + d * 256, z, 2048,
        blk_ln2_g + d * 256, blk_ln2_b + d * 256, z, z_bf);
  }

  k_meancls<<<dim3(4, 4), 256, 0, stream>>>(z, cls_w, cls_b, out);
}

// Round 10
// 635.627 us; speedup vs baseline: 1.1083x; 1.0062x over previous
//
#include <hip/hip_runtime.h>
#include <hip/hip_bf16.h>
#include <math.h>

// Perceiver: B=4,C=3,N=4096,E=256,H=8,FFE=1024,L=512,D=4,NCLS=1000,HS=2048
// bf16 MFMA everywhere GEMM-shaped; fp32 accum; fp32 LN/residual spine.

typedef __attribute__((ext_vector_type(8))) short s8v;    // 8 bf16 = 4 VGPR
typedef __attribute__((ext_vector_type(4))) float f32x4;  // 16x16 MFMA accum
typedef __attribute__((ext_vector_type(16))) float f32x16;// 32x32 MFMA accum
typedef __attribute__((ext_vector_type(4))) unsigned u32x4;

__device__ __forceinline__ short f2b(float f) {
  union { float f; unsigned u; } a; a.f = f;
  unsigned r = a.u + 0x7fff + ((a.u >> 16) & 1);
  return (short)(r >> 16);
}
__device__ __forceinline__ float b2f(short s) {
  union { unsigned u; float f; } a; a.u = ((unsigned)(unsigned short)s) << 16;
  return a.f;
}
__device__ __forceinline__ unsigned cvtpk(float lo, float hi) {
  unsigned r;
  asm("v_cvt_pk_bf16_f32 %0, %1, %2" : "=v"(r) : "v"(lo), "v"(hi));
  return r;
}

// async global->LDS, 16B per lane; LDS dest = uniform base + lane*16
__device__ __forceinline__ void gl16(const void* gp, void* lp) {
  __builtin_amdgcn_global_load_lds(
      (const __attribute__((address_space(1))) unsigned int*)gp,
      (__attribute__((address_space(3))) unsigned int*)lp, 16, 0, 0);
}

// ------- tokens(bf16) = conv1x1(x)+bias+pos, writes tok AND tokT ---------
__global__ __launch_bounds__(256) void k_tokens2(
    const float* __restrict__ x, const float* __restrict__ cw,
    const float* __restrict__ cb, const float* __restrict__ pe,
    short* __restrict__ tok, short* __restrict__ tokT)
{
  int b = blockIdx.y, n0 = blockIdx.x * 32;
  int e = threadIdx.x;
  float c0 = cw[e * 3], c1 = cw[e * 3 + 1], c2 = cw[e * 3 + 2], cbv = cb[e];
  const float* xb = x + b * 12288 + n0;
  short acc[32];
#pragma unroll
  for (int i = 0; i < 32; ++i) {
    int n = n0 + i;
    float s = cbv + pe[n * 256 + e] + xb[i] * c0 + xb[4096 + i] * c1 + xb[8192 + i] * c2;
    short v = f2b(s);
    tok[((long)b * 4096 + n) * 256 + e] = v;
    acc[i] = v;
  }
  short* tr = tokT + ((long)b * 256 + e) * 4096 + n0;
#pragma unroll
  for (int i = 0; i < 4; ++i)
    *reinterpret_cast<s8v*>(tr + i * 8) = *reinterpret_cast<s8v*>(acc + i * 8);
}

// ---------------- batched weight prep: transposes + flat converts --------
struct TrJob {
  const float* src; short* dst;
  int R, C; long sIn, sOut;
  int mode, tilesPerZ, z, tileBase;
  float scale;
};
struct TrJobs { TrJob j[11]; };

__global__ __launch_bounds__(256) void k_trbatch(TrJobs jb, int njobs)
{
  __shared__ float t[32][33];
  int tb = blockIdx.x, ji = 0;
#pragma unroll
  for (int k = 1; k < 11; ++k)
    if (k < njobs && tb >= jb.j[k].tileBase) ji = k;
  TrJob J = jb.j[ji];
  int local = tb - J.tileBase;
  if (J.mode == 1) {          // flat fp32 -> bf16 (*scale)
    long o = (long)local * 8192 + threadIdx.x;
#pragma unroll
    for (int k = 0; k < 32; ++k)
      J.dst[o + k * 256] = f2b(J.src[o + k * 256] * J.scale);
    return;
  }
  int zi = local / J.tilesPerZ, ti = local - zi * J.tilesPerZ;
  int ntx = J.C >> 5;
  int tx = ti % ntx, ty = ti / ntx;
  const float* ib = J.src + (long)zi * J.sIn;
  short* ob = J.dst + (long)zi * J.sOut;
  int c0 = tx * 32, r0 = ty * 32;
  int lx = threadIdx.x & 31, ly = threadIdx.x >> 5;
#pragma unroll
  for (int i = 0; i < 4; ++i)
    t[ly * 4 + i][lx] = ib[(long)(r0 + ly * 4 + i) * J.C + c0 + lx];
  __syncthreads();
#pragma unroll
  for (int i = 0; i < 4; ++i)
    ob[(long)(c0 + ly * 4 + i) * J.R + r0 + lx] = f2b(t[lx][ly * 4 + i] * J.scale);
}

// ---------------- bf16 MFMA BT-GEMM: C = A(MxK) @ Bt(NxK)^T ----------------
// 128x128 tile, BK=32, 256 thr. Prefetch pipeline. Requires K % 64 == 0.
// EPI: 0 = bf16 out, 1 = bias+exact-gelu bf16 out, 2 = fp32 out (partials).
template<int EPI>
__global__ __launch_bounds__(256) void k_mgemm(
    const short* __restrict__ A, const short* __restrict__ Bt,
    void* __restrict__ Cv, const float* __restrict__ bias,
    int K, int lda, int ldb, int ldc,
    long sA, long sB, long sC, int zdA, int zmA, int zdB, int zmB)
{
  __shared__ char As[8192];
  __shared__ char Bs[8192];
  int z = blockIdx.z;
  const short* Ab = A + ((long)((z / zdA) % zmA)) * sA;
  const short* Bb = Bt + ((long)((z / zdB) % zmB)) * sB;
  int t = threadIdx.x;
  int lane = t & 63, w = t >> 6;
  int wr = w >> 1, wc = w & 1;
  int g = lane >> 4, l15 = lane & 15;
  long row0 = (long)blockIdx.y * 128, col0 = (long)blockIdx.x * 128;
  const f32x4 zz = {0.f, 0.f, 0.f, 0.f};
  f32x4 acc[4][4];
#pragma unroll
  for (int m = 0; m < 4; ++m)
#pragma unroll
    for (int n = 0; n < 4; ++n) acc[m][n] = zz;

  auto mload = [&](s8v* aa, s8v* bb, int kk) {
#pragma unroll
    for (int i = 0; i < 2; ++i) {
      int r = i * 64 + (t >> 2), c = t & 3;
      aa[i] = *(const s8v*)&Ab[(row0 + r) * (long)lda + kk + c * 8];
      bb[i] = *(const s8v*)&Bb[(col0 + r) * (long)ldb + kk + c * 8];
    }
  };
  auto mstore = [&](s8v* aa, s8v* bb) {
#pragma unroll
    for (int i = 0; i < 2; ++i) {
      int r = i * 64 + (t >> 2), c = t & 3;
      int off = (r * 64 + c * 16) ^ ((r & 7) << 4);
      *(s8v*)&As[off] = aa[i];
      *(s8v*)&Bs[off] = bb[i];
    }
  };
  auto mcomp = [&]() {
    s8v af[4], bfr[4];
#pragma unroll
    for (int m = 0; m < 4; ++m) {
      int r = wr * 64 + m * 16 + l15;
      af[m] = *(const s8v*)&As[(r * 64 + g * 16) ^ ((r & 7) << 4)];
    }
#pragma unroll
    for (int n = 0; n < 4; ++n) {
      int r = wc * 64 + n * 16 + l15;
      bfr[n] = *(const s8v*)&Bs[(r * 64 + g * 16) ^ ((r & 7) << 4)];
    }
#pragma unroll
    for (int m = 0; m < 4; ++m)
#pragma unroll
      for (int n = 0; n < 4; ++n)
        acc[m][n] = __builtin_amdgcn_mfma_f32_16x16x32_bf16(af[m], bfr[n], acc[m][n], 0, 0, 0);
  };

  s8v a0[2], b0[2], a1[2], b1[2];
  mload(a0, b0, 0);
  for (int k0 = 0; k0 < K; k0 += 64) {
    __syncthreads(); mstore(a0, b0); __syncthreads();
    mload(a1, b1, k0 + 32);
    mcomp();
    __syncthreads(); mstore(a1, b1); __syncthreads();
    if (k0 + 64 < K) mload(a0, b0, k0 + 64);
    mcomp();
  }

  long zo = (long)z * sC;
#pragma unroll
  for (int m = 0; m < 4; ++m)
#pragma unroll
    for (int n = 0; n < 4; ++n)
#pragma unroll
      for (int r = 0; r < 4; ++r) {
        long rr = row0 + wr * 64 + m * 16 + g * 4 + r;
        long cc = col0 + wc * 64 + n * 16 + l15;
        float v = acc[m][n][r];
        if (EPI == 1) {
          v += bias[cc];
          v = 0.5f * v * (1.f + erff(v * 0.70710678118654752f));
        }
        if (EPI == 2)
          ((float*)Cv)[zo + rr * ldc + cc] = v;
        else
          ((short*)Cv)[zo + rr * ldc + cc] = f2b(v);
      }
}

// ---------------- MFMA flash attention v9 (head dim 256, 32x32 MFMA) -----
// 8 waves x 32 q-rows, KVBLK=64, swapped QK^T, in-register softmax,
// DEFERRED-PV pipeline (T15): PV of tile i-1 runs in iter i, overlapping
// softmax VALU + QK LDS latency. Raw barriers + counted vmcnt (no drain).
// kv-split x4 to partials; coalesced Opart epilogue via LDS bounce.
__global__ __launch_bounds__(512, 2) void k_mflash9(
    const short* __restrict__ Qp, const short* __restrict__ Kp,
    const short* __restrict__ Vtp, short* __restrict__ Opart,
    float* __restrict__ MLp,
    int nk, int ldq, int ldk, int ldvt,
    long qh, long qb, long kh, long kb, long vh, long vb)
{
  __shared__ char pool[131072];  // 2 x (K 32KB + V 32KB)
  int t = threadIdx.x, lane = t & 63, w = t >> 6;
  int l31 = lane & 31, hi = lane >> 5;
  int h = blockIdx.y, b = blockIdx.z;
  int kv = blockIdx.x & 3, qblk = blockIdx.x >> 2;
  const short* Q  = Qp  + (long)h * qh + (long)b * qb;
  const short* Kg = Kp  + (long)h * kh + (long)b * kb;
  const short* Vg = Vtp + (long)h * vh + (long)b * vb;
  int q0w = qblk * 256 + w * 32;
  int nkq = nk >> 2;
  int NIT = nkq >> 6;           // KVBLK = 64
  long k0 = (long)kv * nkq;

  // Q B-frags: lane = q-col (l31), k = hi*8+j within d-slice s
  s8v qf[16];
  {
    const short* Qrow = Q + (long)(q0w + l31) * ldq + hi * 8;
#pragma unroll
    for (int s = 0; s < 16; ++s) qf[s] = *(const s8v*)(Qrow + s * 16);
  }

  // staging byte-offsets (32-bit; linear LDS dest + inverse-swizzled source)
  const char* KgB = (const char*)Kg;
  const char* VgB = (const char*)Vg;
  unsigned koff[4], voff[4];
#pragma unroll
  for (int c = 0; c < 4; ++c) {
    int r = 8 * w + 2 * c + hi;                 // K tile row 0..63
    koff[c] = (unsigned)((k0 + r) * (long)ldk * 2) + ((l31 ^ (r & 31)) << 4);
    int rv = 32 * w + 8 * c + (lane >> 3);      // V tile row 0..255
    voff[c] = (unsigned)(((long)rv * ldvt + k0) * 2) + (((lane & 7) ^ (lane >> 3)) << 4);
  }
  const unsigned kStep = (unsigned)(64 * ldk * 2);

  auto stage = [&](int bsel) {   // K loads first, then V (vmcnt queue order)
    char* kd = pool + bsel * 65536 + (w << 12);
    char* vd = kd + 32768;
#pragma unroll
    for (int c = 0; c < 4; ++c) { gl16(KgB + koff[c], kd + c * 1024); koff[c] += kStep; }
#pragma unroll
    for (int c = 0; c < 4; ++c) { gl16(VgB + voff[c], vd + c * 1024); voff[c] += 128; }
  };

  f32x16 accO[8];
#pragma unroll
  for (int n = 0; n < 8; ++n)
#pragma unroll
    for (int i = 0; i < 16; ++i) accO[n][i] = 0.f;
  float mrow = -1e30f, lrow = 0.f;
  s8v paP[4];                     // P A-frags of previous iter (deferred PV)

  stage(0);

  for (int it = 0; it < NIT; ++it) {
    int cur = it & 1;
    // drain V[it-1] + K[it]; V[it] (newest 4) stays in flight
    asm volatile("s_waitcnt vmcnt(4)" ::: "memory");
    __builtin_amdgcn_s_barrier();
    __builtin_amdgcn_sched_barrier(0);
    const char* kls  = pool + cur * 65536;            // K[it]
    const char* vlsP = pool + (cur ^ 1) * 65536 + 32768; // V[it-1]

    // QK[it]: S^T = mfma(K, Q), 2 M-tiles x 16 d-slices
    f32x16 sacc[2];
#pragma unroll
    for (int i = 0; i < 16; ++i) { sacc[0][i] = 0.f; sacc[1][i] = 0.f; }
    __builtin_amdgcn_s_setprio(1);
#pragma unroll
    for (int tt = 0; tt < 2; ++tt) {
      int r = tt * 32 + l31;
#pragma unroll
      for (int s = 0; s < 16; ++s) {
        s8v kf = *(const s8v*)&kls[r * 512 + (((2 * s + hi) ^ l31) << 4)];
        sacc[tt] = __builtin_amdgcn_mfma_f32_32x32x16_bf16(kf, qf[s], sacc[tt], 0, 0, 0);
      }
    }
    // PV[it-1]: independent MFMA stream, overlaps softmax below
    if (it > 0) {
#pragma unroll
      for (int n = 0; n < 8; ++n) {
        int rv = n * 32 + l31;
#pragma unroll
        for (int s2 = 0; s2 < 4; ++s2) {
          s8v vf = *(const s8v*)&vlsP[rv * 128 + (((2 * s2 + hi) ^ (l31 & 7)) << 4)];
          accO[n] = __builtin_amdgcn_mfma_f32_32x32x16_bf16(paP[s2], vf, accO[n], 0, 0, 0);
        }
      }
    }
    __builtin_amdgcn_s_setprio(0);

    // all own ds_reads retired -> buffers (cur^1) safe to overwrite after bar
    asm volatile("s_waitcnt lgkmcnt(0)" ::: "memory");
    __builtin_amdgcn_sched_barrier(0);
    __builtin_amdgcn_s_barrier();
    if (it + 1 < NIT) stage(cur ^ 1);   // K[it+1],V[it+1] in flight over softmax

    // in-register softmax over 64 k (32 local + 32 in partner half)
    float mt = sacc[0][0];
#pragma unroll
    for (int i = 1; i < 16; ++i) mt = fmaxf(mt, sacc[0][i]);
#pragma unroll
    for (int i = 0; i < 16; ++i) mt = fmaxf(mt, sacc[1][i]);
    mt = fmaxf(mt, __shfl_xor(mt, 32));
    if (__any(mt - mrow > 8.f)) {       // defer-max (T13)
      float mn = fmaxf(mrow, mt);
      float al = __expf(mrow - mn);
      mrow = mn; lrow *= al;
#pragma unroll
      for (int r = 0; r < 16; ++r) {
        float alr = __shfl(al, (r & 3) + 8 * (r >> 2) + 4 * hi);
#pragma unroll
        for (int n = 0; n < 8; ++n) accO[n][r] *= alr;
      }
    }
    float ls = 0.f;
#pragma unroll
    for (int tt = 0; tt < 2; ++tt)
#pragma unroll
      for (int i = 0; i < 16; ++i) {
        float p = __expf(sacc[tt][i] - mrow);
        sacc[tt][i] = p; ls += p;
      }
    ls += __shfl_xor(ls, 32);
    lrow += ls;

    // PV A-frags for THIS tile (consumed next iter): cvt_pk + half exchange
#pragma unroll
    for (int s = 0; s < 4; ++s) {
      int tt = s >> 1, r0 = (s & 1) * 8;
      unsigned w0 = cvtpk(sacc[tt][r0 + 0], sacc[tt][r0 + 1]);
      unsigned w1 = cvtpk(sacc[tt][r0 + 2], sacc[tt][r0 + 3]);
      unsigned w2 = cvtpk(sacc[tt][r0 + 4], sacc[tt][r0 + 5]);
      unsigned w3 = cvtpk(sacc[tt][r0 + 6], sacc[tt][r0 + 7]);
      unsigned x0 = (unsigned)__shfl_xor((int)w0, 32);
      unsigned x1 = (unsigned)__shfl_xor((int)w1, 32);
      unsigned x2 = (unsigned)__shfl_xor((int)w2, 32);
      unsigned x3 = (unsigned)__shfl_xor((int)w3, 32);
      u32x4 pw;
      pw.x = hi ? x2 : w0;
      pw.y = hi ? x3 : w1;
      pw.z = hi ? w2 : x0;
      pw.w = hi ? w3 : x1;
      paP[s] = *(s8v*)&pw;
    }
  }

  // final PV[NIT-1]
  asm volatile("s_waitcnt vmcnt(0)" ::: "memory");
  __builtin_amdgcn_s_barrier();
  __builtin_amdgcn_sched_barrier(0);
  {
    const char* vls = pool + ((NIT - 1) & 1) * 65536 + 32768;
    __builtin_amdgcn_s_setprio(1);
#pragma unroll
    for (int n = 0; n < 8; ++n) {
      int rv = n * 32 + l31;
#pragma unroll
      for (int s2 = 0; s2 < 4; ++s2) {
        s8v vf = *(const s8v*)&vls[rv * 128 + (((2 * s2 + hi) ^ (l31 & 7)) << 4)];
        accO[n] = __builtin_amdgcn_mfma_f32_32x32x16_bf16(paP[s2], vf, accO[n], 0, 0, 0);
      }
    }
    __builtin_amdgcn_s_setprio(0);
  }

  // ---- epilogue: ML + coalesced Opart via LDS bounce (K area is dead) ----
  long prow = (((long)kv * 4 + b) * 8 + h) * 512;
  short* Ob = Opart + prow * 256;
  float* MLb = MLp + prow * 2;
  if (lane < 32) {
    MLb[(q0w + l31) * 2] = mrow;
    MLb[(q0w + l31) * 2 + 1] = lrow;
  }
  float* st = (float*)(pool + w * 4096);   // wave-private 4KB in K[0] slot
  int orow = lane >> 1, ohalf = lane & 1;
#pragma unroll
  for (int n = 0; n < 8; ++n) {
#pragma unroll
    for (int r = 0; r < 16; ++r) {
      int ql = (r & 3) + 8 * (r >> 2) + 4 * hi;
      st[ql * 32 + l31] = accO[n][r];
    }
    short obuf[16];
#pragma unroll
    for (int jj = 0; jj < 4; ++jj) {
      f32x4 v = *(const f32x4*)&st[orow * 32 + ohalf * 16 + jj * 4];
      obuf[jj * 4 + 0] = f2b(v.x); obuf[jj * 4 + 1] = f2b(v.y);
      obuf[jj * 4 + 2] = f2b(v.z); obuf[jj * 4 + 3] = f2b(v.w);
    }
    short* dst = Ob + (long)(q0w + orow) * 256 + n * 32 + ohalf * 16;
    *(s8v*)(dst) = *(s8v*)&obuf[0];
    *(s8v*)(dst + 8) = *(s8v*)&obuf[8];
  }
}

// ---------------- combine 4 kv partials -> bufO bf16 ----------------
__global__ __launch_bounds__(512) void k_fcomb(
    const short* __restrict__ Op, const float* __restrict__ ML,
    short* __restrict__ O)
{
  int d = threadIdx.x & 255;
  int q = blockIdx.x * 2 + (threadIdx.x >> 8);
  int h = blockIdx.y, b = blockIdx.z;
  const long kvs = 4L * 8 * 512;  // rows per kv slice
  long r0 = ((long)b * 8 + h) * 512 + q;
  float mm[4], ll[4], m = -1e30f;
#pragma unroll
  for (int kv = 0; kv < 4; ++kv) {
    mm[kv] = ML[(kv * kvs + r0) * 2];
    ll[kv] = ML[(kv * kvs + r0) * 2 + 1];
    m = fmaxf(m, mm[kv]);
  }
  float wv[4], lsum = 0.f;
#pragma unroll
  for (int kv = 0; kv < 4; ++kv) { wv[kv] = __expf(mm[kv] - m); lsum += ll[kv] * wv[kv]; }
  float inv = 1.f / lsum, acc = 0.f;
#pragma unroll
  for (int kv = 0; kv < 4; ++kv)
    acc += b2f(Op[(kv * kvs + r0) * 256 + d]) * wv[kv];
  O[(long)b * 1048576 + (long)q * 2048 + h * 256 + d] = f2b(acc * inv);
}

// ---------------- z = LN(sum(Ypart) + bias + res) ----------------
__global__ __launch_bounds__(256) void k_bias_res_ln(
    const float* __restrict__ Yp, int nPart, long pStride,
    const float* __restrict__ bias,
    const float* __restrict__ res, int resMod,
    const float* __restrict__ g, const float* __restrict__ bta,
    float* __restrict__ out, short* __restrict__ out_bf)
{
  __shared__ float red[4];
  int row = blockIdx.x, e = threadIdx.x;
  float v = bias[e] + res[(long)(row % resMod) * 256 + e];
  for (int s = 0; s < nPart; ++s) v += Yp[s * pStride + (long)row * 256 + e];
  float s1 = v;
#pragma unroll
  for (int o = 32; o > 0; o >>= 1) s1 += __shfl_down(s1, o);
  if ((e & 63) == 0) red[e >> 6] = s1;
  __syncthreads();
  float mean = (red[0] + red[1] + red[2] + red[3]) * (1.f / 256.f);
  float d = v - mean;
  __syncthreads();
  float s2 = d * d;
#pragma unroll
  for (int o = 32; o > 0; o >>= 1) s2 += __shfl_down(s2, o);
  if ((e & 63) == 0) red[e >> 6] = s2;
  __syncthreads();
  float var = (red[0] + red[1] + red[2] + red[3]) * (1.f / 256.f);
  float o = g[e] * d * rsqrtf(var + 1e-5f) + bta[e];
  out[(long)row * 256 + e] = o;
  out_bf[(long)row * 256 + e] = f2b(o);
}

// ---------------- fused mean-over-latents + classifier ----------------
__global__ __launch_bounds__(256) void k_meancls(
    const float* __restrict__ z, const float* __restrict__ w,
    const float* __restrict__ bias, float* __restrict__ out)
{
  __shared__ float zms[256];
  int b = blockIdx.y, e = threadIdx.x;
  float s = 0.f;
  for (int l = 0; l < 512; ++l) s += z[((long)b * 512 + l) * 256 + e];
  zms[e] = s * (1.f / 512.f);
  __syncthreads();
  int j = blockIdx.x * 256 + e;
  if (j >= 1000) return;
  float acc = bias[j];
  for (int e2 = 0; e2 < 256; ++e2) acc += zms[e2] * w[e2 * 1000 + j];
  out[b * 1000 + j] = acc;
}

extern "C" void kernel_launch(void* const* d_in, const int* in_sizes, int n_in,
                              void* d_out, int out_size, void* d_ws, size_t ws_size,
                              hipStream_t stream)
{
  (void)in_sizes; (void)n_in; (void)out_size; (void)ws_size;
  const float* x       = (const float*)d_in[0];
  const float* conv_w  = (const float*)d_in[1];
  const float* conv_b  = (const float*)d_in[2];
  const float* pos_emb = (const float*)d_in[3];
  const float* latents = (const float*)d_in[4];
  const float* ca_wq   = (const float*)d_in[5];
  const float* ca_wk   = (const float*)d_in[6];
  const float* ca_wv   = (const float*)d_in[7];
  const float* ca_wu   = (const float*)d_in[8];
  const float* ca_bu   = (const float*)d_in[9];
  const float* ca_ln_g = (const float*)d_in[10];
  const float* ca_ln_b = (const float*)d_in[11];
  const float* blk_wq  = (const float*)d_in[12];
  const float* blk_wk  = (const float*)d_in[13];
  const float* blk_wv  = (const float*)d_in[14];
  const float* blk_wu  = (const float*)d_in[15];
  const float* blk_bu  = (const float*)d_in[16];
  const float* blk_ln1_g = (const float*)d_in[17];
  const float* blk_ln1_b = (const float*)d_in[18];
  const float* blk_w1  = (const float*)d_in[19];
  const float* blk_b1  = (const float*)d_in[20];
  const float* blk_w2  = (const float*)d_in[21];
  const float* blk_b2  = (const float*)d_in[22];
  const float* blk_ln2_g = (const float*)d_in[23];
  const float* blk_ln2_b = (const float*)d_in[24];
  const float* cls_w   = (const float*)d_in[25];
  const float* cls_b   = (const float*)d_in[26];
  float* out = (float*)d_out;

  // ---- workspace layout (bf16 as short) ----
  short* wqT_ca = (short*)d_ws;            // 2048x256 (scaled)
  short* wkT_ca = wqT_ca + 524288;         // 2048x256
  short* wuT_ca = wkT_ca + 524288;         // 256x2048
  short* wv_ca  = wuT_ca + 524288;         // 256x2048
  short* lat_bf = wv_ca + 524288;          // 512x256
  short* wqkT   = lat_bf + 131072;         // 4 x (4096x256)
  short* wvT    = wqkT + 4194304;          // 4 x (2048x256)
  short* wuT_b  = wvT + 2097152;           // 4 x (256x2048)
  short* w1T    = wuT_b + 2097152;         // 4 x (1024x256)
  short* w2T    = w1T + 1048576;           // 4 x (256x1024)
  short* tok_bf = w2T + 1048576;           // 4 x 4096x256
  short* tokT   = tok_bf + 4194304;        // 4 x 256x4096
  short* qCA    = tokT + 4194304;          // 512x2048
  short* qtil   = qCA + 1048576;           // 8 x 512x256
  short* MstT   = qtil + 1048576;          // 256x2048
  short* VtB    = MstT + 524288;           // 32 x 256x512
  short* bufO   = VtB + 4194304;           // 4 x 512x2048
  short* h1     = bufO + 4194304;          // 2048x1024
  short* z_bf   = h1 + 2097152;            // 2048x256
  float* z      = (float*)(z_bf + 524288); // 2048x256 fp32
  float* zm     = z + 524288;              // spare
  float* Ypart  = zm + 1024;               // 8 x 2048x256 fp32 (split-K partials)
  short* Opart  = (short*)(Ypart + 4194304); // 4 x (4x8x512x256) bf16 kv-partials
  float* MLp    = (float*)(Opart + 16777216); // 4 x (4x8x512x2) fp32
  short* QKb    = tok_bf;                  // alias: 2048x4096 (after CA)

  const float scale = 0.17677669529663687f; // 1/sqrt(32), folded into Wq
  const int BIG = 1 << 30;

  // ---- weight prep: one batched dispatch (Wq pre-scaled) ----
  TrJobs JB; int nj = 0, base = 0;
  auto addT = [&](const float* s, short* d, int R, int C, long sIn, long sOut,
                  int zc, float sc) {
    int tpz = (C >> 5) * (R >> 5);
    JB.j[nj] = {s, d, R, C, sIn, sOut, 0, tpz, zc, base, sc};
    base += tpz * zc; ++nj;
  };
  auto addC = [&](const float* s, short* d, int nelem) {
    int tpz = nelem >> 13;
    JB.j[nj] = {s, d, 0, 0, 0, 0, 1, tpz, 1, base, 1.f};
    base += tpz; ++nj;
  };
  addT(ca_wq, wqT_ca, 256, 2048, 0, 0, 1, scale);
  addT(ca_wk, wkT_ca, 256, 2048, 0, 0, 1, 1.f);
  addT(ca_wu, wuT_ca, 2048, 256, 0, 0, 1, 1.f);
  addT(blk_wq, wqkT, 256, 2048, 524288, 1048576, 4, scale);
  addT(blk_wk, wqkT + 524288, 256, 2048, 524288, 1048576, 4, 1.f);
  addT(blk_wv, wvT, 256, 2048, 524288, 524288, 4, 1.f);
  addT(blk_wu, wuT_b, 2048, 256, 524288, 524288, 4, 1.f);
  addT(blk_w1, w1T, 256, 1024, 262144, 262144, 4, 1.f);
  addT(blk_w2, w2T, 1024, 256, 262144, 262144, 4, 1.f);
  addC(ca_wv, wv_ca, 524288);
  addC(latents, lat_bf, 131072);
  k_trbatch<<<base, 256, 0, stream>>>(JB, nj);

  // ---- tokens (both layouts, one pass) ----
  k_tokens2<<<dim3(128, 4), 256, 0, stream>>>(x, conv_w, conv_b, pos_emb,
                                              tok_bf, tokT);

  // ---- cross-attention (W_K folded into Q; W_V*W_U folded into MstT) ----
  k_mgemm<0><<<dim3(16, 4, 1), 256, 0, stream>>>(
      lat_bf, wqT_ca, qCA, nullptr, 256, 256, 256, 2048, 0, 0, 0, 1, BIG, 1, BIG);
  k_mgemm<0><<<dim3(2, 4, 8), 256, 0, stream>>>(
      qCA, wkT_ca, qtil, nullptr, 256, 2048, 256, 256, 256, 65536, 131072, 1, 8, 1, 8);
  k_mgemm<0><<<dim3(2, 2, 8), 256, 0, stream>>>(
      wuT_ca, wv_ca, MstT, nullptr, 256, 2048, 2048, 2048, 256, 256, 256, 1, 8, 1, 8);
  // CA flash: Q=qtilde(h) [pre-scaled], K=tokens(b), Vt=tokensT(b)
  k_mflash9<<<dim3(8, 8, 4), 512, 0, stream>>>(
      qtil, tok_bf, tokT, Opart, MLp, 4096, 256, 256, 4096,
      131072L, 0L, 0L, 1048576L, 0L, 1048576L);
  k_fcomb<<<dim3(256, 8, 4), 512, 0, stream>>>(Opart, MLp, bufO);
  // Y = bufO(2048x2048) @ MstT^T, split-K x8 -> fp32 partials
  k_mgemm<2><<<dim3(2, 16, 8), 256, 0, stream>>>(
      bufO, MstT, Ypart, nullptr, 256, 2048, 2048, 256, 256, 256, 524288, 1, 8, 1, 8);
  k_bias_res_ln<<<2048, 256, 0, stream>>>(Ypart, 8, 524288L, ca_bu, latents, 512,
                                          ca_ln_g, ca_ln_b, z, z_bf);

  // ---- transformer blocks ----
  for (int d = 0; d < 4; ++d) {
    // [Q|K] = z @ [scale*wq wk]  -> QKb (2048 x 4096) bf16
    k_mgemm<0><<<dim3(32, 16, 1), 256, 0, stream>>>(
        z_bf, wqkT + (long)d * 1048576, QKb, nullptr,
        256, 256, 256, 4096, 0, 0, 0, 1, BIG, 1, BIG);
    // Vt(b,h) = wvT_h @ z_b^T  (256 x 512)
    k_mgemm<0><<<dim3(4, 2, 32), 256, 0, stream>>>(
        wvT + (long)d * 524288, z_bf, VtB, nullptr,
        256, 256, 256, 512, 65536, 131072, 131072, 1, 8, 8, BIG);
    // self flash
    k_mflash9<<<dim3(8, 8, 4), 512, 0, stream>>>(
        QKb, QKb + 2048, VtB, Opart, MLp, 512, 4096, 4096, 512,
        256L, 2097152L, 256L, 2097152L, 131072L, 1048576L);
    k_fcomb<<<dim3(256, 8, 4), 512, 0, stream>>>(Opart, MLp, bufO);
    // Y = bufO @ wu^T, split-K x8 -> fp32 partials
    k_mgemm<2><<<dim3(2, 16, 8), 256, 0, stream>>>(
        bufO, wuT_b + (long)d * 524288, Ypart, nullptr,
        256, 2048, 2048, 256, 256, 256, 524288, 1, 8, 1, 8);
    k_bias_res_ln<<<2048, 256, 0, stream>>>(Ypart, 8, 524288L, blk_bu + d * 256, z, 2048,
        blk_ln1_g + d * 256, blk_ln1_b + d * 256, z, z_bf);
    // h1 = gelu(z @ w1 + b1)
    k_mgemm<1><<<dim3(8, 16, 1), 256, 0, stream>>>(
        z_bf, w1T + (long)d * 262144, h1, blk_b1 + d * 1024,
        256, 256, 256, 1024, 0, 0, 0, 1, BIG, 1, BIG);
    // Y = h1 @ w2, split-K x8 (Ksub=128) -> fp32 partials
    k_mgemm<2><<<dim3(2, 16, 8), 256, 0, stream>>>(
        h1, w2T + (long)d * 262144, Ypart, nullptr,
        128, 1024, 1024, 256, 128, 128, 524288, 1, 8, 1, 8);
    k_bias_res_ln<<<2048, 256, 0, stream>>>(Ypart, 8, 524288L, blk_b2 + d * 256, z, 2048,
        blk_ln2_g + d * 256, blk_ln2_b + d * 256, z, z_bf);
  }

  k_meancls<<<dim3(4, 4), 256, 0, stream>>>(z, cls_w, cls_b, out);
}

// Round 11
// 595.549 us; speedup vs baseline: 1.1829x; 1.0673x over previous
//
#include <hip/hip_runtime.h>
#include <hip/hip_bf16.h>
#include <math.h>

// Perceiver: B=4,C=3,N=4096,E=256,H=8,FFE=1024,L=512,D=4,NCLS=1000,HS=2048
// bf16 MFMA everywhere GEMM-shaped; fp32 accum; fp32 LN/residual spine.

typedef __attribute__((ext_vector_type(8))) short s8v;    // 8 bf16 = 4 VGPR
typedef __attribute__((ext_vector_type(4))) float f32x4;  // 16x16 MFMA accum
typedef __attribute__((ext_vector_type(16))) float f32x16;// 32x32 MFMA accum
typedef __attribute__((ext_vector_type(4))) unsigned u32x4;

__device__ __forceinline__ short f2b(float f) {
  union { float f; unsigned u; } a; a.f = f;
  unsigned r = a.u + 0x7fff + ((a.u >> 16) & 1);
  return (short)(r >> 16);
}
__device__ __forceinline__ float b2f(short s) {
  union { unsigned u; float f; } a; a.u = ((unsigned)(unsigned short)s) << 16;
  return a.f;
}
__device__ __forceinline__ unsigned cvtpk(float lo, float hi) {
  unsigned r;
  asm("v_cvt_pk_bf16_f32 %0, %1, %2" : "=v"(r) : "v"(lo), "v"(hi));
  return r;
}

// async global->LDS, 16B per lane; LDS dest = uniform base + lane*16
__device__ __forceinline__ void gl16(const void* gp, void* lp) {
  __builtin_amdgcn_global_load_lds(
      (const __attribute__((address_space(1))) unsigned int*)gp,
      (__attribute__((address_space(3))) unsigned int*)lp, 16, 0, 0);
}

// ------- tokens(bf16) = conv1x1(x)+bias+pos, writes tok AND tokT ---------
__global__ __launch_bounds__(256) void k_tokens2(
    const float* __restrict__ x, const float* __restrict__ cw,
    const float* __restrict__ cb, const float* __restrict__ pe,
    short* __restrict__ tok, short* __restrict__ tokT)
{
  int b = blockIdx.y, n0 = blockIdx.x * 32;
  int e = threadIdx.x;
  float c0 = cw[e * 3], c1 = cw[e * 3 + 1], c2 = cw[e * 3 + 2], cbv = cb[e];
  const float* xb = x + b * 12288 + n0;
  short acc[32];
#pragma unroll
  for (int i = 0; i < 32; ++i) {
    int n = n0 + i;
    float s = cbv + pe[n * 256 + e] + xb[i] * c0 + xb[4096 + i] * c1 + xb[8192 + i] * c2;
    short v = f2b(s);
    tok[((long)b * 4096 + n) * 256 + e] = v;
    acc[i] = v;
  }
  short* tr = tokT + ((long)b * 256 + e) * 4096 + n0;
#pragma unroll
  for (int i = 0; i < 4; ++i)
    *reinterpret_cast<s8v*>(tr + i * 8) = *reinterpret_cast<s8v*>(acc + i * 8);
}

// ---------------- batched weight prep: transposes + flat converts --------
struct TrJob {
  const float* src; short* dst;
  int R, C; long sIn, sOut;
  int mode, tilesPerZ, z, tileBase;
  float scale;
};
struct TrJobs { TrJob j[11]; };

__global__ __launch_bounds__(256) void k_trbatch(TrJobs jb, int njobs)
{
  __shared__ float t[32][33];
  int tb = blockIdx.x, ji = 0;
#pragma unroll
  for (int k = 1; k < 11; ++k)
    if (k < njobs && tb >= jb.j[k].tileBase) ji = k;
  TrJob J = jb.j[ji];
  int local = tb - J.tileBase;
  if (J.mode == 1) {          // flat fp32 -> bf16 (*scale)
    long o = (long)local * 8192 + threadIdx.x;
#pragma unroll
    for (int k = 0; k < 32; ++k)
      J.dst[o + k * 256] = f2b(J.src[o + k * 256] * J.scale);
    return;
  }
  int zi = local / J.tilesPerZ, ti = local - zi * J.tilesPerZ;
  int ntx = J.C >> 5;
  int tx = ti % ntx, ty = ti / ntx;
  const float* ib = J.src + (long)zi * J.sIn;
  short* ob = J.dst + (long)zi * J.sOut;
  int c0 = tx * 32, r0 = ty * 32;
  int lx = threadIdx.x & 31, ly = threadIdx.x >> 5;
#pragma unroll
  for (int i = 0; i < 4; ++i)
    t[ly * 4 + i][lx] = ib[(long)(r0 + ly * 4 + i) * J.C + c0 + lx];
  __syncthreads();
#pragma unroll
  for (int i = 0; i < 4; ++i)
    ob[(long)(c0 + ly * 4 + i) * J.R + r0 + lx] = f2b(t[lx][ly * 4 + i] * J.scale);
}

// ---------------- bf16 MFMA BT-GEMM: C = A(MxK) @ Bt(NxK)^T ----------------
// 128x128 tile, BK=32, 256 thr. Prefetch pipeline. Requires K % 64 == 0.
// EPI: 0 = bf16 out, 1 = bias+exact-gelu bf16 out, 2 = fp32 out (partials).
template<int EPI>
__global__ __launch_bounds__(256) void k_mgemm(
    const short* __restrict__ A, const short* __restrict__ Bt,
    void* __restrict__ Cv, const float* __restrict__ bias,
    int K, int lda, int ldb, int ldc,
    long sA, long sB, long sC, int zdA, int zmA, int zdB, int zmB)
{
  __shared__ char As[8192];
  __shared__ char Bs[8192];
  int z = blockIdx.z;
  const short* Ab = A + ((long)((z / zdA) % zmA)) * sA;
  const short* Bb = Bt + ((long)((z / zdB) % zmB)) * sB;
  int t = threadIdx.x;
  int lane = t & 63, w = t >> 6;
  int wr = w >> 1, wc = w & 1;
  int g = lane >> 4, l15 = lane & 15;
  long row0 = (long)blockIdx.y * 128, col0 = (long)blockIdx.x * 128;
  const f32x4 zz = {0.f, 0.f, 0.f, 0.f};
  f32x4 acc[4][4];
#pragma unroll
  for (int m = 0; m < 4; ++m)
#pragma unroll
    for (int n = 0; n < 4; ++n) acc[m][n] = zz;

  auto mload = [&](s8v* aa, s8v* bb, int kk) {
#pragma unroll
    for (int i = 0; i < 2; ++i) {
      int r = i * 64 + (t >> 2), c = t & 3;
      aa[i] = *(const s8v*)&Ab[(row0 + r) * (long)lda + kk + c * 8];
      bb[i] = *(const s8v*)&Bb[(col0 + r) * (long)ldb + kk + c * 8];
    }
  };
  auto mstore = [&](s8v* aa, s8v* bb) {
#pragma unroll
    for (int i = 0; i < 2; ++i) {
      int r = i * 64 + (t >> 2), c = t & 3;
      int off = (r * 64 + c * 16) ^ ((r & 7) << 4);
      *(s8v*)&As[off] = aa[i];
      *(s8v*)&Bs[off] = bb[i];
    }
  };
  auto mcomp = [&]() {
    s8v af[4], bfr[4];
#pragma unroll
    for (int m = 0; m < 4; ++m) {
      int r = wr * 64 + m * 16 + l15;
      af[m] = *(const s8v*)&As[(r * 64 + g * 16) ^ ((r & 7) << 4)];
    }
#pragma unroll
    for (int n = 0; n < 4; ++n) {
      int r = wc * 64 + n * 16 + l15;
      bfr[n] = *(const s8v*)&Bs[(r * 64 + g * 16) ^ ((r & 7) << 4)];
    }
#pragma unroll
    for (int m = 0; m < 4; ++m)
#pragma unroll
      for (int n = 0; n < 4; ++n)
        acc[m][n] = __builtin_amdgcn_mfma_f32_16x16x32_bf16(af[m], bfr[n], acc[m][n], 0, 0, 0);
  };

  s8v a0[2], b0[2], a1[2], b1[2];
  mload(a0, b0, 0);
  for (int k0 = 0; k0 < K; k0 += 64) {
    __syncthreads(); mstore(a0, b0); __syncthreads();
    mload(a1, b1, k0 + 32);
    mcomp();
    __syncthreads(); mstore(a1, b1); __syncthreads();
    if (k0 + 64 < K) mload(a0, b0, k0 + 64);
    mcomp();
  }

  long zo = (long)z * sC;
#pragma unroll
  for (int m = 0; m < 4; ++m)
#pragma unroll
    for (int n = 0; n < 4; ++n)
#pragma unroll
      for (int r = 0; r < 4; ++r) {
        long rr = row0 + wr * 64 + m * 16 + g * 4 + r;
        long cc = col0 + wc * 64 + n * 16 + l15;
        float v = acc[m][n][r];
        if (EPI == 1) {
          v += bias[cc];
          v = 0.5f * v * (1.f + erff(v * 0.70710678118654752f));
        }
        if (EPI == 2)
          ((float*)Cv)[zo + rr * ldc + cc] = v;
        else
          ((short*)Cv)[zo + rr * ldc + cc] = f2b(v);
      }
}

// ---------------- MFMA flash attention v10 (head dim 256, 32x32 MFMA) ----
// 4 waves x 32 q-rows = 128 q/block, KVBLK=32, LDS 64KB -> 2 independent
// blocks/CU (decoupled barrier domains fill each other's stalls). Swapped
// QK^T, in-register softmax, P->PV frags via cvt_pk + cross-half shfl.
// kv-split x4 to partials; coalesced Opart epilogue via LDS bounce.
__global__ __launch_bounds__(256, 2) void k_mflash10(
    const short* __restrict__ Qp, const short* __restrict__ Kp,
    const short* __restrict__ Vtp, short* __restrict__ Opart,
    float* __restrict__ MLp,
    int nk, int ldq, int ldk, int ldvt,
    long qh, long qb, long kh, long kb, long vh, long vb)
{
  __shared__ char pool[65536];  // 2 x (K 16KB + V 16KB)
  int t = threadIdx.x, lane = t & 63, w = t >> 6;   // w = 0..3
  int l31 = lane & 31, hi = lane >> 5;
  int h = blockIdx.y, b = blockIdx.z;
  int kv = blockIdx.x & 3, qblk = blockIdx.x >> 2;
  const short* Q  = Qp  + (long)h * qh + (long)b * qb;
  const short* Kg = Kp  + (long)h * kh + (long)b * kb;
  const short* Vg = Vtp + (long)h * vh + (long)b * vb;
  int q0w = qblk * 128 + w * 32;
  int nkq = nk >> 2;
  int NIT = nkq >> 5;           // KVBLK = 32
  long k0 = (long)kv * nkq;

  // Q B-frags: lane = q-col (l31), k = hi*8+j within d-slice s
  s8v qf[16];
  {
    const short* Qrow = Q + (long)(q0w + l31) * ldq + hi * 8;
#pragma unroll
    for (int s = 0; s < 16; ++s) qf[s] = *(const s8v*)(Qrow + s * 16);
  }

  // staging byte-offsets (linear LDS dest + inverse-swizzled source)
  const char* KgB = (const char*)Kg;
  const char* VgB = (const char*)Vg;
  unsigned koff[4], voff[4];
#pragma unroll
  for (int c = 0; c < 4; ++c) {
    int r = 8 * w + 2 * c + hi;                 // K tile row 0..31
    koff[c] = (unsigned)((k0 + r) * (long)ldk * 2) + ((l31 ^ r) << 4);
    int rv = 64 * w + 16 * c + (lane >> 2);     // V tile row 0..255
    voff[c] = (unsigned)(((long)rv * ldvt + k0) * 2)
              + (((lane & 3) ^ ((lane >> 3) & 3)) << 4);
  }
  const unsigned kStep = (unsigned)(32 * ldk * 2);

  auto stage = [&](int bsel) {
    char* kd = pool + bsel * 32768 + (w << 12);
    char* vd = kd + 16384;
#pragma unroll
    for (int c = 0; c < 4; ++c) { gl16(KgB + koff[c], kd + c * 1024); koff[c] += kStep; }
#pragma unroll
    for (int c = 0; c < 4; ++c) { gl16(VgB + voff[c], vd + c * 1024); voff[c] += 64; }
  };

  f32x16 accO[8];
#pragma unroll
  for (int n = 0; n < 8; ++n)
#pragma unroll
    for (int i = 0; i < 16; ++i) accO[n][i] = 0.f;
  float mrow = -1e30f, lrow = 0.f;

  stage(0);

  for (int it = 0; it < NIT; ++it) {
    int cur = it & 1;
    asm volatile("s_waitcnt vmcnt(0)" ::: "memory");
    __syncthreads();
    if (it + 1 < NIT) stage(cur ^ 1);
    const char* kls = pool + cur * 32768;
    const char* vls = kls + 16384;

    // S^T = mfma(K, Q): one 32x32 tile over 16 d-slices; C col=q, row=k
    f32x16 sacc;
#pragma unroll
    for (int i = 0; i < 16; ++i) sacc[i] = 0.f;
    __builtin_amdgcn_s_setprio(1);
#pragma unroll
    for (int s = 0; s < 16; ++s) {
      s8v kf = *(const s8v*)&kls[l31 * 512 + (((2 * s + hi) ^ l31) << 4)];
      sacc = __builtin_amdgcn_mfma_f32_32x32x16_bf16(kf, qf[s], sacc, 0, 0, 0);
    }
    __builtin_amdgcn_s_setprio(0);

    // in-register softmax over 32 k (16 local + 16 in partner half)
    float mt = sacc[0];
#pragma unroll
    for (int i = 1; i < 16; ++i) mt = fmaxf(mt, sacc[i]);
    mt = fmaxf(mt, __shfl_xor(mt, 32));
    if (__any(mt - mrow > 8.f)) {       // defer-max (T13)
      float mn = fmaxf(mrow, mt);
      float al = __expf(mrow - mn);
      mrow = mn; lrow *= al;
#pragma unroll
      for (int r = 0; r < 16; ++r) {
        float alr = __shfl(al, (r & 3) + 8 * (r >> 2) + 4 * hi);
#pragma unroll
        for (int n = 0; n < 8; ++n) accO[n][r] *= alr;
      }
    }
    float ls = 0.f;
#pragma unroll
    for (int i = 0; i < 16; ++i) {
      float p = __expf(sacc[i] - mrow);
      sacc[i] = p; ls += p;
    }
    ls += __shfl_xor(ls, 32);
    lrow += ls;

    // PV A-frags: cvt_pk + cross-half exchange (k-slices of 16)
    s8v pa[2];
#pragma unroll
    for (int s2 = 0; s2 < 2; ++s2) {
      int r0 = s2 * 8;
      unsigned w0 = cvtpk(sacc[r0 + 0], sacc[r0 + 1]);
      unsigned w1 = cvtpk(sacc[r0 + 2], sacc[r0 + 3]);
      unsigned w2 = cvtpk(sacc[r0 + 4], sacc[r0 + 5]);
      unsigned w3 = cvtpk(sacc[r0 + 6], sacc[r0 + 7]);
      unsigned x0 = (unsigned)__shfl_xor((int)w0, 32);
      unsigned x1 = (unsigned)__shfl_xor((int)w1, 32);
      unsigned x2 = (unsigned)__shfl_xor((int)w2, 32);
      unsigned x3 = (unsigned)__shfl_xor((int)w3, 32);
      u32x4 pw;
      pw.x = hi ? x2 : w0;
      pw.y = hi ? x3 : w1;
      pw.z = hi ? w2 : x0;
      pw.w = hi ? w3 : x1;
      pa[s2] = *(s8v*)&pw;
    }

    // O += P @ V: 8 d-tiles x 2 k-slices; B = Vt (col=d, k=hi*8+j)
    __builtin_amdgcn_s_setprio(1);
#pragma unroll
    for (int n = 0; n < 8; ++n) {
      int rv = n * 32 + l31;
#pragma unroll
      for (int s2 = 0; s2 < 2; ++s2) {
        s8v vf = *(const s8v*)&vls[rv * 64 + (((2 * s2 + hi) ^ ((l31 >> 1) & 3)) << 4)];
        accO[n] = __builtin_amdgcn_mfma_f32_32x32x16_bf16(pa[s2], vf, accO[n], 0, 0, 0);
      }
    }
    __builtin_amdgcn_s_setprio(0);
  }

  // ---- epilogue: ML + coalesced Opart via LDS bounce ----
  long prow = (((long)kv * 4 + b) * 8 + h) * 512;
  short* Ob = Opart + prow * 256;
  float* MLb = MLp + prow * 2;
  if (lane < 32) {
    MLb[(q0w + l31) * 2] = mrow;
    MLb[(q0w + l31) * 2 + 1] = lrow;
  }
  __syncthreads();                          // loop traffic done; reuse pool
  float* st = (float*)(pool + w * 4096);    // wave-private 4KB
  int orow = lane >> 1, ohalf = lane & 1;
#pragma unroll
  for (int n = 0; n < 8; ++n) {
#pragma unroll
    for (int r = 0; r < 16; ++r) {
      int ql = (r & 3) + 8 * (r >> 2) + 4 * hi;
      st[ql * 32 + l31] = accO[n][r];
    }
    short obuf[16];
#pragma unroll
    for (int jj = 0; jj < 4; ++jj) {
      f32x4 v = *(const f32x4*)&st[orow * 32 + ohalf * 16 + jj * 4];
      obuf[jj * 4 + 0] = f2b(v.x); obuf[jj * 4 + 1] = f2b(v.y);
      obuf[jj * 4 + 2] = f2b(v.z); obuf[jj * 4 + 3] = f2b(v.w);
    }
    short* dst = Ob + (long)(q0w + orow) * 256 + n * 32 + ohalf * 16;
    *(s8v*)(dst) = *(s8v*)&obuf[0];
    *(s8v*)(dst + 8) = *(s8v*)&obuf[8];
  }
}

// ---------------- combine 4 kv partials -> bufO bf16 ----------------
__global__ __launch_bounds__(512) void k_fcomb(
    const short* __restrict__ Op, const float* __restrict__ ML,
    short* __restrict__ O)
{
  int d = threadIdx.x & 255;
  int q = blockIdx.x * 2 + (threadIdx.x >> 8);
  int h = blockIdx.y, b = blockIdx.z;
  const long kvs = 4L * 8 * 512;  // rows per kv slice
  long r0 = ((long)b * 8 + h) * 512 + q;
  float mm[4], ll[4], m = -1e30f;
#pragma unroll
  for (int kv = 0; kv < 4; ++kv) {
    mm[kv] = ML[(kv * kvs + r0) * 2];
    ll[kv] = ML[(kv * kvs + r0) * 2 + 1];
    m = fmaxf(m, mm[kv]);
  }
  float wv[4], lsum = 0.f;
#pragma unroll
  for (int kv = 0; kv < 4; ++kv) { wv[kv] = __expf(mm[kv] - m); lsum += ll[kv] * wv[kv]; }
  float inv = 1.f / lsum, acc = 0.f;
#pragma unroll
  for (int kv = 0; kv < 4; ++kv)
    acc += b2f(Op[(kv * kvs + r0) * 256 + d]) * wv[kv];
  O[(long)b * 1048576 + (long)q * 2048 + h * 256 + d] = f2b(acc * inv);
}

// ---------------- z = LN(sum(Ypart) + bias + res) ----------------
__global__ __launch_bounds__(256) void k_bias_res_ln(
    const float* __restrict__ Yp, int nPart, long pStride,
    const float* __restrict__ bias,
    const float* __restrict__ res, int resMod,
    const float* __restrict__ g, const float* __restrict__ bta,
    float* __restrict__ out, short* __restrict__ out_bf)
{
  __shared__ float red[4];
  int row = blockIdx.x, e = threadIdx.x;
  float v = bias[e] + res[(long)(row % resMod) * 256 + e];
  for (int s = 0; s < nPart; ++s) v += Yp[s * pStride + (long)row * 256 + e];
  float s1 = v;
#pragma unroll
  for (int o = 32; o > 0; o >>= 1) s1 += __shfl_down(s1, o);
  if ((e & 63) == 0) red[e >> 6] = s1;
  __syncthreads();
  float mean = (red[0] + red[1] + red[2] + red[3]) * (1.f / 256.f);
  float d = v - mean;
  __syncthreads();
  float s2 = d * d;
#pragma unroll
  for (int o = 32; o > 0; o >>= 1) s2 += __shfl_down(s2, o);
  if ((e & 63) == 0) red[e >> 6] = s2;
  __syncthreads();
  float var = (red[0] + red[1] + red[2] + red[3]) * (1.f / 256.f);
  float o = g[e] * d * rsqrtf(var + 1e-5f) + bta[e];
  out[(long)row * 256 + e] = o;
  out_bf[(long)row * 256 + e] = f2b(o);
}

// ---------------- fused mean-over-latents + classifier ----------------
__global__ __launch_bounds__(256) void k_meancls(
    const float* __restrict__ z, const float* __restrict__ w,
    const float* __restrict__ bias, float* __restrict__ out)
{
  __shared__ float zms[256];
  int b = blockIdx.y, e = threadIdx.x;
  float s = 0.f;
  for (int l = 0; l < 512; ++l) s += z[((long)b * 512 + l) * 256 + e];
  zms[e] = s * (1.f / 512.f);
  __syncthreads();
  int j = blockIdx.x * 256 + e;
  if (j >= 1000) return;
  float acc = bias[j];
  for (int e2 = 0; e2 < 256; ++e2) acc += zms[e2] * w[e2 * 1000 + j];
  out[b * 1000 + j] = acc;
}

extern "C" void kernel_launch(void* const* d_in, const int* in_sizes, int n_in,
                              void* d_out, int out_size, void* d_ws, size_t ws_size,
                              hipStream_t stream)
{
  (void)in_sizes; (void)n_in; (void)out_size; (void)ws_size;
  const float* x       = (const float*)d_in[0];
  const float* conv_w  = (const float*)d_in[1];
  const float* conv_b  = (const float*)d_in[2];
  const float* pos_emb = (const float*)d_in[3];
  const float* latents = (const float*)d_in[4];
  const float* ca_wq   = (const float*)d_in[5];
  const float* ca_wk   = (const float*)d_in[6];
  const float* ca_wv   = (const float*)d_in[7];
  const float* ca_wu   = (const float*)d_in[8];
  const float* ca_bu   = (const float*)d_in[9];
  const float* ca_ln_g = (const float*)d_in[10];
  const float* ca_ln_b = (const float*)d_in[11];
  const float* blk_wq  = (const float*)d_in[12];
  const float* blk_wk  = (const float*)d_in[13];
  const float* blk_wv  = (const float*)d_in[14];
  const float* blk_wu  = (const float*)d_in[15];
  const float* blk_bu  = (const float*)d_in[16];
  const float* blk_ln1_g = (const float*)d_in[17];
  const float* blk_ln1_b = (const float*)d_in[18];
  const float* blk_w1  = (const float*)d_in[19];
  const float* blk_b1  = (const float*)d_in[20];
  const float* blk_b2_unused = nullptr; (void)blk_b2_unused;
  const float* blk_w2  = (const float*)d_in[21];
  const float* blk_b2  = (const float*)d_in[22];
  const float* blk_ln2_g = (const float*)d_in[23];
  const float* blk_ln2_b = (const float*)d_in[24];
  const float* cls_w   = (const float*)d_in[25];
  const float* cls_b   = (const float*)d_in[26];
  float* out = (float*)d_out;

  // ---- workspace layout (bf16 as short) ----
  short* wqT_ca = (short*)d_ws;            // 2048x256 (scaled)
  short* wkT_ca = wqT_ca + 524288;         // 2048x256
  short* wuT_ca = wkT_ca + 524288;         // 256x2048
  short* wv_ca  = wuT_ca + 524288;         // 256x2048
  short* lat_bf = wv_ca + 524288;          // 512x256
  short* wqkT   = lat_bf + 131072;         // 4 x (4096x256)
  short* wvT    = wqkT + 4194304;          // 4 x (2048x256)
  short* wuT_b  = wvT + 2097152;           // 4 x (256x2048)
  short* w1T    = wuT_b + 2097152;         // 4 x (1024x256)
  short* w2T    = w1T + 1048576;           // 4 x (256x1024)
  short* tok_bf = w2T + 1048576;           // 4 x 4096x256
  short* tokT   = tok_bf + 4194304;        // 4 x 256x4096
  short* qCA    = tokT + 4194304;          // 512x2048
  short* qtil   = qCA + 1048576;           // 8 x 512x256
  short* MstT   = qtil + 1048576;          // 256x2048
  short* VtB    = MstT + 524288;           // 32 x 256x512
  short* bufO   = VtB + 4194304;           // 4 x 512x2048
  short* h1     = bufO + 4194304;          // 2048x1024
  short* z_bf   = h1 + 2097152;            // 2048x256
  float* z      = (float*)(z_bf + 524288); // 2048x256 fp32
  float* zm     = z + 524288;              // spare
  float* Ypart  = zm + 1024;               // 8 x 2048x256 fp32 (split-K partials)
  short* Opart  = (short*)(Ypart + 4194304); // 4 x (4x8x512x256) bf16 kv-partials
  float* MLp    = (float*)(Opart + 16777216); // 4 x (4x8x512x2) fp32
  short* QKb    = tok_bf;                  // alias: 2048x4096 (after CA)

  const float scale = 0.17677669529663687f; // 1/sqrt(32), folded into Wq
  const int BIG = 1 << 30;

  // ---- weight prep: one batched dispatch (Wq pre-scaled) ----
  TrJobs JB; int nj = 0, base = 0;
  auto addT = [&](const float* s, short* d, int R, int C, long sIn, long sOut,
                  int zc, float sc) {
    int tpz = (C >> 5) * (R >> 5);
    JB.j[nj] = {s, d, R, C, sIn, sOut, 0, tpz, zc, base, sc};
    base += tpz * zc; ++nj;
  };
  auto addC = [&](const float* s, short* d, int nelem) {
    int tpz = nelem >> 13;
    JB.j[nj] = {s, d, 0, 0, 0, 0, 1, tpz, 1, base, 1.f};
    base += tpz; ++nj;
  };
  addT(ca_wq, wqT_ca, 256, 2048, 0, 0, 1, scale);
  addT(ca_wk, wkT_ca, 256, 2048, 0, 0, 1, 1.f);
  addT(ca_wu, wuT_ca, 2048, 256, 0, 0, 1, 1.f);
  addT(blk_wq, wqkT, 256, 2048, 524288, 1048576, 4, scale);
  addT(blk_wk, wqkT + 524288, 256, 2048, 524288, 1048576, 4, 1.f);
  addT(blk_wv, wvT, 256, 2048, 524288, 524288, 4, 1.f);
  addT(blk_wu, wuT_b, 2048, 256, 524288, 524288, 4, 1.f);
  addT(blk_w1, w1T, 256, 1024, 262144, 262144, 4, 1.f);
  addT(blk_w2, w2T, 1024, 256, 262144, 262144, 4, 1.f);
  addC(ca_wv, wv_ca, 524288);
  addC(latents, lat_bf, 131072);
  k_trbatch<<<base, 256, 0, stream>>>(JB, nj);

  // ---- tokens (both layouts, one pass) ----
  k_tokens2<<<dim3(128, 4), 256, 0, stream>>>(x, conv_w, conv_b, pos_emb,
                                              tok_bf, tokT);

  // ---- cross-attention (W_K folded into Q; W_V*W_U folded into MstT) ----
  k_mgemm<0><<<dim3(16, 4, 1), 256, 0, stream>>>(
      lat_bf, wqT_ca, qCA, nullptr, 256, 256, 256, 2048, 0, 0, 0, 1, BIG, 1, BIG);
  k_mgemm<0><<<dim3(2, 4, 8), 256, 0, stream>>>(
      qCA, wkT_ca, qtil, nullptr, 256, 2048, 256, 256, 256, 65536, 131072, 1, 8, 1, 8);
  k_mgemm<0><<<dim3(2, 2, 8), 256, 0, stream>>>(
      wuT_ca, wv_ca, MstT, nullptr, 256, 2048, 2048, 2048, 256, 256, 256, 1, 8, 1, 8);
  // CA flash: Q=qtilde(h) [pre-scaled], K=tokens(b), Vt=tokensT(b)
  k_mflash10<<<dim3(16, 8, 4), 256, 0, stream>>>(
      qtil, tok_bf, tokT, Opart, MLp, 4096, 256, 256, 4096,
      131072L, 0L, 0L, 1048576L, 0L, 1048576L);
  k_fcomb<<<dim3(256, 8, 4), 512, 0, stream>>>(Opart, MLp, bufO);
  // Y = bufO(2048x2048) @ MstT^T, split-K x8 -> fp32 partials
  k_mgemm<2><<<dim3(2, 16, 8), 256, 0, stream>>>(
      bufO, MstT, Ypart, nullptr, 256, 2048, 2048, 256, 256, 256, 524288, 1, 8, 1, 8);
  k_bias_res_ln<<<2048, 256, 0, stream>>>(Ypart, 8, 524288L, ca_bu, latents, 512,
                                          ca_ln_g, ca_ln_b, z, z_bf);

  // ---- transformer blocks ----
  for (int d = 0; d < 4; ++d) {
    // [Q|K] = z @ [scale*wq wk]  -> QKb (2048 x 4096) bf16
    k_mgemm<0><<<dim3(32, 16, 1), 256, 0, stream>>>(
        z_bf, wqkT + (long)d * 1048576, QKb, nullptr,
        256, 256, 256, 4096, 0, 0, 0, 1, BIG, 1, BIG);
    // Vt(b,h) = wvT_h @ z_b^T  (256 x 512)
    k_mgemm<0><<<dim3(4, 2, 32), 256, 0, stream>>>(
        wvT + (long)d * 524288, z_bf, VtB, nullptr,
        256, 256, 256, 512, 65536, 131072, 131072, 1, 8, 8, BIG);
    // self flash
    k_mflash10<<<dim3(16, 8, 4), 256, 0, stream>>>(
        QKb, QKb + 2048, VtB, Opart, MLp, 512, 4096, 4096, 512,
        256L, 2097152L, 256L, 2097152L, 131072L, 1048576L);
    k_fcomb<<<dim3(256, 8, 4), 512, 0, stream>>>(Opart, MLp, bufO);
    // Y = bufO @ wu^T, split-K x8 -> fp32 partials
    k_mgemm<2><<<dim3(2, 16, 8), 256, 0, stream>>>(
        bufO, wuT_b + (long)d * 524288, Ypart, nullptr,
        256, 2048, 2048, 256, 256, 256, 524288, 1, 8, 1, 8);
    k_bias_res_ln<<<2048, 256, 0, stream>>>(Ypart, 8, 524288L, blk_bu + d * 256, z, 2048,
        blk_ln1_g + d * 256, blk_ln1_b + d * 256, z, z_bf);
    // h1 = gelu(z @ w1 + b1)
    k_mgemm<1><<<dim3(8, 16, 1), 256, 0, stream>>>(
        z_bf, w1T + (long)d * 262144, h1, blk_b1 + d * 1024,
        256, 256, 256, 1024, 0, 0, 0, 1, BIG, 1, BIG);
    // Y = h1 @ w2, split-K x8 (Ksub=128) -> fp32 partials
    k_mgemm<2><<<dim3(2, 16, 8), 256, 0, stream>>>(
        h1, w2T + (long)d * 262144, Ypart, nullptr,
        128, 1024, 1024, 256, 128, 128, 524288, 1, 8, 1, 8);
    k_bias_res_ln<<<2048, 256, 0, stream>>>(Ypart, 8, 524288L, blk_b2 + d * 256, z, 2048,
        blk_ln2_g + d * 256, blk_ln2_b + d * 256, z, z_bf);
  }

  k_meancls<<<dim3(4, 4), 256, 0, stream>>>(z, cls_w, cls_b, out);
}

// Round 12
// 586.684 us; speedup vs baseline: 1.2008x; 1.0151x over previous
//
#include <hip/hip_runtime.h>
#include <hip/hip_bf16.h>
#include <math.h>

// Perceiver: B=4,C=3,N=4096,E=256,H=8,FFE=1024,L=512,D=4,NCLS=1000,HS=2048
// bf16 MFMA everywhere GEMM-shaped; fp32 accum; fp32 LN/residual spine.
// Split-K partials stored bf16 (halves Ypart HBM round-trip).

typedef __attribute__((ext_vector_type(8))) short s8v;    // 8 bf16 = 4 VGPR
typedef __attribute__((ext_vector_type(4))) float f32x4;  // 16x16 MFMA accum
typedef __attribute__((ext_vector_type(16))) float f32x16;// 32x32 MFMA accum
typedef __attribute__((ext_vector_type(4))) unsigned u32x4;

__device__ __forceinline__ short f2b(float f) {
  union { float f; unsigned u; } a; a.f = f;
  unsigned r = a.u + 0x7fff + ((a.u >> 16) & 1);
  return (short)(r >> 16);
}
__device__ __forceinline__ float b2f(short s) {
  union { unsigned u; float f; } a; a.u = ((unsigned)(unsigned short)s) << 16;
  return a.f;
}
__device__ __forceinline__ unsigned cvtpk(float lo, float hi) {
  unsigned r;
  asm("v_cvt_pk_bf16_f32 %0, %1, %2" : "=v"(r) : "v"(lo), "v"(hi));
  return r;
}

// async global->LDS, 16B per lane; LDS dest = uniform base + lane*16
__device__ __forceinline__ void gl16(const void* gp, void* lp) {
  __builtin_amdgcn_global_load_lds(
      (const __attribute__((address_space(1))) unsigned int*)gp,
      (__attribute__((address_space(3))) unsigned int*)lp, 16, 0, 0);
}

// ------- tokens(bf16) = conv1x1(x)+bias+pos, writes tok AND tokT ---------
__global__ __launch_bounds__(256) void k_tokens2(
    const float* __restrict__ x, const float* __restrict__ cw,
    const float* __restrict__ cb, const float* __restrict__ pe,
    short* __restrict__ tok, short* __restrict__ tokT)
{
  int b = blockIdx.y, n0 = blockIdx.x * 32;
  int e = threadIdx.x;
  float c0 = cw[e * 3], c1 = cw[e * 3 + 1], c2 = cw[e * 3 + 2], cbv = cb[e];
  const float* xb = x + b * 12288 + n0;
  short acc[32];
#pragma unroll
  for (int i = 0; i < 32; ++i) {
    int n = n0 + i;
    float s = cbv + pe[n * 256 + e] + xb[i] * c0 + xb[4096 + i] * c1 + xb[8192 + i] * c2;
    short v = f2b(s);
    tok[((long)b * 4096 + n) * 256 + e] = v;
    acc[i] = v;
  }
  short* tr = tokT + ((long)b * 256 + e) * 4096 + n0;
#pragma unroll
  for (int i = 0; i < 4; ++i)
    *reinterpret_cast<s8v*>(tr + i * 8) = *reinterpret_cast<s8v*>(acc + i * 8);
}

// ---------------- batched weight prep: transposes + flat converts --------
struct TrJob {
  const float* src; short* dst;
  int R, C; long sIn, sOut;
  int mode, tilesPerZ, z, tileBase;
  float scale;
};
struct TrJobs { TrJob j[11]; };

__global__ __launch_bounds__(256) void k_trbatch(TrJobs jb, int njobs)
{
  __shared__ float t[32][33];
  int tb = blockIdx.x, ji = 0;
#pragma unroll
  for (int k = 1; k < 11; ++k)
    if (k < njobs && tb >= jb.j[k].tileBase) ji = k;
  TrJob J = jb.j[ji];
  int local = tb - J.tileBase;
  if (J.mode == 1) {          // flat fp32 -> bf16 (*scale)
    long o = (long)local * 8192 + threadIdx.x;
#pragma unroll
    for (int k = 0; k < 32; ++k)
      J.dst[o + k * 256] = f2b(J.src[o + k * 256] * J.scale);
    return;
  }
  int zi = local / J.tilesPerZ, ti = local - zi * J.tilesPerZ;
  int ntx = J.C >> 5;
  int tx = ti % ntx, ty = ti / ntx;
  const float* ib = J.src + (long)zi * J.sIn;
  short* ob = J.dst + (long)zi * J.sOut;
  int c0 = tx * 32, r0 = ty * 32;
  int lx = threadIdx.x & 31, ly = threadIdx.x >> 5;
#pragma unroll
  for (int i = 0; i < 4; ++i)
    t[ly * 4 + i][lx] = ib[(long)(r0 + ly * 4 + i) * J.C + c0 + lx];
  __syncthreads();
#pragma unroll
  for (int i = 0; i < 4; ++i)
    ob[(long)(c0 + ly * 4 + i) * J.R + r0 + lx] = f2b(t[lx][ly * 4 + i] * J.scale);
}

// ---------------- bf16 MFMA BT-GEMM: C = A(MxK) @ Bt(NxK)^T ----------------
// 128x128 tile, BK=32, 256 thr. Prefetch pipeline. Requires K % 64 == 0.
// EPI: 0 = bf16 out, 1 = bias+exact-gelu bf16 out, 2 = bf16 partials out.
template<int EPI>
__global__ __launch_bounds__(256) void k_mgemm(
    const short* __restrict__ A, const short* __restrict__ Bt,
    void* __restrict__ Cv, const float* __restrict__ bias,
    int K, int lda, int ldb, int ldc,
    long sA, long sB, long sC, int zdA, int zmA, int zdB, int zmB)
{
  __shared__ char As[8192];
  __shared__ char Bs[8192];
  int z = blockIdx.z;
  const short* Ab = A + ((long)((z / zdA) % zmA)) * sA;
  const short* Bb = Bt + ((long)((z / zdB) % zmB)) * sB;
  int t = threadIdx.x;
  int lane = t & 63, w = t >> 6;
  int wr = w >> 1, wc = w & 1;
  int g = lane >> 4, l15 = lane & 15;
  long row0 = (long)blockIdx.y * 128, col0 = (long)blockIdx.x * 128;
  const f32x4 zz = {0.f, 0.f, 0.f, 0.f};
  f32x4 acc[4][4];
#pragma unroll
  for (int m = 0; m < 4; ++m)
#pragma unroll
    for (int n = 0; n < 4; ++n) acc[m][n] = zz;

  auto mload = [&](s8v* aa, s8v* bb, int kk) {
#pragma unroll
    for (int i = 0; i < 2; ++i) {
      int r = i * 64 + (t >> 2), c = t & 3;
      aa[i] = *(const s8v*)&Ab[(row0 + r) * (long)lda + kk + c * 8];
      bb[i] = *(const s8v*)&Bb[(col0 + r) * (long)ldb + kk + c * 8];
    }
  };
  auto mstore = [&](s8v* aa, s8v* bb) {
#pragma unroll
    for (int i = 0; i < 2; ++i) {
      int r = i * 64 + (t >> 2), c = t & 3;
      int off = (r * 64 + c * 16) ^ ((r & 7) << 4);
      *(s8v*)&As[off] = aa[i];
      *(s8v*)&Bs[off] = bb[i];
    }
  };
  auto mcomp = [&]() {
    s8v af[4], bfr[4];
#pragma unroll
    for (int m = 0; m < 4; ++m) {
      int r = wr * 64 + m * 16 + l15;
      af[m] = *(const s8v*)&As[(r * 64 + g * 16) ^ ((r & 7) << 4)];
    }
#pragma unroll
    for (int n = 0; n < 4; ++n) {
      int r = wc * 64 + n * 16 + l15;
      bfr[n] = *(const s8v*)&Bs[(r * 64 + g * 16) ^ ((r & 7) << 4)];
    }
#pragma unroll
    for (int m = 0; m < 4; ++m)
#pragma unroll
      for (int n = 0; n < 4; ++n)
        acc[m][n] = __builtin_amdgcn_mfma_f32_16x16x32_bf16(af[m], bfr[n], acc[m][n], 0, 0, 0);
  };

  s8v a0[2], b0[2], a1[2], b1[2];
  mload(a0, b0, 0);
  for (int k0 = 0; k0 < K; k0 += 64) {
    __syncthreads(); mstore(a0, b0); __syncthreads();
    mload(a1, b1, k0 + 32);
    mcomp();
    __syncthreads(); mstore(a1, b1); __syncthreads();
    if (k0 + 64 < K) mload(a0, b0, k0 + 64);
    mcomp();
  }

  long zo = (long)z * sC;
#pragma unroll
  for (int m = 0; m < 4; ++m)
#pragma unroll
    for (int n = 0; n < 4; ++n)
#pragma unroll
      for (int r = 0; r < 4; ++r) {
        long rr = row0 + wr * 64 + m * 16 + g * 4 + r;
        long cc = col0 + wc * 64 + n * 16 + l15;
        float v = acc[m][n][r];
        if (EPI == 1) {
          v += bias[cc];
          v = 0.5f * v * (1.f + erff(v * 0.70710678118654752f));
        }
        ((short*)Cv)[zo + rr * ldc + cc] = f2b(v);
      }
}

// ---------------- MFMA flash attention v10 (head dim 256, 32x32 MFMA) ----
// 4 waves x 32 q-rows = 128 q/block, KVBLK=32, LDS 64KB -> 2 independent
// blocks/CU (decoupled barrier domains fill each other's stalls). Swapped
// QK^T, in-register softmax, P->PV frags via cvt_pk + cross-half shfl.
// kv-split x4 to partials; coalesced Opart epilogue via LDS bounce.
__global__ __launch_bounds__(256, 2) void k_mflash10(
    const short* __restrict__ Qp, const short* __restrict__ Kp,
    const short* __restrict__ Vtp, short* __restrict__ Opart,
    float* __restrict__ MLp,
    int nk, int ldq, int ldk, int ldvt,
    long qh, long qb, long kh, long kb, long vh, long vb)
{
  __shared__ char pool[65536];  // 2 x (K 16KB + V 16KB)
  int t = threadIdx.x, lane = t & 63, w = t >> 6;   // w = 0..3
  int l31 = lane & 31, hi = lane >> 5;
  int h = blockIdx.y, b = blockIdx.z;
  int kv = blockIdx.x & 3, qblk = blockIdx.x >> 2;
  const short* Q  = Qp  + (long)h * qh + (long)b * qb;
  const short* Kg = Kp  + (long)h * kh + (long)b * kb;
  const short* Vg = Vtp + (long)h * vh + (long)b * vb;
  int q0w = qblk * 128 + w * 32;
  int nkq = nk >> 2;
  int NIT = nkq >> 5;           // KVBLK = 32
  long k0 = (long)kv * nkq;

  // Q B-frags: lane = q-col (l31), k = hi*8+j within d-slice s
  s8v qf[16];
  {
    const short* Qrow = Q + (long)(q0w + l31) * ldq + hi * 8;
#pragma unroll
    for (int s = 0; s < 16; ++s) qf[s] = *(const s8v*)(Qrow + s * 16);
  }

  // staging byte-offsets (linear LDS dest + inverse-swizzled source)
  const char* KgB = (const char*)Kg;
  const char* VgB = (const char*)Vg;
  unsigned koff[4], voff[4];
#pragma unroll
  for (int c = 0; c < 4; ++c) {
    int r = 8 * w + 2 * c + hi;                 // K tile row 0..31
    koff[c] = (unsigned)((k0 + r) * (long)ldk * 2) + ((l31 ^ r) << 4);
    int rv = 64 * w + 16 * c + (lane >> 2);     // V tile row 0..255
    voff[c] = (unsigned)(((long)rv * ldvt + k0) * 2)
              + (((lane & 3) ^ ((lane >> 3) & 3)) << 4);
  }
  const unsigned kStep = (unsigned)(32 * ldk * 2);

  auto stage = [&](int bsel) {
    char* kd = pool + bsel * 32768 + (w << 12);
    char* vd = kd + 16384;
#pragma unroll
    for (int c = 0; c < 4; ++c) { gl16(KgB + koff[c], kd + c * 1024); koff[c] += kStep; }
#pragma unroll
    for (int c = 0; c < 4; ++c) { gl16(VgB + voff[c], vd + c * 1024); voff[c] += 64; }
  };

  f32x16 accO[8];
#pragma unroll
  for (int n = 0; n < 8; ++n)
#pragma unroll
    for (int i = 0; i < 16; ++i) accO[n][i] = 0.f;
  float mrow = -1e30f, lrow = 0.f;

  stage(0);

  for (int it = 0; it < NIT; ++it) {
    int cur = it & 1;
    asm volatile("s_waitcnt vmcnt(0)" ::: "memory");
    __syncthreads();
    if (it + 1 < NIT) stage(cur ^ 1);
    const char* kls = pool + cur * 32768;
    const char* vls = kls + 16384;

    // S^T = mfma(K, Q): one 32x32 tile over 16 d-slices; C col=q, row=k
    f32x16 sacc;
#pragma unroll
    for (int i = 0; i < 16; ++i) sacc[i] = 0.f;
    __builtin_amdgcn_s_setprio(1);
#pragma unroll
    for (int s = 0; s < 16; ++s) {
      s8v kf = *(const s8v*)&kls[l31 * 512 + (((2 * s + hi) ^ l31) << 4)];
      sacc = __builtin_amdgcn_mfma_f32_32x32x16_bf16(kf, qf[s], sacc, 0, 0, 0);
    }
    __builtin_amdgcn_s_setprio(0);

    // in-register softmax over 32 k (16 local + 16 in partner half)
    float mt = sacc[0];
#pragma unroll
    for (int i = 1; i < 16; ++i) mt = fmaxf(mt, sacc[i]);
    mt = fmaxf(mt, __shfl_xor(mt, 32));
    if (__any(mt - mrow > 8.f)) {       // defer-max (T13)
      float mn = fmaxf(mrow, mt);
      float al = __expf(mrow - mn);
      mrow = mn; lrow *= al;
#pragma unroll
      for (int r = 0; r < 16; ++r) {
        float alr = __shfl(al, (r & 3) + 8 * (r >> 2) + 4 * hi);
#pragma unroll
        for (int n = 0; n < 8; ++n) accO[n][r] *= alr;
      }
    }
    float ls = 0.f;
#pragma unroll
    for (int i = 0; i < 16; ++i) {
      float p = __expf(sacc[i] - mrow);
      sacc[i] = p; ls += p;
    }
    ls += __shfl_xor(ls, 32);
    lrow += ls;

    // PV A-frags: cvt_pk + cross-half exchange (k-slices of 16)
    s8v pa[2];
#pragma unroll
    for (int s2 = 0; s2 < 2; ++s2) {
      int r0 = s2 * 8;
      unsigned w0 = cvtpk(sacc[r0 + 0], sacc[r0 + 1]);
      unsigned w1 = cvtpk(sacc[r0 + 2], sacc[r0 + 3]);
      unsigned w2 = cvtpk(sacc[r0 + 4], sacc[r0 + 5]);
      unsigned w3 = cvtpk(sacc[r0 + 6], sacc[r0 + 7]);
      unsigned x0 = (unsigned)__shfl_xor((int)w0, 32);
      unsigned x1 = (unsigned)__shfl_xor((int)w1, 32);
      unsigned x2 = (unsigned)__shfl_xor((int)w2, 32);
      unsigned x3 = (unsigned)__shfl_xor((int)w3, 32);
      u32x4 pw;
      pw.x = hi ? x2 : w0;
      pw.y = hi ? x3 : w1;
      pw.z = hi ? w2 : x0;
      pw.w = hi ? w3 : x1;
      pa[s2] = *(s8v*)&pw;
    }

    // O += P @ V: 8 d-tiles x 2 k-slices; B = Vt (col=d, k=hi*8+j)
    __builtin_amdgcn_s_setprio(1);
#pragma unroll
    for (int n = 0; n < 8; ++n) {
      int rv = n * 32 + l31;
#pragma unroll
      for (int s2 = 0; s2 < 2; ++s2) {
        s8v vf = *(const s8v*)&vls[rv * 64 + (((2 * s2 + hi) ^ ((l31 >> 1) & 3)) << 4)];
        accO[n] = __builtin_amdgcn_mfma_f32_32x32x16_bf16(pa[s2], vf, accO[n], 0, 0, 0);
      }
    }
    __builtin_amdgcn_s_setprio(0);
  }

  // ---- epilogue: ML + coalesced Opart via LDS bounce ----
  long prow = (((long)kv * 4 + b) * 8 + h) * 512;
  short* Ob = Opart + prow * 256;
  float* MLb = MLp + prow * 2;
  if (lane < 32) {
    MLb[(q0w + l31) * 2] = mrow;
    MLb[(q0w + l31) * 2 + 1] = lrow;
  }
  __syncthreads();                          // loop traffic done; reuse pool
  float* st = (float*)(pool + w * 4096);    // wave-private 4KB
  int orow = lane >> 1, ohalf = lane & 1;
#pragma unroll
  for (int n = 0; n < 8; ++n) {
#pragma unroll
    for (int r = 0; r < 16; ++r) {
      int ql = (r & 3) + 8 * (r >> 2) + 4 * hi;
      st[ql * 32 + l31] = accO[n][r];
    }
    short obuf[16];
#pragma unroll
    for (int jj = 0; jj < 4; ++jj) {
      f32x4 v = *(const f32x4*)&st[orow * 32 + ohalf * 16 + jj * 4];
      obuf[jj * 4 + 0] = f2b(v.x); obuf[jj * 4 + 1] = f2b(v.y);
      obuf[jj * 4 + 2] = f2b(v.z); obuf[jj * 4 + 3] = f2b(v.w);
    }
    short* dst = Ob + (long)(q0w + orow) * 256 + n * 32 + ohalf * 16;
    *(s8v*)(dst) = *(s8v*)&obuf[0];
    *(s8v*)(dst + 8) = *(s8v*)&obuf[8];
  }
}

// ---------------- combine 4 kv partials -> bufO bf16 ----------------
__global__ __launch_bounds__(512) void k_fcomb(
    const short* __restrict__ Op, const float* __restrict__ ML,
    short* __restrict__ O)
{
  int d = threadIdx.x & 255;
  int q = blockIdx.x * 2 + (threadIdx.x >> 8);
  int h = blockIdx.y, b = blockIdx.z;
  const long kvs = 4L * 8 * 512;  // rows per kv slice
  long r0 = ((long)b * 8 + h) * 512 + q;
  float mm[4], ll[4], m = -1e30f;
#pragma unroll
  for (int kv = 0; kv < 4; ++kv) {
    mm[kv] = ML[(kv * kvs + r0) * 2];
    ll[kv] = ML[(kv * kvs + r0) * 2 + 1];
    m = fmaxf(m, mm[kv]);
  }
  float wv[4], lsum = 0.f;
#pragma unroll
  for (int kv = 0; kv < 4; ++kv) { wv[kv] = __expf(mm[kv] - m); lsum += ll[kv] * wv[kv]; }
  float inv = 1.f / lsum, acc = 0.f;
#pragma unroll
  for (int kv = 0; kv < 4; ++kv)
    acc += b2f(Op[(kv * kvs + r0) * 256 + d]) * wv[kv];
  O[(long)b * 1048576 + (long)q * 2048 + h * 256 + d] = f2b(acc * inv);
}

// ---------------- z = LN(sum(bf16 Ypart) + bias + res) ----------------
__global__ __launch_bounds__(256) void k_bias_res_ln(
    const short* __restrict__ Yp, int nPart, long pStride,
    const float* __restrict__ bias,
    const float* __restrict__ res, int resMod,
    const float* __restrict__ g, const float* __restrict__ bta,
    float* __restrict__ out, short* __restrict__ out_bf)
{
  __shared__ float red[4];
  int row = blockIdx.x, e = threadIdx.x;
  float v = bias[e] + res[(long)(row % resMod) * 256 + e];
  for (int s = 0; s < nPart; ++s) v += b2f(Yp[s * pStride + (long)row * 256 + e]);
  float s1 = v;
#pragma unroll
  for (int o = 32; o > 0; o >>= 1) s1 += __shfl_down(s1, o);
  if ((e & 63) == 0) red[e >> 6] = s1;
  __syncthreads();
  float mean = (red[0] + red[1] + red[2] + red[3]) * (1.f / 256.f);
  float d = v - mean;
  __syncthreads();
  float s2 = d * d;
#pragma unroll
  for (int o = 32; o > 0; o >>= 1) s2 += __shfl_down(s2, o);
  if ((e & 63) == 0) red[e >> 6] = s2;
  __syncthreads();
  float var = (red[0] + red[1] + red[2] + red[3]) * (1.f / 256.f);
  float o = g[e] * d * rsqrtf(var + 1e-5f) + bta[e];
  out[(long)row * 256 + e] = o;
  out_bf[(long)row * 256 + e] = f2b(o);
}

// ---------------- fused mean-over-latents + classifier ----------------
__global__ __launch_bounds__(256) void k_meancls(
    const float* __restrict__ z, const float* __restrict__ w,
    const float* __restrict__ bias, float* __restrict__ out)
{
  __shared__ float zms[256];
  int b = blockIdx.y, e = threadIdx.x;
  float s = 0.f;
  for (int l = 0; l < 512; ++l) s += z[((long)b * 512 + l) * 256 + e];
  zms[e] = s * (1.f / 512.f);
  __syncthreads();
  int j = blockIdx.x * 256 + e;
  if (j >= 1000) return;
  float acc = bias[j];
  for (int e2 = 0; e2 < 256; ++e2) acc += zms[e2] * w[e2 * 1000 + j];
  out[b * 1000 + j] = acc;
}

extern "C" void kernel_launch(void* const* d_in, const int* in_sizes, int n_in,
                              void* d_out, int out_size, void* d_ws, size_t ws_size,
                              hipStream_t stream)
{
  (void)in_sizes; (void)n_in; (void)out_size; (void)ws_size;
  const float* x       = (const float*)d_in[0];
  const float* conv_w  = (const float*)d_in[1];
  const float* conv_b  = (const float*)d_in[2];
  const float* pos_emb = (const float*)d_in[3];
  const float* latents = (const float*)d_in[4];
  const float* ca_wq   = (const float*)d_in[5];
  const float* ca_wk   = (const float*)d_in[6];
  const float* ca_wv   = (const float*)d_in[7];
  const float* ca_wu   = (const float*)d_in[8];
  const float* ca_bu   = (const float*)d_in[9];
  const float* ca_ln_g = (const float*)d_in[10];
  const float* ca_ln_b = (const float*)d_in[11];
  const float* blk_wq  = (const float*)d_in[12];
  const float* blk_wk  = (const float*)d_in[13];
  const float* blk_wv  = (const float*)d_in[14];
  const float* blk_wu  = (const float*)d_in[15];
  const float* blk_bu  = (const float*)d_in[16];
  const float* blk_ln1_g = (const float*)d_in[17];
  const float* blk_ln1_b = (const float*)d_in[18];
  const float* blk_w1  = (const float*)d_in[19];
  const float* blk_b1  = (const float*)d_in[20];
  const float* blk_w2  = (const float*)d_in[21];
  const float* blk_b2  = (const float*)d_in[22];
  const float* blk_ln2_g = (const float*)d_in[23];
  const float* blk_ln2_b = (const float*)d_in[24];
  const float* cls_w   = (const float*)d_in[25];
  const float* cls_b   = (const float*)d_in[26];
  float* out = (float*)d_out;

  // ---- workspace layout (bf16 as short) ----
  short* wqT_ca = (short*)d_ws;            // 2048x256 (scaled)
  short* wkT_ca = wqT_ca + 524288;         // 2048x256
  short* wuT_ca = wkT_ca + 524288;         // 256x2048
  short* wv_ca  = wuT_ca + 524288;         // 256x2048
  short* lat_bf = wv_ca + 524288;          // 512x256
  short* wqkT   = lat_bf + 131072;         // 4 x (4096x256)
  short* wvT    = wqkT + 4194304;          // 4 x (2048x256)
  short* wuT_b  = wvT + 2097152;           // 4 x (256x2048)
  short* w1T    = wuT_b + 2097152;         // 4 x (1024x256)
  short* w2T    = w1T + 1048576;           // 4 x (256x1024)
  short* tok_bf = w2T + 1048576;           // 4 x 4096x256
  short* tokT   = tok_bf + 4194304;        // 4 x 256x4096
  short* qCA    = tokT + 4194304;          // 512x2048
  short* qtil   = qCA + 1048576;           // 8 x 512x256
  short* MstT   = qtil + 1048576;          // 256x2048
  short* VtB    = MstT + 524288;           // 32 x 256x512
  short* bufO   = VtB + 4194304;           // 4 x 512x2048
  short* h1     = bufO + 4194304;          // 2048x1024
  short* z_bf   = h1 + 2097152;            // 2048x256
  float* z      = (float*)(z_bf + 524288); // 2048x256 fp32
  float* zm     = z + 524288;              // spare
  short* Ypart  = (short*)(zm + 1024);     // 8 x 2048x256 bf16 (split-K partials)
  short* Opart  = Ypart + 4194304;         // 4 x (4x8x512x256) bf16 kv-partials
  float* MLp    = (float*)(Opart + 16777216); // 4 x (4x8x512x2) fp32
  short* QKb    = tok_bf;                  // alias: 2048x4096 (after CA)

  const float scale = 0.17677669529663687f; // 1/sqrt(32), folded into Wq
  const int BIG = 1 << 30;

  // ---- weight prep: one batched dispatch (Wq pre-scaled) ----
  TrJobs JB; int nj = 0, base = 0;
  auto addT = [&](const float* s, short* d, int R, int C, long sIn, long sOut,
                  int zc, float sc) {
    int tpz = (C >> 5) * (R >> 5);
    JB.j[nj] = {s, d, R, C, sIn, sOut, 0, tpz, zc, base, sc};
    base += tpz * zc; ++nj;
  };
  auto addC = [&](const float* s, short* d, int nelem) {
    int tpz = nelem >> 13;
    JB.j[nj] = {s, d, 0, 0, 0, 0, 1, tpz, 1, base, 1.f};
    base += tpz; ++nj;
  };
  addT(ca_wq, wqT_ca, 256, 2048, 0, 0, 1, scale);
  addT(ca_wk, wkT_ca, 256, 2048, 0, 0, 1, 1.f);
  addT(ca_wu, wuT_ca, 2048, 256, 0, 0, 1, 1.f);
  addT(blk_wq, wqkT, 256, 2048, 524288, 1048576, 4, scale);
  addT(blk_wk, wqkT + 524288, 256, 2048, 524288, 1048576, 4, 1.f);
  addT(blk_wv, wvT, 256, 2048, 524288, 524288, 4, 1.f);
  addT(blk_wu, wuT_b, 2048, 256, 524288, 524288, 4, 1.f);
  addT(blk_w1, w1T, 256, 1024, 262144, 262144, 4, 1.f);
  addT(blk_w2, w2T, 1024, 256, 262144, 262144, 4, 1.f);
  addC(ca_wv, wv_ca, 524288);
  addC(latents, lat_bf, 131072);
  k_trbatch<<<base, 256, 0, stream>>>(JB, nj);

  // ---- tokens (both layouts, one pass) ----
  k_tokens2<<<dim3(128, 4), 256, 0, stream>>>(x, conv_w, conv_b, pos_emb,
                                              tok_bf, tokT);

  // ---- cross-attention (W_K folded into Q; W_V*W_U folded into MstT) ----
  k_mgemm<0><<<dim3(16, 4, 1), 256, 0, stream>>>(
      lat_bf, wqT_ca, qCA, nullptr, 256, 256, 256, 2048, 0, 0, 0, 1, BIG, 1, BIG);
  k_mgemm<0><<<dim3(2, 4, 8), 256, 0, stream>>>(
      qCA, wkT_ca, qtil, nullptr, 256, 2048, 256, 256, 256, 65536, 131072, 1, 8, 1, 8);
  k_mgemm<0><<<dim3(2, 2, 8), 256, 0, stream>>>(
      wuT_ca, wv_ca, MstT, nullptr, 256, 2048, 2048, 2048, 256, 256, 256, 1, 8, 1, 8);
  // CA flash: Q=qtilde(h) [pre-scaled], K=tokens(b), Vt=tokensT(b)
  k_mflash10<<<dim3(16, 8, 4), 256, 0, stream>>>(
      qtil, tok_bf, tokT, Opart, MLp, 4096, 256, 256, 4096,
      131072L, 0L, 0L, 1048576L, 0L, 1048576L);
  k_fcomb<<<dim3(256, 8, 4), 512, 0, stream>>>(Opart, MLp, bufO);
  // Y = bufO(2048x2048) @ MstT^T, split-K x8 -> bf16 partials
  k_mgemm<2><<<dim3(2, 16, 8), 256, 0, stream>>>(
      bufO, MstT, Ypart, nullptr, 256, 2048, 2048, 256, 256, 256, 524288, 1, 8, 1, 8);
  k_bias_res_ln<<<2048, 256, 0, stream>>>(Ypart, 8, 524288L, ca_bu, latents, 512,
                                          ca_ln_g, ca_ln_b, z, z_bf);

  // ---- transformer blocks ----
  for (int d = 0; d < 4; ++d) {
    // [Q|K] = z @ [scale*wq wk]  -> QKb (2048 x 4096) bf16
    k_mgemm<0><<<dim3(32, 16, 1), 256, 0, stream>>>(
        z_bf, wqkT + (long)d * 1048576, QKb, nullptr,
        256, 256, 256, 4096, 0, 0, 0, 1, BIG, 1, BIG);
    // Vt(b,h) = wvT_h @ z_b^T  (256 x 512)
    k_mgemm<0><<<dim3(4, 2, 32), 256, 0, stream>>>(
        wvT + (long)d * 524288, z_bf, VtB, nullptr,
        256, 256, 256, 512, 65536, 131072, 131072, 1, 8, 8, BIG);
    // self flash
    k_mflash10<<<dim3(16, 8, 4), 256, 0, stream>>>(
        QKb, QKb + 2048, VtB, Opart, MLp, 512, 4096, 4096, 512,
        256L, 2097152L, 256L, 2097152L, 131072L, 1048576L);
    k_fcomb<<<dim3(256, 8, 4), 512, 0, stream>>>(Opart, MLp, bufO);
    // Y = bufO @ wu^T, split-K x8 -> bf16 partials
    k_mgemm<2><<<dim3(2, 16, 8), 256, 0, stream>>>(
        bufO, wuT_b + (long)d * 524288, Ypart, nullptr,
        256, 2048, 2048, 256, 256, 256, 524288, 1, 8, 1, 8);
    k_bias_res_ln<<<2048, 256, 0, stream>>>(Ypart, 8, 524288L, blk_bu + d * 256, z, 2048,
        blk_ln1_g + d * 256, blk_ln1_b + d * 256, z, z_bf);
    // h1 = gelu(z @ w1 + b1)
    k_mgemm<1><<<dim3(8, 16, 1), 256, 0, stream>>>(
        z_bf, w1T + (long)d * 262144, h1, blk_b1 + d * 1024,
        256, 256, 256, 1024, 0, 0, 0, 1, BIG, 1, BIG);
    // Y = h1 @ w2, split-K x8 (Ksub=128) -> bf16 partials
    k_mgemm<2><<<dim3(2, 16, 8), 256, 0, stream>>>(
        h1, w2T + (long)d * 262144, Ypart, nullptr,
        128, 1024, 1024, 256, 128, 128, 524288, 1, 8, 1, 8);
    k_bias_res_ln<<<2048, 256, 0, stream>>>(Ypart, 8, 524288L, blk_b2 + d * 256, z, 2048,
        blk_ln2_g + d * 256, blk_ln2_b + d * 256, z, z_bf);
  }

  k_meancls<<<dim3(4, 4), 256, 0, stream>>>(z, cls_w, cls_b, out);
}

// Round 13
// 567.750 us; speedup vs baseline: 1.2408x; 1.0333x over previous
//
#include <hip/hip_runtime.h>
#include <hip/hip_bf16.h>
#include <math.h>

// Perceiver: B=4,C=3,N=4096,E=256,H=8,FFE=1024,L=512,D=4,NCLS=1000,HS=2048
// bf16 MFMA everywhere GEMM-shaped; fp32 accum; fp32 LN/residual spine.
// Split-K partials bf16; attn-out GEMM fuses the kv-partial combine (no fcomb).

typedef __attribute__((ext_vector_type(8))) short s8v;    // 8 bf16 = 4 VGPR
typedef __attribute__((ext_vector_type(4))) float f32x4;  // 16x16 MFMA accum
typedef __attribute__((ext_vector_type(16))) float f32x16;// 32x32 MFMA accum
typedef __attribute__((ext_vector_type(4))) unsigned u32x4;

__device__ __forceinline__ short f2b(float f) {
  union { float f; unsigned u; } a; a.f = f;
  unsigned r = a.u + 0x7fff + ((a.u >> 16) & 1);
  return (short)(r >> 16);
}
__device__ __forceinline__ float b2f(short s) {
  union { unsigned u; float f; } a; a.u = ((unsigned)(unsigned short)s) << 16;
  return a.f;
}
__device__ __forceinline__ unsigned cvtpk(float lo, float hi) {
  unsigned r;
  asm("v_cvt_pk_bf16_f32 %0, %1, %2" : "=v"(r) : "v"(lo), "v"(hi));
  return r;
}

// async global->LDS, 16B per lane; LDS dest = uniform base + lane*16
__device__ __forceinline__ void gl16(const void* gp, void* lp) {
  __builtin_amdgcn_global_load_lds(
      (const __attribute__((address_space(1))) unsigned int*)gp,
      (__attribute__((address_space(3))) unsigned int*)lp, 16, 0, 0);
}

// ------- tokens(bf16) = conv1x1(x)+bias+pos, writes tok AND tokT ---------
__global__ __launch_bounds__(256) void k_tokens2(
    const float* __restrict__ x, const float* __restrict__ cw,
    const float* __restrict__ cb, const float* __restrict__ pe,
    short* __restrict__ tok, short* __restrict__ tokT)
{
  int b = blockIdx.y, n0 = blockIdx.x * 32;
  int e = threadIdx.x;
  float c0 = cw[e * 3], c1 = cw[e * 3 + 1], c2 = cw[e * 3 + 2], cbv = cb[e];
  const float* xb = x + b * 12288 + n0;
  short acc[32];
#pragma unroll
  for (int i = 0; i < 32; ++i) {
    int n = n0 + i;
    float s = cbv + pe[n * 256 + e] + xb[i] * c0 + xb[4096 + i] * c1 + xb[8192 + i] * c2;
    short v = f2b(s);
    tok[((long)b * 4096 + n) * 256 + e] = v;
    acc[i] = v;
  }
  short* tr = tokT + ((long)b * 256 + e) * 4096 + n0;
#pragma unroll
  for (int i = 0; i < 4; ++i)
    *reinterpret_cast<s8v*>(tr + i * 8) = *reinterpret_cast<s8v*>(acc + i * 8);
}

// ---------------- batched weight prep: transposes + flat converts --------
struct TrJob {
  const float* src; short* dst;
  int R, C; long sIn, sOut;
  int mode, tilesPerZ, z, tileBase;
  float scale;
};
struct TrJobs { TrJob j[11]; };

__global__ __launch_bounds__(256) void k_trbatch(TrJobs jb, int njobs)
{
  __shared__ float t[32][33];
  int tb = blockIdx.x, ji = 0;
#pragma unroll
  for (int k = 1; k < 11; ++k)
    if (k < njobs && tb >= jb.j[k].tileBase) ji = k;
  TrJob J = jb.j[ji];
  int local = tb - J.tileBase;
  if (J.mode == 1) {          // flat fp32 -> bf16 (*scale)
    long o = (long)local * 8192 + threadIdx.x;
#pragma unroll
    for (int k = 0; k < 32; ++k)
      J.dst[o + k * 256] = f2b(J.src[o + k * 256] * J.scale);
    return;
  }
  int zi = local / J.tilesPerZ, ti = local - zi * J.tilesPerZ;
  int ntx = J.C >> 5;
  int tx = ti % ntx, ty = ti / ntx;
  const float* ib = J.src + (long)zi * J.sIn;
  short* ob = J.dst + (long)zi * J.sOut;
  int c0 = tx * 32, r0 = ty * 32;
  int lx = threadIdx.x & 31, ly = threadIdx.x >> 5;
#pragma unroll
  for (int i = 0; i < 4; ++i)
    t[ly * 4 + i][lx] = ib[(long)(r0 + ly * 4 + i) * J.C + c0 + lx];
  __syncthreads();
#pragma unroll
  for (int i = 0; i < 4; ++i)
    ob[(long)(c0 + ly * 4 + i) * J.R + r0 + lx] = f2b(t[lx][ly * 4 + i] * J.scale);
}

// ---------------- bf16 MFMA BT-GEMM: C = A(MxK) @ Bt(NxK)^T ----------------
// 128x128 tile, BK=32, 256 thr. Prefetch pipeline. Requires K % 64 == 0.
// EPI: 0 = bf16 out, 1 = bias+exact-gelu bf16 out, 2 = bf16 partials out.
template<int EPI>
__global__ __launch_bounds__(256) void k_mgemm(
    const short* __restrict__ A, const short* __restrict__ Bt,
    void* __restrict__ Cv, const float* __restrict__ bias,
    int K, int lda, int ldb, int ldc,
    long sA, long sB, long sC, int zdA, int zmA, int zdB, int zmB)
{
  __shared__ char As[8192];
  __shared__ char Bs[8192];
  int z = blockIdx.z;
  const short* Ab = A + ((long)((z / zdA) % zmA)) * sA;
  const short* Bb = Bt + ((long)((z / zdB) % zmB)) * sB;
  int t = threadIdx.x;
  int lane = t & 63, w = t >> 6;
  int wr = w >> 1, wc = w & 1;
  int g = lane >> 4, l15 = lane & 15;
  long row0 = (long)blockIdx.y * 128, col0 = (long)blockIdx.x * 128;
  const f32x4 zz = {0.f, 0.f, 0.f, 0.f};
  f32x4 acc[4][4];
#pragma unroll
  for (int m = 0; m < 4; ++m)
#pragma unroll
    for (int n = 0; n < 4; ++n) acc[m][n] = zz;

  auto mload = [&](s8v* aa, s8v* bb, int kk) {
#pragma unroll
    for (int i = 0; i < 2; ++i) {
      int r = i * 64 + (t >> 2), c = t & 3;
      aa[i] = *(const s8v*)&Ab[(row0 + r) * (long)lda + kk + c * 8];
      bb[i] = *(const s8v*)&Bb[(col0 + r) * (long)ldb + kk + c * 8];
    }
  };
  auto mstore = [&](s8v* aa, s8v* bb) {
#pragma unroll
    for (int i = 0; i < 2; ++i) {
      int r = i * 64 + (t >> 2), c = t & 3;
      int off = (r * 64 + c * 16) ^ ((r & 7) << 4);
      *(s8v*)&As[off] = aa[i];
      *(s8v*)&Bs[off] = bb[i];
    }
  };
  auto mcomp = [&]() {
    s8v af[4], bfr[4];
#pragma unroll
    for (int m = 0; m < 4; ++m) {
      int r = wr * 64 + m * 16 + l15;
      af[m] = *(const s8v*)&As[(r * 64 + g * 16) ^ ((r & 7) << 4)];
    }
#pragma unroll
    for (int n = 0; n < 4; ++n) {
      int r = wc * 64 + n * 16 + l15;
      bfr[n] = *(const s8v*)&Bs[(r * 64 + g * 16) ^ ((r & 7) << 4)];
    }
#pragma unroll
    for (int m = 0; m < 4; ++m)
#pragma unroll
      for (int n = 0; n < 4; ++n)
        acc[m][n] = __builtin_amdgcn_mfma_f32_16x16x32_bf16(af[m], bfr[n], acc[m][n], 0, 0, 0);
  };

  s8v a0[2], b0[2], a1[2], b1[2];
  mload(a0, b0, 0);
  for (int k0 = 0; k0 < K; k0 += 64) {
    __syncthreads(); mstore(a0, b0); __syncthreads();
    mload(a1, b1, k0 + 32);
    mcomp();
    __syncthreads(); mstore(a1, b1); __syncthreads();
    if (k0 + 64 < K) mload(a0, b0, k0 + 64);
    mcomp();
  }

  long zo = (long)z * sC;
#pragma unroll
  for (int m = 0; m < 4; ++m)
#pragma unroll
    for (int n = 0; n < 4; ++n)
#pragma unroll
      for (int r = 0; r < 4; ++r) {
        long rr = row0 + wr * 64 + m * 16 + g * 4 + r;
        long cc = col0 + wc * 64 + n * 16 + l15;
        float v = acc[m][n][r];
        if (EPI == 1) {
          v += bias[cc];
          v = 0.5f * v * (1.f + erff(v * 0.70710678118654752f));
        }
        ((short*)Cv)[zo + rr * ldc + cc] = f2b(v);
      }
}

// -------- attn-out GEMM with fused kv-partial combine (replaces fcomb) ----
// Y_chunk[z=head] = combine(Opart, ML) @ Bt_chunk^T, split-K x8 (chunk=head).
// A-rows are thread-fixed -> combine weights precomputed once per thread.
// grid (2, 16, 8), 256 thr; writes bf16 partials (sC = 524288).
__global__ __launch_bounds__(256) void k_mgemm_att(
    const short* __restrict__ Op,   // [kv4][b4][h8][512][256] bf16
    const float* __restrict__ ML,   // [kv4][b4][h8][512][2] fp32
    const short* __restrict__ Bt,   // (256 out-cols) x (2048) bf16, NxK
    short* __restrict__ Cv,         // bf16 partials [z][2048][256]
    int ldb)
{
  __shared__ char As[8192];
  __shared__ char Bs[8192];
  int z = blockIdx.z;               // head = K-chunk
  int t = threadIdx.x;
  int lane = t & 63, w = t >> 6;
  int wr = w >> 1, wc = w & 1;
  int g = lane >> 4, l15 = lane & 15;
  long row0 = (long)blockIdx.y * 128, col0 = (long)blockIdx.x * 128;
  const long kvs = 4L * 8 * 512;    // rows per kv slice

  // per-thread fixed A rows: r_i = i*64 + (t>>2); combine weights once
  long arow[2]; float wgt[2][4];
#pragma unroll
  for (int i = 0; i < 2; ++i) {
    long gr = row0 + i * 64 + (t >> 2);
    int bb = (int)(gr >> 9), q = (int)(gr & 511);
    long base = ((long)bb * 8 + z) * 512 + q;
    arow[i] = base;
    float mm[4], ll[4], M = -1e30f;
#pragma unroll
    for (int kv = 0; kv < 4; ++kv) {
      float2 mlv = *(const float2*)&ML[(kv * kvs + base) * 2];
      mm[kv] = mlv.x; ll[kv] = mlv.y;
      M = fmaxf(M, mm[kv]);
    }
    float ls = 0.f;
#pragma unroll
    for (int kv = 0; kv < 4; ++kv) { mm[kv] = __expf(mm[kv] - M); ls += ll[kv] * mm[kv]; }
    float inv = 1.f / ls;
#pragma unroll
    for (int kv = 0; kv < 4; ++kv) wgt[i][kv] = mm[kv] * inv;
  }

  const f32x4 zz = {0.f, 0.f, 0.f, 0.f};
  f32x4 acc[4][4];
#pragma unroll
  for (int m = 0; m < 4; ++m)
#pragma unroll
    for (int n = 0; n < 4; ++n) acc[m][n] = zz;

  auto mload = [&](s8v* aa, s8v* bb, int kk) {
    int c = t & 3;
#pragma unroll
    for (int i = 0; i < 2; ++i) {
      s8v v0 = *(const s8v*)&Op[(0 * kvs + arow[i]) * 256 + kk + c * 8];
      s8v v1 = *(const s8v*)&Op[(1 * kvs + arow[i]) * 256 + kk + c * 8];
      s8v v2 = *(const s8v*)&Op[(2 * kvs + arow[i]) * 256 + kk + c * 8];
      s8v v3 = *(const s8v*)&Op[(3 * kvs + arow[i]) * 256 + kk + c * 8];
      short o[8];
#pragma unroll
      for (int e = 0; e < 8; ++e)
        o[e] = f2b(wgt[i][0] * b2f(v0[e]) + wgt[i][1] * b2f(v1[e]) +
                   wgt[i][2] * b2f(v2[e]) + wgt[i][3] * b2f(v3[e]));
      aa[i] = *(s8v*)o;
      int r = i * 64 + (t >> 2);
      bb[i] = *(const s8v*)&Bt[(long)z * 256 + (col0 + r) * (long)ldb + kk + c * 8];
    }
  };
  auto mstore = [&](s8v* aa, s8v* bb) {
#pragma unroll
    for (int i = 0; i < 2; ++i) {
      int r = i * 64 + (t >> 2), c = t & 3;
      int off = (r * 64 + c * 16) ^ ((r & 7) << 4);
      *(s8v*)&As[off] = aa[i];
      *(s8v*)&Bs[off] = bb[i];
    }
  };
  auto mcomp = [&]() {
    s8v af[4], bfr[4];
#pragma unroll
    for (int m = 0; m < 4; ++m) {
      int r = wr * 64 + m * 16 + l15;
      af[m] = *(const s8v*)&As[(r * 64 + g * 16) ^ ((r & 7) << 4)];
    }
#pragma unroll
    for (int n = 0; n < 4; ++n) {
      int r = wc * 64 + n * 16 + l15;
      bfr[n] = *(const s8v*)&Bs[(r * 64 + g * 16) ^ ((r & 7) << 4)];
    }
#pragma unroll
    for (int m = 0; m < 4; ++m)
#pragma unroll
      for (int n = 0; n < 4; ++n)
        acc[m][n] = __builtin_amdgcn_mfma_f32_16x16x32_bf16(af[m], bfr[n], acc[m][n], 0, 0, 0);
  };

  s8v a0[2], b0[2], a1[2], b1[2];
  mload(a0, b0, 0);
  for (int k0 = 0; k0 < 256; k0 += 64) {
    __syncthreads(); mstore(a0, b0); __syncthreads();
    mload(a1, b1, k0 + 32);
    mcomp();
    __syncthreads(); mstore(a1, b1); __syncthreads();
    if (k0 + 64 < 256) mload(a0, b0, k0 + 64);
    mcomp();
  }

  long zo = (long)z * 524288;
#pragma unroll
  for (int m = 0; m < 4; ++m)
#pragma unroll
    for (int n = 0; n < 4; ++n)
#pragma unroll
      for (int r = 0; r < 4; ++r) {
        long rr = row0 + wr * 64 + m * 16 + g * 4 + r;
        long cc = col0 + wc * 64 + n * 16 + l15;
        Cv[zo + rr * 256 + cc] = f2b(acc[m][n][r]);
      }
}

// ---------------- MFMA flash attention v10 (head dim 256, 32x32 MFMA) ----
// 4 waves x 32 q-rows = 128 q/block, KVBLK=32, LDS 64KB -> 2 independent
// blocks/CU. Swapped QK^T, in-register softmax, P->PV frags via cvt_pk +
// cross-half shfl. kv-split x4 to partials; coalesced Opart epilogue.
__global__ __launch_bounds__(256, 2) void k_mflash10(
    const short* __restrict__ Qp, const short* __restrict__ Kp,
    const short* __restrict__ Vtp, short* __restrict__ Opart,
    float* __restrict__ MLp,
    int nk, int ldq, int ldk, int ldvt,
    long qh, long qb, long kh, long kb, long vh, long vb)
{
  __shared__ char pool[65536];  // 2 x (K 16KB + V 16KB)
  int t = threadIdx.x, lane = t & 63, w = t >> 6;   // w = 0..3
  int l31 = lane & 31, hi = lane >> 5;
  int h = blockIdx.y, b = blockIdx.z;
  int kv = blockIdx.x & 3, qblk = blockIdx.x >> 2;
  const short* Q  = Qp  + (long)h * qh + (long)b * qb;
  const short* Kg = Kp  + (long)h * kh + (long)b * kb;
  const short* Vg = Vtp + (long)h * vh + (long)b * vb;
  int q0w = qblk * 128 + w * 32;
  int nkq = nk >> 2;
  int NIT = nkq >> 5;           // KVBLK = 32
  long k0 = (long)kv * nkq;

  // Q B-frags: lane = q-col (l31), k = hi*8+j within d-slice s
  s8v qf[16];
  {
    const short* Qrow = Q + (long)(q0w + l31) * ldq + hi * 8;
#pragma unroll
    for (int s = 0; s < 16; ++s) qf[s] = *(const s8v*)(Qrow + s * 16);
  }

  // staging byte-offsets (linear LDS dest + inverse-swizzled source)
  const char* KgB = (const char*)Kg;
  const char* VgB = (const char*)Vg;
  unsigned koff[4], voff[4];
#pragma unroll
  for (int c = 0; c < 4; ++c) {
    int r = 8 * w + 2 * c + hi;                 // K tile row 0..31
    koff[c] = (unsigned)((k0 + r) * (long)ldk * 2) + ((l31 ^ r) << 4);
    int rv = 64 * w + 16 * c + (lane >> 2);     // V tile row 0..255
    voff[c] = (unsigned)(((long)rv * ldvt + k0) * 2)
              + (((lane & 3) ^ ((lane >> 3) & 3)) << 4);
  }
  const unsigned kStep = (unsigned)(32 * ldk * 2);

  auto stage = [&](int bsel) {
    char* kd = pool + bsel * 32768 + (w << 12);
    char* vd = kd + 16384;
#pragma unroll
    for (int c = 0; c < 4; ++c) { gl16(KgB + koff[c], kd + c * 1024); koff[c] += kStep; }
#pragma unroll
    for (int c = 0; c < 4; ++c) { gl16(VgB + voff[c], vd + c * 1024); voff[c] += 64; }
  };

  f32x16 accO[8];
#pragma unroll
  for (int n = 0; n < 8; ++n)
#pragma unroll
    for (int i = 0; i < 16; ++i) accO[n][i] = 0.f;
  float mrow = -1e30f, lrow = 0.f;

  stage(0);

  for (int it = 0; it < NIT; ++it) {
    int cur = it & 1;
    asm volatile("s_waitcnt vmcnt(0)" ::: "memory");
    __syncthreads();
    if (it + 1 < NIT) stage(cur ^ 1);
    const char* kls = pool + cur * 32768;
    const char* vls = kls + 16384;

    // S^T = mfma(K, Q): one 32x32 tile over 16 d-slices; C col=q, row=k
    f32x16 sacc;
#pragma unroll
    for (int i = 0; i < 16; ++i) sacc[i] = 0.f;
    __builtin_amdgcn_s_setprio(1);
#pragma unroll
    for (int s = 0; s < 16; ++s) {
      s8v kf = *(const s8v*)&kls[l31 * 512 + (((2 * s + hi) ^ l31) << 4)];
      sacc = __builtin_amdgcn_mfma_f32_32x32x16_bf16(kf, qf[s], sacc, 0, 0, 0);
    }
    __builtin_amdgcn_s_setprio(0);

    // in-register softmax over 32 k (16 local + 16 in partner half)
    float mt = sacc[0];
#pragma unroll
    for (int i = 1; i < 16; ++i) mt = fmaxf(mt, sacc[i]);
    mt = fmaxf(mt, __shfl_xor(mt, 32));
    if (__any(mt - mrow > 8.f)) {       // defer-max (T13)
      float mn = fmaxf(mrow, mt);
      float al = __expf(mrow - mn);
      mrow = mn; lrow *= al;
#pragma unroll
      for (int r = 0; r < 16; ++r) {
        float alr = __shfl(al, (r & 3) + 8 * (r >> 2) + 4 * hi);
#pragma unroll
        for (int n = 0; n < 8; ++n) accO[n][r] *= alr;
      }
    }
    float ls = 0.f;
#pragma unroll
    for (int i = 0; i < 16; ++i) {
      float p = __expf(sacc[i] - mrow);
      sacc[i] = p; ls += p;
    }
    ls += __shfl_xor(ls, 32);
    lrow += ls;

    // PV A-frags: cvt_pk + cross-half exchange (k-slices of 16)
    s8v pa[2];
#pragma unroll
    for (int s2 = 0; s2 < 2; ++s2) {
      int r0 = s2 * 8;
      unsigned w0 = cvtpk(sacc[r0 + 0], sacc[r0 + 1]);
      unsigned w1 = cvtpk(sacc[r0 + 2], sacc[r0 + 3]);
      unsigned w2 = cvtpk(sacc[r0 + 4], sacc[r0 + 5]);
      unsigned w3 = cvtpk(sacc[r0 + 6], sacc[r0 + 7]);
      unsigned x0 = (unsigned)__shfl_xor((int)w0, 32);
      unsigned x1 = (unsigned)__shfl_xor((int)w1, 32);
      unsigned x2 = (unsigned)__shfl_xor((int)w2, 32);
      unsigned x3 = (unsigned)__shfl_xor((int)w3, 32);
      u32x4 pw;
      pw.x = hi ? x2 : w0;
      pw.y = hi ? x3 : w1;
      pw.z = hi ? w2 : x0;
      pw.w = hi ? w3 : x1;
      pa[s2] = *(s8v*)&pw;
    }

    // O += P @ V: 8 d-tiles x 2 k-slices; B = Vt (col=d, k=hi*8+j)
    __builtin_amdgcn_s_setprio(1);
#pragma unroll
    for (int n = 0; n < 8; ++n) {
      int rv = n * 32 + l31;
#pragma unroll
      for (int s2 = 0; s2 < 2; ++s2) {
        s8v vf = *(const s8v*)&vls[rv * 64 + (((2 * s2 + hi) ^ ((l31 >> 1) & 3)) << 4)];
        accO[n] = __builtin_amdgcn_mfma_f32_32x32x16_bf16(pa[s2], vf, accO[n], 0, 0, 0);
      }
    }
    __builtin_amdgcn_s_setprio(0);
  }

  // ---- epilogue: ML + coalesced Opart via LDS bounce ----
  long prow = (((long)kv * 4 + b) * 8 + h) * 512;
  short* Ob = Opart + prow * 256;
  float* MLb = MLp + prow * 2;
  if (lane < 32) {
    MLb[(q0w + l31) * 2] = mrow;
    MLb[(q0w + l31) * 2 + 1] = lrow;
  }
  __syncthreads();                          // loop traffic done; reuse pool
  float* st = (float*)(pool + w * 4096);    // wave-private 4KB
  int orow = lane >> 1, ohalf = lane & 1;
#pragma unroll
  for (int n = 0; n < 8; ++n) {
#pragma unroll
    for (int r = 0; r < 16; ++r) {
      int ql = (r & 3) + 8 * (r >> 2) + 4 * hi;
      st[ql * 32 + l31] = accO[n][r];
    }
    short obuf[16];
#pragma unroll
    for (int jj = 0; jj < 4; ++jj) {
      f32x4 v = *(const f32x4*)&st[orow * 32 + ohalf * 16 + jj * 4];
      obuf[jj * 4 + 0] = f2b(v.x); obuf[jj * 4 + 1] = f2b(v.y);
      obuf[jj * 4 + 2] = f2b(v.z); obuf[jj * 4 + 3] = f2b(v.w);
    }
    short* dst = Ob + (long)(q0w + orow) * 256 + n * 32 + ohalf * 16;
    *(s8v*)(dst) = *(s8v*)&obuf[0];
    *(s8v*)(dst + 8) = *(s8v*)&obuf[8];
  }
}

// ---------------- z = LN(sum(bf16 Ypart) + bias + res) ----------------
__global__ __launch_bounds__(256) void k_bias_res_ln(
    const short* __restrict__ Yp, int nPart, long pStride,
    const float* __restrict__ bias,
    const float* __restrict__ res, int resMod,
    const float* __restrict__ g, const float* __restrict__ bta,
    float* __restrict__ out, short* __restrict__ out_bf)
{
  __shared__ float red[4];
  int row = blockIdx.x, e = threadIdx.x;
  float v = bias[e] + res[(long)(row % resMod) * 256 + e];
  for (int s = 0; s < nPart; ++s) v += b2f(Yp[s * pStride + (long)row * 256 + e]);
  float s1 = v;
#pragma unroll
  for (int o = 32; o > 0; o >>= 1) s1 += __shfl_down(s1, o);
  if ((e & 63) == 0) red[e >> 6] = s1;
  __syncthreads();
  float mean = (red[0] + red[1] + red[2] + red[3]) * (1.f / 256.f);
  float d = v - mean;
  __syncthreads();
  float s2 = d * d;
#pragma unroll
  for (int o = 32; o > 0; o >>= 1) s2 += __shfl_down(s2, o);
  if ((e & 63) == 0) red[e >> 6] = s2;
  __syncthreads();
  float var = (red[0] + red[1] + red[2] + red[3]) * (1.f / 256.f);
  float o = g[e] * d * rsqrtf(var + 1e-5f) + bta[e];
  out[(long)row * 256 + e] = o;
  out_bf[(long)row * 256 + e] = f2b(o);
}

// ---------------- fused mean-over-latents + classifier ----------------
__global__ __launch_bounds__(256) void k_meancls(
    const float* __restrict__ z, const float* __restrict__ w,
    const float* __restrict__ bias, float* __restrict__ out)
{
  __shared__ float zms[256];
  int b = blockIdx.y, e = threadIdx.x;
  float s = 0.f;
  for (int l = 0; l < 512; ++l) s += z[((long)b * 512 + l) * 256 + e];
  zms[e] = s * (1.f / 512.f);
  __syncthreads();
  int j = blockIdx.x * 256 + e;
  if (j >= 1000) return;
  float acc = bias[j];
  for (int e2 = 0; e2 < 256; ++e2) acc += zms[e2] * w[e2 * 1000 + j];
  out[b * 1000 + j] = acc;
}

extern "C" void kernel_launch(void* const* d_in, const int* in_sizes, int n_in,
                              void* d_out, int out_size, void* d_ws, size_t ws_size,
                              hipStream_t stream)
{
  (void)in_sizes; (void)n_in; (void)out_size; (void)ws_size;
  const float* x       = (const float*)d_in[0];
  const float* conv_w  = (const float*)d_in[1];
  const float* conv_b  = (const float*)d_in[2];
  const float* pos_emb = (const float*)d_in[3];
  const float* latents = (const float*)d_in[4];
  const float* ca_wq   = (const float*)d_in[5];
  const float* ca_wk   = (const float*)d_in[6];
  const float* ca_wv   = (const float*)d_in[7];
  const float* ca_wu   = (const float*)d_in[8];
  const float* ca_bu   = (const float*)d_in[9];
  const float* ca_ln_g = (const float*)d_in[10];
  const float* ca_ln_b = (const float*)d_in[11];
  const float* blk_wq  = (const float*)d_in[12];
  const float* blk_wk  = (const float*)d_in[13];
  const float* blk_wv  = (const float*)d_in[14];
  const float* blk_wu  = (const float*)d_in[15];
  const float* blk_bu  = (const float*)d_in[16];
  const float* blk_ln1_g = (const float*)d_in[17];
  const float* blk_ln1_b = (const float*)d_in[18];
  const float* blk_w1  = (const float*)d_in[19];
  const float* blk_b1  = (const float*)d_in[20];
  const float* blk_w2  = (const float*)d_in[21];
  const float* blk_b2  = (const float*)d_in[22];
  const float* blk_ln2_g = (const float*)d_in[23];
  const float* blk_ln2_b = (const float*)d_in[24];
  const float* cls_w   = (const float*)d_in[25];
  const float* cls_b   = (const float*)d_in[26];
  float* out = (float*)d_out;

  // ---- workspace layout (bf16 as short) ----
  short* wqT_ca = (short*)d_ws;            // 2048x256 (scaled)
  short* wkT_ca = wqT_ca + 524288;         // 2048x256
  short* wuT_ca = wkT_ca + 524288;         // 256x2048
  short* wv_ca  = wuT_ca + 524288;         // 256x2048
  short* lat_bf = wv_ca + 524288;          // 512x256
  short* wqkT   = lat_bf + 131072;         // 4 x (4096x256)
  short* wvT    = wqkT + 4194304;          // 4 x (2048x256)
  short* wuT_b  = wvT + 2097152;           // 4 x (256x2048)
  short* w1T    = wuT_b + 2097152;         // 4 x (1024x256)
  short* w2T    = w1T + 1048576;           // 4 x (256x1024)
  short* tok_bf = w2T + 1048576;           // 4 x 4096x256
  short* tokT   = tok_bf + 4194304;        // 4 x 256x4096
  short* qCA    = tokT + 4194304;          // 512x2048
  short* qtil   = qCA + 1048576;           // 8 x 512x256
  short* MstT   = qtil + 1048576;          // 256x2048
  short* VtB    = MstT + 524288;           // 32 x 256x512
  short* bufO   = VtB + 4194304;           // (unused now)
  short* h1     = bufO + 4194304;          // 2048x1024
  short* z_bf   = h1 + 2097152;            // 2048x256
  float* z      = (float*)(z_bf + 524288); // 2048x256 fp32
  float* zm     = z + 524288;              // spare
  short* Ypart  = (short*)(zm + 1024);     // 8 x 2048x256 bf16 (split-K partials)
  short* Opart  = Ypart + 4194304;         // 4 x (4x8x512x256) bf16 kv-partials
  float* MLp    = (float*)(Opart + 16777216); // 4 x (4x8x512x2) fp32
  short* QKb    = tok_bf;                  // alias: 2048x4096 (after CA)

  const float scale = 0.17677669529663687f; // 1/sqrt(32), folded into Wq
  const int BIG = 1 << 30;

  // ---- weight prep: one batched dispatch (Wq pre-scaled) ----
  TrJobs JB; int nj = 0, base = 0;
  auto addT = [&](const float* s, short* d, int R, int C, long sIn, long sOut,
                  int zc, float sc) {
    int tpz = (C >> 5) * (R >> 5);
    JB.j[nj] = {s, d, R, C, sIn, sOut, 0, tpz, zc, base, sc};
    base += tpz * zc; ++nj;
  };
  auto addC = [&](const float* s, short* d, int nelem) {
    int tpz = nelem >> 13;
    JB.j[nj] = {s, d, 0, 0, 0, 0, 1, tpz, 1, base, 1.f};
    base += tpz; ++nj;
  };
  addT(ca_wq, wqT_ca, 256, 2048, 0, 0, 1, scale);
  addT(ca_wk, wkT_ca, 256, 2048, 0, 0, 1, 1.f);
  addT(ca_wu, wuT_ca, 2048, 256, 0, 0, 1, 1.f);
  addT(blk_wq, wqkT, 256, 2048, 524288, 1048576, 4, scale);
  addT(blk_wk, wqkT + 524288, 256, 2048, 524288, 1048576, 4, 1.f);
  addT(blk_wv, wvT, 256, 2048, 524288, 524288, 4, 1.f);
  addT(blk_wu, wuT_b, 2048, 256, 524288, 524288, 4, 1.f);
  addT(blk_w1, w1T, 256, 1024, 262144, 262144, 4, 1.f);
  addT(blk_w2, w2T, 1024, 256, 262144, 262144, 4, 1.f);
  addC(ca_wv, wv_ca, 524288);
  addC(latents, lat_bf, 131072);
  k_trbatch<<<base, 256, 0, stream>>>(JB, nj);

  // ---- tokens (both layouts, one pass) ----
  k_tokens2<<<dim3(128, 4), 256, 0, stream>>>(x, conv_w, conv_b, pos_emb,
                                              tok_bf, tokT);

  // ---- cross-attention (W_K folded into Q; W_V*W_U folded into MstT) ----
  k_mgemm<0><<<dim3(16, 4, 1), 256, 0, stream>>>(
      lat_bf, wqT_ca, qCA, nullptr, 256, 256, 256, 2048, 0, 0, 0, 1, BIG, 1, BIG);
  k_mgemm<0><<<dim3(2, 4, 8), 256, 0, stream>>>(
      qCA, wkT_ca, qtil, nullptr, 256, 2048, 256, 256, 256, 65536, 131072, 1, 8, 1, 8);
  k_mgemm<0><<<dim3(2, 2, 8), 256, 0, stream>>>(
      wuT_ca, wv_ca, MstT, nullptr, 256, 2048, 2048, 2048, 256, 256, 256, 1, 8, 1, 8);
  // CA flash: Q=qtilde(h) [pre-scaled], K=tokens(b), Vt=tokensT(b)
  k_mflash10<<<dim3(16, 8, 4), 256, 0, stream>>>(
      qtil, tok_bf, tokT, Opart, MLp, 4096, 256, 256, 4096,
      131072L, 0L, 0L, 1048576L, 0L, 1048576L);
  // Y = combine(Opart) @ MstT^T, split-K x8 (chunk = head) -> bf16 partials
  k_mgemm_att<<<dim3(2, 16, 8), 256, 0, stream>>>(Opart, MLp, MstT, Ypart, 2048);
  k_bias_res_ln<<<2048, 256, 0, stream>>>(Ypart, 8, 524288L, ca_bu, latents, 512,
                                          ca_ln_g, ca_ln_b, z, z_bf);

  // ---- transformer blocks ----
  for (int d = 0; d < 4; ++d) {
    // [Q|K] = z @ [scale*wq wk]  -> QKb (2048 x 4096) bf16
    k_mgemm<0><<<dim3(32, 16, 1), 256, 0, stream>>>(
        z_bf, wqkT + (long)d * 1048576, QKb, nullptr,
        256, 256, 256, 4096, 0, 0, 0, 1, BIG, 1, BIG);
    // Vt(b,h) = wvT_h @ z_b^T  (256 x 512)
    k_mgemm<0><<<dim3(4, 2, 32), 256, 0, stream>>>(
        wvT + (long)d * 524288, z_bf, VtB, nullptr,
        256, 256, 256, 512, 65536, 131072, 131072, 1, 8, 8, BIG);
    // self flash
    k_mflash10<<<dim3(16, 8, 4), 256, 0, stream>>>(
        QKb, QKb + 2048, VtB, Opart, MLp, 512, 4096, 4096, 512,
        256L, 2097152L, 256L, 2097152L, 131072L, 1048576L);
    // Y = combine(Opart) @ wu^T, split-K x8 (chunk = head) -> bf16 partials
    k_mgemm_att<<<dim3(2, 16, 8), 256, 0, stream>>>(
        Opart, MLp, wuT_b + (long)d * 524288, Ypart, 2048);
    k_bias_res_ln<<<2048, 256, 0, stream>>>(Ypart, 8, 524288L, blk_bu + d * 256, z, 2048,
        blk_ln1_g + d * 256, blk_ln1_b + d * 256, z, z_bf);
    // h1 = gelu(z @ w1 + b1)
    k_mgemm<1><<<dim3(8, 16, 1), 256, 0, stream>>>(
        z_bf, w1T + (long)d * 262144, h1, blk_b1 + d * 1024,
        256, 256, 256, 1024, 0, 0, 0, 1, BIG, 1, BIG);
    // Y = h1 @ w2, split-K x8 (Ksub=128) -> bf16 partials
    k_mgemm<2><<<dim3(2, 16, 8), 256, 0, stream>>>(
        h1, w2T + (long)d * 262144, Ypart, nullptr,
        128, 1024, 1024, 256, 128, 128, 524288, 1, 8, 1, 8);
    k_bias_res_ln<<<2048, 256, 0, stream>>>(Ypart, 8, 524288L, blk_b2 + d * 256, z, 2048,
        blk_ln2_g + d * 256, blk_ln2_b + d * 256, z, z_bf);
  }

  k_meancls<<<dim3(4, 4), 256, 0, stream>>>(z, cls_w, cls_b, out);
}

// Round 14
// 546.819 us; speedup vs baseline: 1.2883x; 1.0383x over previous
//
#include <hip/hip_runtime.h>
#include <hip/hip_bf16.h>
#include <math.h>

// Perceiver: B=4,C=3,N=4096,E=256,H=8,FFE=1024,L=512,D=4,NCLS=1000,HS=2048
// bf16 MFMA everywhere GEMM-shaped; fp32 accum; fp32 LN/residual spine.
// Split-K partials bf16; attn-out GEMM fuses kv-partial combine; independent
// GEMM jobs merged into single dispatches (QK+Vt per layer, qCA+MstT).

typedef __attribute__((ext_vector_type(8))) short s8v;    // 8 bf16 = 4 VGPR
typedef __attribute__((ext_vector_type(4))) float f32x4;  // 16x16 MFMA accum
typedef __attribute__((ext_vector_type(16))) float f32x16;// 32x32 MFMA accum
typedef __attribute__((ext_vector_type(4))) unsigned u32x4;

__device__ __forceinline__ short f2b(float f) {
  union { float f; unsigned u; } a; a.f = f;
  unsigned r = a.u + 0x7fff + ((a.u >> 16) & 1);
  return (short)(r >> 16);
}
__device__ __forceinline__ float b2f(short s) {
  union { unsigned u; float f; } a; a.u = ((unsigned)(unsigned short)s) << 16;
  return a.f;
}
__device__ __forceinline__ unsigned cvtpk(float lo, float hi) {
  unsigned r;
  asm("v_cvt_pk_bf16_f32 %0, %1, %2" : "=v"(r) : "v"(lo), "v"(hi));
  return r;
}

// async global->LDS, 16B per lane; LDS dest = uniform base + lane*16
__device__ __forceinline__ void gl16(const void* gp, void* lp) {
  __builtin_amdgcn_global_load_lds(
      (const __attribute__((address_space(1))) unsigned int*)gp,
      (__attribute__((address_space(3))) unsigned int*)lp, 16, 0, 0);
}

// ------- tokens(bf16) = conv1x1(x)+bias+pos, writes tok AND tokT ---------
__global__ __launch_bounds__(256) void k_tokens2(
    const float* __restrict__ x, const float* __restrict__ cw,
    const float* __restrict__ cb, const float* __restrict__ pe,
    short* __restrict__ tok, short* __restrict__ tokT)
{
  int b = blockIdx.y, n0 = blockIdx.x * 32;
  int e = threadIdx.x;
  float c0 = cw[e * 3], c1 = cw[e * 3 + 1], c2 = cw[e * 3 + 2], cbv = cb[e];
  const float* xb = x + b * 12288 + n0;
  short acc[32];
#pragma unroll
  for (int i = 0; i < 32; ++i) {
    int n = n0 + i;
    float s = cbv + pe[n * 256 + e] + xb[i] * c0 + xb[4096 + i] * c1 + xb[8192 + i] * c2;
    short v = f2b(s);
    tok[((long)b * 4096 + n) * 256 + e] = v;
    acc[i] = v;
  }
  short* tr = tokT + ((long)b * 256 + e) * 4096 + n0;
#pragma unroll
  for (int i = 0; i < 4; ++i)
    *reinterpret_cast<s8v*>(tr + i * 8) = *reinterpret_cast<s8v*>(acc + i * 8);
}

// ---------------- batched weight prep: transposes + flat converts --------
struct TrJob {
  const float* src; short* dst;
  int R, C; long sIn, sOut;
  int mode, tilesPerZ, z, tileBase;
  float scale;
};
struct TrJobs { TrJob j[11]; };

__global__ __launch_bounds__(256) void k_trbatch(TrJobs jb, int njobs)
{
  __shared__ float t[32][33];
  int tb = blockIdx.x, ji = 0;
#pragma unroll
  for (int k = 1; k < 11; ++k)
    if (k < njobs && tb >= jb.j[k].tileBase) ji = k;
  TrJob J = jb.j[ji];
  int local = tb - J.tileBase;
  if (J.mode == 1) {          // flat fp32 -> bf16 (*scale)
    long o = (long)local * 8192 + threadIdx.x;
#pragma unroll
    for (int k = 0; k < 32; ++k)
      J.dst[o + k * 256] = f2b(J.src[o + k * 256] * J.scale);
    return;
  }
  int zi = local / J.tilesPerZ, ti = local - zi * J.tilesPerZ;
  int ntx = J.C >> 5;
  int tx = ti % ntx, ty = ti / ntx;
  const float* ib = J.src + (long)zi * J.sIn;
  short* ob = J.dst + (long)zi * J.sOut;
  int c0 = tx * 32, r0 = ty * 32;
  int lx = threadIdx.x & 31, ly = threadIdx.x >> 5;
#pragma unroll
  for (int i = 0; i < 4; ++i)
    t[ly * 4 + i][lx] = ib[(long)(r0 + ly * 4 + i) * J.C + c0 + lx];
  __syncthreads();
#pragma unroll
  for (int i = 0; i < 4; ++i)
    ob[(long)(c0 + ly * 4 + i) * J.R + r0 + lx] = f2b(t[lx][ly * 4 + i] * J.scale);
}

// ---------------- shared MFMA BT-GEMM core: C = A(MxK) @ Bt(NxK)^T --------
// 128x128 tile, BK=32, 256 thr, prefetch pipeline. K % 64 == 0.
// EPI: 0 = bf16 out, 1 = bias+exact-gelu bf16 out.
template<int EPI>
__device__ __forceinline__ void gemm_core(
    const short* __restrict__ Ab, const short* __restrict__ Bb,
    short* __restrict__ Cb, const float* __restrict__ bias,
    int K, int lda, int ldb, int ldc, long row0, long col0,
    char* As, char* Bs)
{
  int t = threadIdx.x;
  int lane = t & 63, w = t >> 6;
  int wr = w >> 1, wc = w & 1;
  int g = lane >> 4, l15 = lane & 15;
  const f32x4 zz = {0.f, 0.f, 0.f, 0.f};
  f32x4 acc[4][4];
#pragma unroll
  for (int m = 0; m < 4; ++m)
#pragma unroll
    for (int n = 0; n < 4; ++n) acc[m][n] = zz;

  auto mload = [&](s8v* aa, s8v* bb, int kk) {
#pragma unroll
    for (int i = 0; i < 2; ++i) {
      int r = i * 64 + (t >> 2), c = t & 3;
      aa[i] = *(const s8v*)&Ab[(row0 + r) * (long)lda + kk + c * 8];
      bb[i] = *(const s8v*)&Bb[(col0 + r) * (long)ldb + kk + c * 8];
    }
  };
  auto mstore = [&](s8v* aa, s8v* bb) {
#pragma unroll
    for (int i = 0; i < 2; ++i) {
      int r = i * 64 + (t >> 2), c = t & 3;
      int off = (r * 64 + c * 16) ^ ((r & 7) << 4);
      *(s8v*)&As[off] = aa[i];
      *(s8v*)&Bs[off] = bb[i];
    }
  };
  auto mcomp = [&]() {
    s8v af[4], bfr[4];
#pragma unroll
    for (int m = 0; m < 4; ++m) {
      int r = wr * 64 + m * 16 + l15;
      af[m] = *(const s8v*)&As[(r * 64 + g * 16) ^ ((r & 7) << 4)];
    }
#pragma unroll
    for (int n = 0; n < 4; ++n) {
      int r = wc * 64 + n * 16 + l15;
      bfr[n] = *(const s8v*)&Bs[(r * 64 + g * 16) ^ ((r & 7) << 4)];
    }
#pragma unroll
    for (int m = 0; m < 4; ++m)
#pragma unroll
      for (int n = 0; n < 4; ++n)
        acc[m][n] = __builtin_amdgcn_mfma_f32_16x16x32_bf16(af[m], bfr[n], acc[m][n], 0, 0, 0);
  };

  s8v a0[2], b0[2], a1[2], b1[2];
  mload(a0, b0, 0);
  for (int k0 = 0; k0 < K; k0 += 64) {
    __syncthreads(); mstore(a0, b0); __syncthreads();
    mload(a1, b1, k0 + 32);
    mcomp();
    __syncthreads(); mstore(a1, b1); __syncthreads();
    if (k0 + 64 < K) mload(a0, b0, k0 + 64);
    mcomp();
  }

#pragma unroll
  for (int m = 0; m < 4; ++m)
#pragma unroll
    for (int n = 0; n < 4; ++n)
#pragma unroll
      for (int r = 0; r < 4; ++r) {
        long rr = row0 + wr * 64 + m * 16 + g * 4 + r;
        long cc = col0 + wc * 64 + n * 16 + l15;
        float v = acc[m][n][r];
        if (EPI == 1) {
          v += bias[cc];
          v = 0.5f * v * (1.f + erff(v * 0.70710678118654752f));
        }
        Cb[rr * ldc + cc] = f2b(v);
      }
}

// generic batched BT-GEMM kernel (qtil, FF1, FF2)
template<int EPI>
__global__ __launch_bounds__(256) void k_mgemm(
    const short* __restrict__ A, const short* __restrict__ Bt,
    short* __restrict__ Cv, const float* __restrict__ bias,
    int K, int lda, int ldb, int ldc,
    long sA, long sB, long sC, int zdA, int zmA, int zdB, int zmB)
{
  __shared__ char As[8192];
  __shared__ char Bs[8192];
  int z = blockIdx.z;
  const short* Ab = A + ((long)((z / zdA) % zmA)) * sA;
  const short* Bb = Bt + ((long)((z / zdB) % zmB)) * sB;
  gemm_core<EPI>(Ab, Bb, Cv + (long)z * sC, bias, K, lda, ldb, ldc,
                 (long)blockIdx.y * 128, (long)blockIdx.x * 128, As, Bs);
}

// merged per-layer dispatch: QK proj (blocks 0..511) + Vt proj (512..767)
__global__ __launch_bounds__(256) void k_qkvt(
    const short* __restrict__ z_bf, const short* __restrict__ wqkT_d,
    const short* __restrict__ wvT_d, short* __restrict__ QKb,
    short* __restrict__ VtB)
{
  __shared__ char As[8192];
  __shared__ char Bs[8192];
  int bid = blockIdx.x;
  if (bid < 512) {          // [Q|K] = z @ wqk: 2048 x 4096, K=256
    int bx = bid & 31, by = bid >> 5;
    gemm_core<0>(z_bf, wqkT_d, QKb, nullptr, 256, 256, 256, 4096,
                 (long)by * 128, (long)bx * 128, As, Bs);
  } else {                  // Vt(b,h) = wvT_h @ z_b^T: 256 x 512, K=256
    int local = bid - 512;
    int bx = local & 3, rest = local >> 2;
    int by = rest & 1, bz = rest >> 1;    // bz = b*8 + ... = 0..31
    int hh = bz & 7, bb = bz >> 3;
    gemm_core<0>(wvT_d + hh * 65536, z_bf + (long)bb * 131072,
                 VtB + (long)bz * 131072, nullptr, 256, 256, 256, 512,
                 (long)by * 128, (long)bx * 128, As, Bs);
  }
}

// merged CA prep: qCA (blocks 0..63) + MstT (64..95)
__global__ __launch_bounds__(256) void k_capre(
    const short* __restrict__ lat_bf, const short* __restrict__ wqT_ca,
    const short* __restrict__ wuT_ca, const short* __restrict__ wv_ca,
    short* __restrict__ qCA, short* __restrict__ MstT)
{
  __shared__ char As[8192];
  __shared__ char Bs[8192];
  int bid = blockIdx.x;
  if (bid < 64) {           // qCA = latents @ Wq: 512 x 2048, K=256
    int bx = bid & 15, by = bid >> 4;
    gemm_core<0>(lat_bf, wqT_ca, qCA, nullptr, 256, 256, 256, 2048,
                 (long)by * 128, (long)bx * 128, As, Bs);
  } else {                  // MstT_h = Wu_h^T @ Wv_h^T: 256 x 2048(cols h*256)
    int local = bid - 64;
    int bx = local & 1, by = (local >> 1) & 1, hh = local >> 2;
    gemm_core<0>(wuT_ca + hh * 256, wv_ca + hh * 256, MstT + hh * 256,
                 nullptr, 256, 2048, 2048, 2048,
                 (long)by * 128, (long)bx * 128, As, Bs);
  }
}

// -------- attn-out GEMM with fused kv-partial combine ----
// Y_chunk[z=head] = combine(Opart, ML) @ Bt_chunk^T, split-K x8 (chunk=head).
__global__ __launch_bounds__(256) void k_mgemm_att(
    const short* __restrict__ Op,   // [kv4][b4][h8][512][256] bf16
    const float* __restrict__ ML,   // [kv4][b4][h8][512][2] fp32
    const short* __restrict__ Bt,   // (256 out-cols) x (2048) bf16, NxK
    short* __restrict__ Cv,         // bf16 partials [z][2048][256]
    int ldb)
{
  __shared__ char As[8192];
  __shared__ char Bs[8192];
  int z = blockIdx.z;               // head = K-chunk
  int t = threadIdx.x;
  int lane = t & 63, w = t >> 6;
  int wr = w >> 1, wc = w & 1;
  int g = lane >> 4, l15 = lane & 15;
  long row0 = (long)blockIdx.y * 128, col0 = (long)blockIdx.x * 128;
  const long kvs = 4L * 8 * 512;    // rows per kv slice

  long arow[2]; float wgt[2][4];
#pragma unroll
  for (int i = 0; i < 2; ++i) {
    long gr = row0 + i * 64 + (t >> 2);
    int bb = (int)(gr >> 9), q = (int)(gr & 511);
    long base = ((long)bb * 8 + z) * 512 + q;
    arow[i] = base;
    float mm[4], ll[4], M = -1e30f;
#pragma unroll
    for (int kv = 0; kv < 4; ++kv) {
      float2 mlv = *(const float2*)&ML[(kv * kvs + base) * 2];
      mm[kv] = mlv.x; ll[kv] = mlv.y;
      M = fmaxf(M, mm[kv]);
    }
    float ls = 0.f;
#pragma unroll
    for (int kv = 0; kv < 4; ++kv) { mm[kv] = __expf(mm[kv] - M); ls += ll[kv] * mm[kv]; }
    float inv = 1.f / ls;
#pragma unroll
    for (int kv = 0; kv < 4; ++kv) wgt[i][kv] = mm[kv] * inv;
  }

  const f32x4 zz = {0.f, 0.f, 0.f, 0.f};
  f32x4 acc[4][4];
#pragma unroll
  for (int m = 0; m < 4; ++m)
#pragma unroll
    for (int n = 0; n < 4; ++n) acc[m][n] = zz;

  auto mload = [&](s8v* aa, s8v* bb, int kk) {
    int c = t & 3;
#pragma unroll
    for (int i = 0; i < 2; ++i) {
      s8v v0 = *(const s8v*)&Op[(0 * kvs + arow[i]) * 256 + kk + c * 8];
      s8v v1 = *(const s8v*)&Op[(1 * kvs + arow[i]) * 256 + kk + c * 8];
      s8v v2 = *(const s8v*)&Op[(2 * kvs + arow[i]) * 256 + kk + c * 8];
      s8v v3 = *(const s8v*)&Op[(3 * kvs + arow[i]) * 256 + kk + c * 8];
      short o[8];
#pragma unroll
      for (int e = 0; e < 8; ++e)
        o[e] = f2b(wgt[i][0] * b2f(v0[e]) + wgt[i][1] * b2f(v1[e]) +
                   wgt[i][2] * b2f(v2[e]) + wgt[i][3] * b2f(v3[e]));
      aa[i] = *(s8v*)o;
      int r = i * 64 + (t >> 2);
      bb[i] = *(const s8v*)&Bt[(long)z * 256 + (col0 + r) * (long)ldb + kk + c * 8];
    }
  };
  auto mstore = [&](s8v* aa, s8v* bb) {
#pragma unroll
    for (int i = 0; i < 2; ++i) {
      int r = i * 64 + (t >> 2), c = t & 3;
      int off = (r * 64 + c * 16) ^ ((r & 7) << 4);
      *(s8v*)&As[off] = aa[i];
      *(s8v*)&Bs[off] = bb[i];
    }
  };
  auto mcomp = [&]() {
    s8v af[4], bfr[4];
#pragma unroll
    for (int m = 0; m < 4; ++m) {
      int r = wr * 64 + m * 16 + l15;
      af[m] = *(const s8v*)&As[(r * 64 + g * 16) ^ ((r & 7) << 4)];
    }
#pragma unroll
    for (int n = 0; n < 4; ++n) {
      int r = wc * 64 + n * 16 + l15;
      bfr[n] = *(const s8v*)&Bs[(r * 64 + g * 16) ^ ((r & 7) << 4)];
    }
#pragma unroll
    for (int m = 0; m < 4; ++m)
#pragma unroll
      for (int n = 0; n < 4; ++n)
        acc[m][n] = __builtin_amdgcn_mfma_f32_16x16x32_bf16(af[m], bfr[n], acc[m][n], 0, 0, 0);
  };

  s8v a0[2], b0[2], a1[2], b1[2];
  mload(a0, b0, 0);
  for (int k0 = 0; k0 < 256; k0 += 64) {
    __syncthreads(); mstore(a0, b0); __syncthreads();
    mload(a1, b1, k0 + 32);
    mcomp();
    __syncthreads(); mstore(a1, b1); __syncthreads();
    if (k0 + 64 < 256) mload(a0, b0, k0 + 64);
    mcomp();
  }

  long zo = (long)z * 524288;
#pragma unroll
  for (int m = 0; m < 4; ++m)
#pragma unroll
    for (int n = 0; n < 4; ++n)
#pragma unroll
      for (int r = 0; r < 4; ++r) {
        long rr = row0 + wr * 64 + m * 16 + g * 4 + r;
        long cc = col0 + wc * 64 + n * 16 + l15;
        Cv[zo + rr * 256 + cc] = f2b(acc[m][n][r]);
      }
}

// ---------------- MFMA flash attention v10 (head dim 256, 32x32 MFMA) ----
// 4 waves x 32 q-rows = 128 q/block, KVBLK=32, LDS 64KB -> 2 independent
// blocks/CU. Swapped QK^T, in-register softmax, P->PV frags via cvt_pk +
// cross-half shfl. kv-split x4 to partials; coalesced Opart epilogue.
__global__ __launch_bounds__(256, 2) void k_mflash10(
    const short* __restrict__ Qp, const short* __restrict__ Kp,
    const short* __restrict__ Vtp, short* __restrict__ Opart,
    float* __restrict__ MLp,
    int nk, int ldq, int ldk, int ldvt,
    long qh, long qb, long kh, long kb, long vh, long vb)
{
  __shared__ char pool[65536];  // 2 x (K 16KB + V 16KB)
  int t = threadIdx.x, lane = t & 63, w = t >> 6;   // w = 0..3
  int l31 = lane & 31, hi = lane >> 5;
  int h = blockIdx.y, b = blockIdx.z;
  int kv = blockIdx.x & 3, qblk = blockIdx.x >> 2;
  const short* Q  = Qp  + (long)h * qh + (long)b * qb;
  const short* Kg = Kp  + (long)h * kh + (long)b * kb;
  const short* Vg = Vtp + (long)h * vh + (long)b * vb;
  int q0w = qblk * 128 + w * 32;
  int nkq = nk >> 2;
  int NIT = nkq >> 5;           // KVBLK = 32
  long k0 = (long)kv * nkq;

  // Q B-frags: lane = q-col (l31), k = hi*8+j within d-slice s
  s8v qf[16];
  {
    const short* Qrow = Q + (long)(q0w + l31) * ldq + hi * 8;
#pragma unroll
    for (int s = 0; s < 16; ++s) qf[s] = *(const s8v*)(Qrow + s * 16);
  }

  // staging byte-offsets (linear LDS dest + inverse-swizzled source)
  const char* KgB = (const char*)Kg;
  const char* VgB = (const char*)Vg;
  unsigned koff[4], voff[4];
#pragma unroll
  for (int c = 0; c < 4; ++c) {
    int r = 8 * w + 2 * c + hi;                 // K tile row 0..31
    koff[c] = (unsigned)((k0 + r) * (long)ldk * 2) + ((l31 ^ r) << 4);
    int rv = 64 * w + 16 * c + (lane >> 2);     // V tile row 0..255
    voff[c] = (unsigned)(((long)rv * ldvt + k0) * 2)
              + (((lane & 3) ^ ((lane >> 3) & 3)) << 4);
  }
  const unsigned kStep = (unsigned)(32 * ldk * 2);

  auto stage = [&](int bsel) {
    char* kd = pool + bsel * 32768 + (w << 12);
    char* vd = kd + 16384;
#pragma unroll
    for (int c = 0; c < 4; ++c) { gl16(KgB + koff[c], kd + c * 1024); koff[c] += kStep; }
#pragma unroll
    for (int c = 0; c < 4; ++c) { gl16(VgB + voff[c], vd + c * 1024); voff[c] += 64; }
  };

  f32x16 accO[8];
#pragma unroll
  for (int n = 0; n < 8; ++n)
#pragma unroll
    for (int i = 0; i < 16; ++i) accO[n][i] = 0.f;
  float mrow = -1e30f, lrow = 0.f;

  stage(0);

  for (int it = 0; it < NIT; ++it) {
    int cur = it & 1;
    asm volatile("s_waitcnt vmcnt(0)" ::: "memory");
    __syncthreads();
    if (it + 1 < NIT) stage(cur ^ 1);
    const char* kls = pool + cur * 32768;
    const char* vls = kls + 16384;

    // S^T = mfma(K, Q): one 32x32 tile over 16 d-slices; C col=q, row=k
    f32x16 sacc;
#pragma unroll
    for (int i = 0; i < 16; ++i) sacc[i] = 0.f;
    __builtin_amdgcn_s_setprio(1);
#pragma unroll
    for (int s = 0; s < 16; ++s) {
      s8v kf = *(const s8v*)&kls[l31 * 512 + (((2 * s + hi) ^ l31) << 4)];
      sacc = __builtin_amdgcn_mfma_f32_32x32x16_bf16(kf, qf[s], sacc, 0, 0, 0);
    }
    __builtin_amdgcn_s_setprio(0);

    // in-register softmax over 32 k (16 local + 16 in partner half)
    float mt = sacc[0];
#pragma unroll
    for (int i = 1; i < 16; ++i) mt = fmaxf(mt, sacc[i]);
    mt = fmaxf(mt, __shfl_xor(mt, 32));
    if (__any(mt - mrow > 8.f)) {       // defer-max (T13)
      float mn = fmaxf(mrow, mt);
      float al = __expf(mrow - mn);
      mrow = mn; lrow *= al;
#pragma unroll
      for (int r = 0; r < 16; ++r) {
        float alr = __shfl(al, (r & 3) + 8 * (r >> 2) + 4 * hi);
#pragma unroll
        for (int n = 0; n < 8; ++n) accO[n][r] *= alr;
      }
    }
    float ls = 0.f;
#pragma unroll
    for (int i = 0; i < 16; ++i) {
      float p = __expf(sacc[i] - mrow);
      sacc[i] = p; ls += p;
    }
    ls += __shfl_xor(ls, 32);
    lrow += ls;

    // PV A-frags: cvt_pk + cross-half exchange (k-slices of 16)
    s8v pa[2];
#pragma unroll
    for (int s2 = 0; s2 < 2; ++s2) {
      int r0 = s2 * 8;
      unsigned w0 = cvtpk(sacc[r0 + 0], sacc[r0 + 1]);
      unsigned w1 = cvtpk(sacc[r0 + 2], sacc[r0 + 3]);
      unsigned w2 = cvtpk(sacc[r0 + 4], sacc[r0 + 5]);
      unsigned w3 = cvtpk(sacc[r0 + 6], sacc[r0 + 7]);
      unsigned x0 = (unsigned)__shfl_xor((int)w0, 32);
      unsigned x1 = (unsigned)__shfl_xor((int)w1, 32);
      unsigned x2 = (unsigned)__shfl_xor((int)w2, 32);
      unsigned x3 = (unsigned)__shfl_xor((int)w3, 32);
      u32x4 pw;
      pw.x = hi ? x2 : w0;
      pw.y = hi ? x3 : w1;
      pw.z = hi ? w2 : x0;
      pw.w = hi ? w3 : x1;
      pa[s2] = *(s8v*)&pw;
    }

    // O += P @ V: 8 d-tiles x 2 k-slices; B = Vt (col=d, k=hi*8+j)
    __builtin_amdgcn_s_setprio(1);
#pragma unroll
    for (int n = 0; n < 8; ++n) {
      int rv = n * 32 + l31;
#pragma unroll
      for (int s2 = 0; s2 < 2; ++s2) {
        s8v vf = *(const s8v*)&vls[rv * 64 + (((2 * s2 + hi) ^ ((l31 >> 1) & 3)) << 4)];
        accO[n] = __builtin_amdgcn_mfma_f32_32x32x16_bf16(pa[s2], vf, accO[n], 0, 0, 0);
      }
    }
    __builtin_amdgcn_s_setprio(0);
  }

  // ---- epilogue: ML + coalesced Opart via LDS bounce ----
  long prow = (((long)kv * 4 + b) * 8 + h) * 512;
  short* Ob = Opart + prow * 256;
  float* MLb = MLp + prow * 2;
  if (lane < 32) {
    MLb[(q0w + l31) * 2] = mrow;
    MLb[(q0w + l31) * 2 + 1] = lrow;
  }
  __syncthreads();                          // loop traffic done; reuse pool
  float* st = (float*)(pool + w * 4096);    // wave-private 4KB
  int orow = lane >> 1, ohalf = lane & 1;
#pragma unroll
  for (int n = 0; n < 8; ++n) {
#pragma unroll
    for (int r = 0; r < 16; ++r) {
      int ql = (r & 3) + 8 * (r >> 2) + 4 * hi;
      st[ql * 32 + l31] = accO[n][r];
    }
    short obuf[16];
#pragma unroll
    for (int jj = 0; jj < 4; ++jj) {
      f32x4 v = *(const f32x4*)&st[orow * 32 + ohalf * 16 + jj * 4];
      obuf[jj * 4 + 0] = f2b(v.x); obuf[jj * 4 + 1] = f2b(v.y);
      obuf[jj * 4 + 2] = f2b(v.z); obuf[jj * 4 + 3] = f2b(v.w);
    }
    short* dst = Ob + (long)(q0w + orow) * 256 + n * 32 + ohalf * 16;
    *(s8v*)(dst) = *(s8v*)&obuf[0];
    *(s8v*)(dst + 8) = *(s8v*)&obuf[8];
  }
}

// ---------------- z = LN(sum(bf16 Ypart) + bias + res) ----------------
__global__ __launch_bounds__(256) void k_bias_res_ln(
    const short* __restrict__ Yp, int nPart, long pStride,
    const float* __restrict__ bias,
    const float* __restrict__ res, int resMod,
    const float* __restrict__ g, const float* __restrict__ bta,
    float* __restrict__ out, short* __restrict__ out_bf)
{
  __shared__ float red[4];
  int row = blockIdx.x, e = threadIdx.x;
  float v = bias[e] + res[(long)(row % resMod) * 256 + e];
  for (int s = 0; s < nPart; ++s) v += b2f(Yp[s * pStride + (long)row * 256 + e]);
  float s1 = v;
#pragma unroll
  for (int o = 32; o > 0; o >>= 1) s1 += __shfl_down(s1, o);
  if ((e & 63) == 0) red[e >> 6] = s1;
  __syncthreads();
  float mean = (red[0] + red[1] + red[2] + red[3]) * (1.f / 256.f);
  float d = v - mean;
  __syncthreads();
  float s2 = d * d;
#pragma unroll
  for (int o = 32; o > 0; o >>= 1) s2 += __shfl_down(s2, o);
  if ((e & 63) == 0) red[e >> 6] = s2;
  __syncthreads();
  float var = (red[0] + red[1] + red[2] + red[3]) * (1.f / 256.f);
  float o = g[e] * d * rsqrtf(var + 1e-5f) + bta[e];
  out[(long)row * 256 + e] = o;
  out_bf[(long)row * 256 + e] = f2b(o);
}

// ---------------- fused mean-over-latents + classifier ----------------
__global__ __launch_bounds__(256) void k_meancls(
    const float* __restrict__ z, const float* __restrict__ w,
    const float* __restrict__ bias, float* __restrict__ out)
{
  __shared__ float zms[256];
  int b = blockIdx.y, e = threadIdx.x;
  float s = 0.f;
  for (int l = 0; l < 512; ++l) s += z[((long)b * 512 + l) * 256 + e];
  zms[e] = s * (1.f / 512.f);
  __syncthreads();
  int j = blockIdx.x * 256 + e;
  if (j >= 1000) return;
  float acc = bias[j];
  for (int e2 = 0; e2 < 256; ++e2) acc += zms[e2] * w[e2 * 1000 + j];
  out[b * 1000 + j] = acc;
}

extern "C" void kernel_launch(void* const* d_in, const int* in_sizes, int n_in,
                              void* d_out, int out_size, void* d_ws, size_t ws_size,
                              hipStream_t stream)
{
  (void)in_sizes; (void)n_in; (void)out_size; (void)ws_size;
  const float* x       = (const float*)d_in[0];
  const float* conv_w  = (const float*)d_in[1];
  const float* conv_b  = (const float*)d_in[2];
  const float* pos_emb = (const float*)d_in[3];
  const float* latents = (const float*)d_in[4];
  const float* ca_wq   = (const float*)d_in[5];
  const float* ca_wk   = (const float*)d_in[6];
  const float* ca_wv   = (const float*)d_in[7];
  const float* ca_wu   = (const float*)d_in[8];
  const float* ca_bu   = (const float*)d_in[9];
  const float* ca_ln_g = (const float*)d_in[10];
  const float* ca_ln_b = (const float*)d_in[11];
  const float* blk_wq  = (const float*)d_in[12];
  const float* blk_wk  = (const float*)d_in[13];
  const float* blk_wv  = (const float*)d_in[14];
  const float* blk_wu  = (const float*)d_in[15];
  const float* blk_bu  = (const float*)d_in[16];
  const float* blk_ln1_g = (const float*)d_in[17];
  const float* blk_ln1_b = (const float*)d_in[18];
  const float* blk_w1  = (const float*)d_in[19];
  const float* blk_b1  = (const float*)d_in[20];
  const float* blk_w2  = (const float*)d_in[21];
  const float* blk_b2  = (const float*)d_in[22];
  const float* blk_ln2_g = (const float*)d_in[23];
  const float* blk_ln2_b = (const float*)d_in[24];
  const float* cls_w   = (const float*)d_in[25];
  const float* cls_b   = (const float*)d_in[26];
  float* out = (float*)d_out;

  // ---- workspace layout (bf16 as short) ----
  short* wqT_ca = (short*)d_ws;            // 2048x256 (scaled)
  short* wkT_ca = wqT_ca + 524288;         // 2048x256
  short* wuT_ca = wkT_ca + 524288;         // 256x2048
  short* wv_ca  = wuT_ca + 524288;         // 256x2048
  short* lat_bf = wv_ca + 524288;          // 512x256
  short* wqkT   = lat_bf + 131072;         // 4 x (4096x256)
  short* wvT    = wqkT + 4194304;          // 4 x (2048x256)
  short* wuT_b  = wvT + 2097152;           // 4 x (256x2048)
  short* w1T    = wuT_b + 2097152;         // 4 x (1024x256)
  short* w2T    = w1T + 1048576;           // 4 x (256x1024)
  short* tok_bf = w2T + 1048576;           // 4 x 4096x256
  short* tokT   = tok_bf + 4194304;        // 4 x 256x4096
  short* qCA    = tokT + 4194304;          // 512x2048
  short* qtil   = qCA + 1048576;           // 8 x 512x256
  short* MstT   = qtil + 1048576;          // 256x2048
  short* VtB    = MstT + 524288;           // 32 x 256x512
  short* bufO   = VtB + 4194304;           // (unused)
  short* h1     = bufO + 4194304;          // 2048x1024
  short* z_bf   = h1 + 2097152;            // 2048x256
  float* z      = (float*)(z_bf + 524288); // 2048x256 fp32
  float* zm     = z + 524288;              // spare
  short* Ypart  = (short*)(zm + 1024);     // 8 x 2048x256 bf16 (split-K partials)
  short* Opart  = Ypart + 4194304;         // 4 x (4x8x512x256) bf16 kv-partials
  float* MLp    = (float*)(Opart + 16777216); // 4 x (4x8x512x2) fp32
  short* QKb    = tok_bf;                  // alias: 2048x4096 (after CA)

  const float scale = 0.17677669529663687f; // 1/sqrt(32), folded into Wq
  const int BIG = 1 << 30;

  // ---- weight prep: one batched dispatch (Wq pre-scaled) ----
  TrJobs JB; int nj = 0, base = 0;
  auto addT = [&](const float* s, short* d, int R, int C, long sIn, long sOut,
                  int zc, float sc) {
    int tpz = (C >> 5) * (R >> 5);
    JB.j[nj] = {s, d, R, C, sIn, sOut, 0, tpz, zc, base, sc};
    base += tpz * zc; ++nj;
  };
  auto addC = [&](const float* s, short* d, int nelem) {
    int tpz = nelem >> 13;
    JB.j[nj] = {s, d, 0, 0, 0, 0, 1, tpz, 1, base, 1.f};
    base += tpz; ++nj;
  };
  addT(ca_wq, wqT_ca, 256, 2048, 0, 0, 1, scale);
  addT(ca_wk, wkT_ca, 256, 2048, 0, 0, 1, 1.f);
  addT(ca_wu, wuT_ca, 2048, 256, 0, 0, 1, 1.f);
  addT(blk_wq, wqkT, 256, 2048, 524288, 1048576, 4, scale);
  addT(blk_wk, wqkT + 524288, 256, 2048, 524288, 1048576, 4, 1.f);
  addT(blk_wv, wvT, 256, 2048, 524288, 524288, 4, 1.f);
  addT(blk_wu, wuT_b, 2048, 256, 524288, 524288, 4, 1.f);
  addT(blk_w1, w1T, 256, 1024, 262144, 262144, 4, 1.f);
  addT(blk_w2, w2T, 1024, 256, 262144, 262144, 4, 1.f);
  addC(ca_wv, wv_ca, 524288);
  addC(latents, lat_bf, 131072);
  k_trbatch<<<base, 256, 0, stream>>>(JB, nj);

  // ---- tokens (both layouts, one pass) ----
  k_tokens2<<<dim3(128, 4), 256, 0, stream>>>(x, conv_w, conv_b, pos_emb,
                                              tok_bf, tokT);

  // ---- CA prep: qCA = latents @ Wq ; MstT_h = Wu_h^T @ Wv_h^T (merged) ----
  k_capre<<<96, 256, 0, stream>>>(lat_bf, wqT_ca, wuT_ca, wv_ca, qCA, MstT);
  // qtilde_h = qCA_h @ Wk_h^T
  k_mgemm<0><<<dim3(2, 4, 8), 256, 0, stream>>>(
      qCA, wkT_ca, qtil, nullptr, 256, 2048, 256, 256, 256, 65536, 131072, 1, 8, 1, 8);
  // CA flash: Q=qtilde(h) [pre-scaled], K=tokens(b), Vt=tokensT(b)
  k_mflash10<<<dim3(16, 8, 4), 256, 0, stream>>>(
      qtil, tok_bf, tokT, Opart, MLp, 4096, 256, 256, 4096,
      131072L, 0L, 0L, 1048576L, 0L, 1048576L);
  // Y = combine(Opart) @ MstT^T, split-K x8 (chunk = head) -> bf16 partials
  k_mgemm_att<<<dim3(2, 16, 8), 256, 0, stream>>>(Opart, MLp, MstT, Ypart, 2048);
  k_bias_res_ln<<<2048, 256, 0, stream>>>(Ypart, 8, 524288L, ca_bu, latents, 512,
                                          ca_ln_g, ca_ln_b, z, z_bf);

  // ---- transformer blocks ----
  for (int d = 0; d < 4; ++d) {
    // merged: [Q|K] = z @ wqk  AND  Vt(b,h) = wvT_h @ z_b^T
    k_qkvt<<<768, 256, 0, stream>>>(z_bf, wqkT + (long)d * 1048576,
                                    wvT + (long)d * 524288, QKb, VtB);
    // self flash
    k_mflash10<<<dim3(16, 8, 4), 256, 0, stream>>>(
        QKb, QKb + 2048, VtB, Opart, MLp, 512, 4096, 4096, 512,
        256L, 2097152L, 256L, 2097152L, 131072L, 1048576L);
    // Y = combine(Opart) @ wu^T, split-K x8 (chunk = head) -> bf16 partials
    k_mgemm_att<<<dim3(2, 16, 8), 256, 0, stream>>>(
        Opart, MLp, wuT_b + (long)d * 524288, Ypart, 2048);
    k_bias_res_ln<<<2048, 256, 0, stream>>>(Ypart, 8, 524288L, blk_bu + d * 256, z, 2048,
        blk_ln1_g + d * 256, blk_ln1_b + d * 256, z, z_bf);
    // h1 = gelu(z @ w1 + b1)
    k_mgemm<1><<<dim3(8, 16, 1), 256, 0, stream>>>(
        z_bf, w1T + (long)d * 262144, h1, blk_b1 + d * 1024,
        256, 256, 256, 1024, 0, 0, 0, 1, BIG, 1, BIG);
    // Y = h1 @ w2, split-K x8 (Ksub=128) -> bf16 partials
    k_mgemm<0><<<dim3(2, 16, 8), 256, 0, stream>>>(
        h1, w2T + (long)d * 262144, Ypart, nullptr,
        128, 1024, 1024, 256, 128, 128, 524288, 1, 8, 1, 8);
    k_bias_res_ln<<<2048, 256, 0, stream>>>(Ypart, 8, 524288L, blk_b2 + d * 256, z, 2048,
        blk_ln2_g + d * 256, blk_ln2_b + d * 256, z, z_bf);
  }

  k_meancls<<<dim3(4, 4), 256, 0, stream>>>(z, cls_w, cls_b, out);
}

// Round 15
// 543.583 us; speedup vs baseline: 1.2960x; 1.0060x over previous
//
#include <hip/hip_runtime.h>
#include <hip/hip_bf16.h>
#include <math.h>

// Perceiver: B=4,C=3,N=4096,E=256,H=8,FFE=1024,L=512,D=4,NCLS=1000,HS=2048
// bf16 MFMA everywhere GEMM-shaped; fp32 accum; fp32 LN/residual spine.
// Split-K partials bf16; attn-out GEMM fuses kv-partial combine; merged
// dispatches (prep+tokens, QK+Vt, qCA+MstT); vectorized 8-row LN.

typedef __attribute__((ext_vector_type(8))) short s8v;    // 8 bf16 = 4 VGPR
typedef __attribute__((ext_vector_type(4))) float f32x4;  // 16x16 MFMA accum
typedef __attribute__((ext_vector_type(16))) float f32x16;// 32x32 MFMA accum
typedef __attribute__((ext_vector_type(4))) unsigned u32x4;

__device__ __forceinline__ short f2b(float f) {
  union { float f; unsigned u; } a; a.f = f;
  unsigned r = a.u + 0x7fff + ((a.u >> 16) & 1);
  return (short)(r >> 16);
}
__device__ __forceinline__ float b2f(short s) {
  union { unsigned u; float f; } a; a.u = ((unsigned)(unsigned short)s) << 16;
  return a.f;
}
__device__ __forceinline__ unsigned cvtpk(float lo, float hi) {
  unsigned r;
  asm("v_cvt_pk_bf16_f32 %0, %1, %2" : "=v"(r) : "v"(lo), "v"(hi));
  return r;
}

// async global->LDS, 16B per lane; LDS dest = uniform base + lane*16
__device__ __forceinline__ void gl16(const void* gp, void* lp) {
  __builtin_amdgcn_global_load_lds(
      (const __attribute__((address_space(1))) unsigned int*)gp,
      (__attribute__((address_space(3))) unsigned int*)lp, 16, 0, 0);
}

// ------ merged prep: weight transposes/converts + tokens (tok & tokT) ----
struct TrJob {
  const float* src; short* dst;
  int R, C; long sIn, sOut;
  int mode, tilesPerZ, z, tileBase;
  float scale;
};
struct TrJobs { TrJob j[11]; };

__global__ __launch_bounds__(256) void k_prep(
    TrJobs jb, int njobs, int trBlocks,
    const float* __restrict__ x, const float* __restrict__ cw,
    const float* __restrict__ cb, const float* __restrict__ pe,
    short* __restrict__ tok, short* __restrict__ tokT)
{
  __shared__ float t[32][33];
  int tb = blockIdx.x;
  if (tb >= trBlocks) {             // ---- tokens job ----
    int local = tb - trBlocks;      // 0..511
    int b = local >> 7, n0 = (local & 127) * 32;
    int e = threadIdx.x;
    float c0 = cw[e * 3], c1 = cw[e * 3 + 1], c2 = cw[e * 3 + 2], cbv = cb[e];
    const float* xb = x + b * 12288 + n0;
    short acc[32];
#pragma unroll
    for (int i = 0; i < 32; ++i) {
      int n = n0 + i;
      float s = cbv + pe[n * 256 + e] + xb[i] * c0 + xb[4096 + i] * c1 + xb[8192 + i] * c2;
      short v = f2b(s);
      tok[((long)b * 4096 + n) * 256 + e] = v;
      acc[i] = v;
    }
    short* tr = tokT + ((long)b * 256 + e) * 4096 + n0;
#pragma unroll
    for (int i = 0; i < 4; ++i)
      *reinterpret_cast<s8v*>(tr + i * 8) = *reinterpret_cast<s8v*>(acc + i * 8);
    return;
  }
  int ji = 0;
#pragma unroll
  for (int k = 1; k < 11; ++k)
    if (k < njobs && tb >= jb.j[k].tileBase) ji = k;
  TrJob J = jb.j[ji];
  int local = tb - J.tileBase;
  if (J.mode == 1) {          // flat fp32 -> bf16 (*scale)
    long o = (long)local * 8192 + threadIdx.x;
#pragma unroll
    for (int k = 0; k < 32; ++k)
      J.dst[o + k * 256] = f2b(J.src[o + k * 256] * J.scale);
    return;
  }
  int zi = local / J.tilesPerZ, ti = local - zi * J.tilesPerZ;
  int ntx = J.C >> 5;
  int tx = ti % ntx, ty = ti / ntx;
  const float* ib = J.src + (long)zi * J.sIn;
  short* ob = J.dst + (long)zi * J.sOut;
  int c0 = tx * 32, r0 = ty * 32;
  int lx = threadIdx.x & 31, ly = threadIdx.x >> 5;
#pragma unroll
  for (int i = 0; i < 4; ++i)
    t[ly * 4 + i][lx] = ib[(long)(r0 + ly * 4 + i) * J.C + c0 + lx];
  __syncthreads();
#pragma unroll
  for (int i = 0; i < 4; ++i)
    ob[(long)(c0 + ly * 4 + i) * J.R + r0 + lx] = f2b(t[lx][ly * 4 + i] * J.scale);
}

// ---------------- shared MFMA BT-GEMM core: C = A(MxK) @ Bt(NxK)^T --------
// 128x128 tile, BK=32, 256 thr, prefetch pipeline. K % 64 == 0.
// EPI: 0 = bf16 out, 1 = bias+exact-gelu bf16 out.
template<int EPI>
__device__ __forceinline__ void gemm_core(
    const short* __restrict__ Ab, const short* __restrict__ Bb,
    short* __restrict__ Cb, const float* __restrict__ bias,
    int K, int lda, int ldb, int ldc, long row0, long col0,
    char* As, char* Bs)
{
  int t = threadIdx.x;
  int lane = t & 63, w = t >> 6;
  int wr = w >> 1, wc = w & 1;
  int g = lane >> 4, l15 = lane & 15;
  const f32x4 zz = {0.f, 0.f, 0.f, 0.f};
  f32x4 acc[4][4];
#pragma unroll
  for (int m = 0; m < 4; ++m)
#pragma unroll
    for (int n = 0; n < 4; ++n) acc[m][n] = zz;

  auto mload = [&](s8v* aa, s8v* bb, int kk) {
#pragma unroll
    for (int i = 0; i < 2; ++i) {
      int r = i * 64 + (t >> 2), c = t & 3;
      aa[i] = *(const s8v*)&Ab[(row0 + r) * (long)lda + kk + c * 8];
      bb[i] = *(const s8v*)&Bb[(col0 + r) * (long)ldb + kk + c * 8];
    }
  };
  auto mstore = [&](s8v* aa, s8v* bb) {
#pragma unroll
    for (int i = 0; i < 2; ++i) {
      int r = i * 64 + (t >> 2), c = t & 3;
      int off = (r * 64 + c * 16) ^ ((r & 7) << 4);
      *(s8v*)&As[off] = aa[i];
      *(s8v*)&Bs[off] = bb[i];
    }
  };
  auto mcomp = [&]() {
    s8v af[4], bfr[4];
#pragma unroll
    for (int m = 0; m < 4; ++m) {
      int r = wr * 64 + m * 16 + l15;
      af[m] = *(const s8v*)&As[(r * 64 + g * 16) ^ ((r & 7) << 4)];
    }
#pragma unroll
    for (int n = 0; n < 4; ++n) {
      int r = wc * 64 + n * 16 + l15;
      bfr[n] = *(const s8v*)&Bs[(r * 64 + g * 16) ^ ((r & 7) << 4)];
    }
#pragma unroll
    for (int m = 0; m < 4; ++m)
#pragma unroll
      for (int n = 0; n < 4; ++n)
        acc[m][n] = __builtin_amdgcn_mfma_f32_16x16x32_bf16(af[m], bfr[n], acc[m][n], 0, 0, 0);
  };

  s8v a0[2], b0[2], a1[2], b1[2];
  mload(a0, b0, 0);
  for (int k0 = 0; k0 < K; k0 += 64) {
    __syncthreads(); mstore(a0, b0); __syncthreads();
    mload(a1, b1, k0 + 32);
    mcomp();
    __syncthreads(); mstore(a1, b1); __syncthreads();
    if (k0 + 64 < K) mload(a0, b0, k0 + 64);
    mcomp();
  }

#pragma unroll
  for (int m = 0; m < 4; ++m)
#pragma unroll
    for (int n = 0; n < 4; ++n)
#pragma unroll
      for (int r = 0; r < 4; ++r) {
        long rr = row0 + wr * 64 + m * 16 + g * 4 + r;
        long cc = col0 + wc * 64 + n * 16 + l15;
        float v = acc[m][n][r];
        if (EPI == 1) {
          v += bias[cc];
          v = 0.5f * v * (1.f + erff(v * 0.70710678118654752f));
        }
        Cb[rr * ldc + cc] = f2b(v);
      }
}

// generic batched BT-GEMM kernel (qtil, FF1, FF2)
template<int EPI>
__global__ __launch_bounds__(256) void k_mgemm(
    const short* __restrict__ A, const short* __restrict__ Bt,
    short* __restrict__ Cv, const float* __restrict__ bias,
    int K, int lda, int ldb, int ldc,
    long sA, long sB, long sC, int zdA, int zmA, int zdB, int zmB)
{
  __shared__ char As[8192];
  __shared__ char Bs[8192];
  int z = blockIdx.z;
  const short* Ab = A + ((long)((z / zdA) % zmA)) * sA;
  const short* Bb = Bt + ((long)((z / zdB) % zmB)) * sB;
  gemm_core<EPI>(Ab, Bb, Cv + (long)z * sC, bias, K, lda, ldb, ldc,
                 (long)blockIdx.y * 128, (long)blockIdx.x * 128, As, Bs);
}

// merged per-layer dispatch: QK proj (blocks 0..511) + Vt proj (512..767)
__global__ __launch_bounds__(256) void k_qkvt(
    const short* __restrict__ z_bf, const short* __restrict__ wqkT_d,
    const short* __restrict__ wvT_d, short* __restrict__ QKb,
    short* __restrict__ VtB)
{
  __shared__ char As[8192];
  __shared__ char Bs[8192];
  int bid = blockIdx.x;
  if (bid < 512) {          // [Q|K] = z @ wqk: 2048 x 4096, K=256
    int bx = bid & 31, by = bid >> 5;
    gemm_core<0>(z_bf, wqkT_d, QKb, nullptr, 256, 256, 256, 4096,
                 (long)by * 128, (long)bx * 128, As, Bs);
  } else {                  // Vt(b,h) = wvT_h @ z_b^T: 256 x 512, K=256
    int local = bid - 512;
    int bx = local & 3, rest = local >> 2;
    int by = rest & 1, bz = rest >> 1;    // bz = 0..31
    int hh = bz & 7, bb = bz >> 3;
    gemm_core<0>(wvT_d + hh * 65536, z_bf + (long)bb * 131072,
                 VtB + (long)bz * 131072, nullptr, 256, 256, 256, 512,
                 (long)by * 128, (long)bx * 128, As, Bs);
  }
}

// merged CA prep: qCA (blocks 0..63) + MstT (64..95)
__global__ __launch_bounds__(256) void k_capre(
    const short* __restrict__ lat_bf, const short* __restrict__ wqT_ca,
    const short* __restrict__ wuT_ca, const short* __restrict__ wv_ca,
    short* __restrict__ qCA, short* __restrict__ MstT)
{
  __shared__ char As[8192];
  __shared__ char Bs[8192];
  int bid = blockIdx.x;
  if (bid < 64) {           // qCA = latents @ Wq: 512 x 2048, K=256
    int bx = bid & 15, by = bid >> 4;
    gemm_core<0>(lat_bf, wqT_ca, qCA, nullptr, 256, 256, 256, 2048,
                 (long)by * 128, (long)bx * 128, As, Bs);
  } else {                  // MstT_h = Wu_h^T @ Wv_h^T: 256 x 2048(cols h*256)
    int local = bid - 64;
    int bx = local & 1, by = (local >> 1) & 1, hh = local >> 2;
    gemm_core<0>(wuT_ca + hh * 256, wv_ca + hh * 256, MstT + hh * 256,
                 nullptr, 256, 2048, 2048, 2048,
                 (long)by * 128, (long)bx * 128, As, Bs);
  }
}

// -------- attn-out GEMM with fused kv-partial combine ----
__global__ __launch_bounds__(256) void k_mgemm_att(
    const short* __restrict__ Op,   // [kv4][b4][h8][512][256] bf16
    const float* __restrict__ ML,   // [kv4][b4][h8][512][2] fp32
    const short* __restrict__ Bt,   // (256 out-cols) x (2048) bf16, NxK
    short* __restrict__ Cv,         // bf16 partials [z][2048][256]
    int ldb)
{
  __shared__ char As[8192];
  __shared__ char Bs[8192];
  int z = blockIdx.z;               // head = K-chunk
  int t = threadIdx.x;
  int lane = t & 63, w = t >> 6;
  int wr = w >> 1, wc = w & 1;
  int g = lane >> 4, l15 = lane & 15;
  long row0 = (long)blockIdx.y * 128, col0 = (long)blockIdx.x * 128;
  const long kvs = 4L * 8 * 512;    // rows per kv slice

  long arow[2]; float wgt[2][4];
#pragma unroll
  for (int i = 0; i < 2; ++i) {
    long gr = row0 + i * 64 + (t >> 2);
    int bb = (int)(gr >> 9), q = (int)(gr & 511);
    long base = ((long)bb * 8 + z) * 512 + q;
    arow[i] = base;
    float mm[4], ll[4], M = -1e30f;
#pragma unroll
    for (int kv = 0; kv < 4; ++kv) {
      float2 mlv = *(const float2*)&ML[(kv * kvs + base) * 2];
      mm[kv] = mlv.x; ll[kv] = mlv.y;
      M = fmaxf(M, mm[kv]);
    }
    float ls = 0.f;
#pragma unroll
    for (int kv = 0; kv < 4; ++kv) { mm[kv] = __expf(mm[kv] - M); ls += ll[kv] * mm[kv]; }
    float inv = 1.f / ls;
#pragma unroll
    for (int kv = 0; kv < 4; ++kv) wgt[i][kv] = mm[kv] * inv;
  }

  const f32x4 zz = {0.f, 0.f, 0.f, 0.f};
  f32x4 acc[4][4];
#pragma unroll
  for (int m = 0; m < 4; ++m)
#pragma unroll
    for (int n = 0; n < 4; ++n) acc[m][n] = zz;

  auto mload = [&](s8v* aa, s8v* bb, int kk) {
    int c = t & 3;
#pragma unroll
    for (int i = 0; i < 2; ++i) {
      s8v v0 = *(const s8v*)&Op[(0 * kvs + arow[i]) * 256 + kk + c * 8];
      s8v v1 = *(const s8v*)&Op[(1 * kvs + arow[i]) * 256 + kk + c * 8];
      s8v v2 = *(const s8v*)&Op[(2 * kvs + arow[i]) * 256 + kk + c * 8];
      s8v v3 = *(const s8v*)&Op[(3 * kvs + arow[i]) * 256 + kk + c * 8];
      short o[8];
#pragma unroll
      for (int e = 0; e < 8; ++e)
        o[e] = f2b(wgt[i][0] * b2f(v0[e]) + wgt[i][1] * b2f(v1[e]) +
                   wgt[i][2] * b2f(v2[e]) + wgt[i][3] * b2f(v3[e]));
      aa[i] = *(s8v*)o;
      int r = i * 64 + (t >> 2);
      bb[i] = *(const s8v*)&Bt[(long)z * 256 + (col0 + r) * (long)ldb + kk + c * 8];
    }
  };
  auto mstore = [&](s8v* aa, s8v* bb) {
#pragma unroll
    for (int i = 0; i < 2; ++i) {
      int r = i * 64 + (t >> 2), c = t & 3;
      int off = (r * 64 + c * 16) ^ ((r & 7) << 4);
      *(s8v*)&As[off] = aa[i];
      *(s8v*)&Bs[off] = bb[i];
    }
  };
  auto mcomp = [&]() {
    s8v af[4], bfr[4];
#pragma unroll
    for (int m = 0; m < 4; ++m) {
      int r = wr * 64 + m * 16 + l15;
      af[m] = *(const s8v*)&As[(r * 64 + g * 16) ^ ((r & 7) << 4)];
    }
#pragma unroll
    for (int n = 0; n < 4; ++n) {
      int r = wc * 64 + n * 16 + l15;
      bfr[n] = *(const s8v*)&Bs[(r * 64 + g * 16) ^ ((r & 7) << 4)];
    }
#pragma unroll
    for (int m = 0; m < 4; ++m)
#pragma unroll
      for (int n = 0; n < 4; ++n)
        acc[m][n] = __builtin_amdgcn_mfma_f32_16x16x32_bf16(af[m], bfr[n], acc[m][n], 0, 0, 0);
  };

  s8v a0[2], b0[2], a1[2], b1[2];
  mload(a0, b0, 0);
  for (int k0 = 0; k0 < 256; k0 += 64) {
    __syncthreads(); mstore(a0, b0); __syncthreads();
    mload(a1, b1, k0 + 32);
    mcomp();
    __syncthreads(); mstore(a1, b1); __syncthreads();
    if (k0 + 64 < 256) mload(a0, b0, k0 + 64);
    mcomp();
  }

  long zo = (long)z * 524288;
#pragma unroll
  for (int m = 0; m < 4; ++m)
#pragma unroll
    for (int n = 0; n < 4; ++n)
#pragma unroll
      for (int r = 0; r < 4; ++r) {
        long rr = row0 + wr * 64 + m * 16 + g * 4 + r;
        long cc = col0 + wc * 64 + n * 16 + l15;
        Cv[zo + rr * 256 + cc] = f2b(acc[m][n][r]);
      }
}

// ---------------- MFMA flash attention v10 (head dim 256, 32x32 MFMA) ----
__global__ __launch_bounds__(256, 2) void k_mflash10(
    const short* __restrict__ Qp, const short* __restrict__ Kp,
    const short* __restrict__ Vtp, short* __restrict__ Opart,
    float* __restrict__ MLp,
    int nk, int ldq, int ldk, int ldvt,
    long qh, long qb, long kh, long kb, long vh, long vb)
{
  __shared__ char pool[65536];  // 2 x (K 16KB + V 16KB)
  int t = threadIdx.x, lane = t & 63, w = t >> 6;   // w = 0..3
  int l31 = lane & 31, hi = lane >> 5;
  int h = blockIdx.y, b = blockIdx.z;
  int kv = blockIdx.x & 3, qblk = blockIdx.x >> 2;
  const short* Q  = Qp  + (long)h * qh + (long)b * qb;
  const short* Kg = Kp  + (long)h * kh + (long)b * kb;
  const short* Vg = Vtp + (long)h * vh + (long)b * vb;
  int q0w = qblk * 128 + w * 32;
  int nkq = nk >> 2;
  int NIT = nkq >> 5;           // KVBLK = 32
  long k0 = (long)kv * nkq;

  s8v qf[16];
  {
    const short* Qrow = Q + (long)(q0w + l31) * ldq + hi * 8;
#pragma unroll
    for (int s = 0; s < 16; ++s) qf[s] = *(const s8v*)(Qrow + s * 16);
  }

  const char* KgB = (const char*)Kg;
  const char* VgB = (const char*)Vg;
  unsigned koff[4], voff[4];
#pragma unroll
  for (int c = 0; c < 4; ++c) {
    int r = 8 * w + 2 * c + hi;                 // K tile row 0..31
    koff[c] = (unsigned)((k0 + r) * (long)ldk * 2) + ((l31 ^ r) << 4);
    int rv = 64 * w + 16 * c + (lane >> 2);     // V tile row 0..255
    voff[c] = (unsigned)(((long)rv * ldvt + k0) * 2)
              + (((lane & 3) ^ ((lane >> 3) & 3)) << 4);
  }
  const unsigned kStep = (unsigned)(32 * ldk * 2);

  auto stage = [&](int bsel) {
    char* kd = pool + bsel * 32768 + (w << 12);
    char* vd = kd + 16384;
#pragma unroll
    for (int c = 0; c < 4; ++c) { gl16(KgB + koff[c], kd + c * 1024); koff[c] += kStep; }
#pragma unroll
    for (int c = 0; c < 4; ++c) { gl16(VgB + voff[c], vd + c * 1024); voff[c] += 64; }
  };

  f32x16 accO[8];
#pragma unroll
  for (int n = 0; n < 8; ++n)
#pragma unroll
    for (int i = 0; i < 16; ++i) accO[n][i] = 0.f;
  float mrow = -1e30f, lrow = 0.f;

  stage(0);

  for (int it = 0; it < NIT; ++it) {
    int cur = it & 1;
    asm volatile("s_waitcnt vmcnt(0)" ::: "memory");
    __syncthreads();
    if (it + 1 < NIT) stage(cur ^ 1);
    const char* kls = pool + cur * 32768;
    const char* vls = kls + 16384;

    f32x16 sacc;
#pragma unroll
    for (int i = 0; i < 16; ++i) sacc[i] = 0.f;
    __builtin_amdgcn_s_setprio(1);
#pragma unroll
    for (int s = 0; s < 16; ++s) {
      s8v kf = *(const s8v*)&kls[l31 * 512 + (((2 * s + hi) ^ l31) << 4)];
      sacc = __builtin_amdgcn_mfma_f32_32x32x16_bf16(kf, qf[s], sacc, 0, 0, 0);
    }
    __builtin_amdgcn_s_setprio(0);

    float mt = sacc[0];
#pragma unroll
    for (int i = 1; i < 16; ++i) mt = fmaxf(mt, sacc[i]);
    mt = fmaxf(mt, __shfl_xor(mt, 32));
    if (__any(mt - mrow > 8.f)) {       // defer-max (T13)
      float mn = fmaxf(mrow, mt);
      float al = __expf(mrow - mn);
      mrow = mn; lrow *= al;
#pragma unroll
      for (int r = 0; r < 16; ++r) {
        float alr = __shfl(al, (r & 3) + 8 * (r >> 2) + 4 * hi);
#pragma unroll
        for (int n = 0; n < 8; ++n) accO[n][r] *= alr;
      }
    }
    float ls = 0.f;
#pragma unroll
    for (int i = 0; i < 16; ++i) {
      float p = __expf(sacc[i] - mrow);
      sacc[i] = p; ls += p;
    }
    ls += __shfl_xor(ls, 32);
    lrow += ls;

    s8v pa[2];
#pragma unroll
    for (int s2 = 0; s2 < 2; ++s2) {
      int r0 = s2 * 8;
      unsigned w0 = cvtpk(sacc[r0 + 0], sacc[r0 + 1]);
      unsigned w1 = cvtpk(sacc[r0 + 2], sacc[r0 + 3]);
      unsigned w2 = cvtpk(sacc[r0 + 4], sacc[r0 + 5]);
      unsigned w3 = cvtpk(sacc[r0 + 6], sacc[r0 + 7]);
      unsigned x0 = (unsigned)__shfl_xor((int)w0, 32);
      unsigned x1 = (unsigned)__shfl_xor((int)w1, 32);
      unsigned x2 = (unsigned)__shfl_xor((int)w2, 32);
      unsigned x3 = (unsigned)__shfl_xor((int)w3, 32);
      u32x4 pw;
      pw.x = hi ? x2 : w0;
      pw.y = hi ? x3 : w1;
      pw.z = hi ? w2 : x0;
      pw.w = hi ? w3 : x1;
      pa[s2] = *(s8v*)&pw;
    }

    __builtin_amdgcn_s_setprio(1);
#pragma unroll
    for (int n = 0; n < 8; ++n) {
      int rv = n * 32 + l31;
#pragma unroll
      for (int s2 = 0; s2 < 2; ++s2) {
        s8v vf = *(const s8v*)&vls[rv * 64 + (((2 * s2 + hi) ^ ((l31 >> 1) & 3)) << 4)];
        accO[n] = __builtin_amdgcn_mfma_f32_32x32x16_bf16(pa[s2], vf, accO[n], 0, 0, 0);
      }
    }
    __builtin_amdgcn_s_setprio(0);
  }

  long prow = (((long)kv * 4 + b) * 8 + h) * 512;
  short* Ob = Opart + prow * 256;
  float* MLb = MLp + prow * 2;
  if (lane < 32) {
    MLb[(q0w + l31) * 2] = mrow;
    MLb[(q0w + l31) * 2 + 1] = lrow;
  }
  __syncthreads();                          // loop traffic done; reuse pool
  float* st = (float*)(pool + w * 4096);    // wave-private 4KB
  int orow = lane >> 1, ohalf = lane & 1;
#pragma unroll
  for (int n = 0; n < 8; ++n) {
#pragma unroll
    for (int r = 0; r < 16; ++r) {
      int ql = (r & 3) + 8 * (r >> 2) + 4 * hi;
      st[ql * 32 + l31] = accO[n][r];
    }
    short obuf[16];
#pragma unroll
    for (int jj = 0; jj < 4; ++jj) {
      f32x4 v = *(const f32x4*)&st[orow * 32 + ohalf * 16 + jj * 4];
      obuf[jj * 4 + 0] = f2b(v.x); obuf[jj * 4 + 1] = f2b(v.y);
      obuf[jj * 4 + 2] = f2b(v.z); obuf[jj * 4 + 3] = f2b(v.w);
    }
    short* dst = Ob + (long)(q0w + orow) * 256 + n * 32 + ohalf * 16;
    *(s8v*)(dst) = *(s8v*)&obuf[0];
    *(s8v*)(dst + 8) = *(s8v*)&obuf[8];
  }
}

// ------ z = LN(sum(bf16 Ypart) + bias + res), vectorized 8 rows/block ----
__global__ __launch_bounds__(256) void k_bias_res_ln(
    const short* __restrict__ Yp, int nPart, long pStride,
    const float* __restrict__ bias,
    const float* __restrict__ res, int resMod,
    const float* __restrict__ g, const float* __restrict__ bta,
    float* __restrict__ out, short* __restrict__ out_bf)
{
  int t = threadIdx.x;
  int rloc = t >> 5, l32 = t & 31;
  long row = (long)blockIdx.x * 8 + rloc;
  int e0 = l32 * 8;
  float v[8];
  const float* rp = res + (row % resMod) * 256 + e0;
  const float* bp = bias + e0;
#pragma unroll
  for (int j = 0; j < 8; ++j) v[j] = bp[j] + rp[j];
  for (int s = 0; s < nPart; ++s) {
    s8v yv = *(const s8v*)&Yp[s * pStride + row * 256 + e0];
#pragma unroll
    for (int j = 0; j < 8; ++j) v[j] += b2f(yv[j]);
  }
  float s1 = 0.f;
#pragma unroll
  for (int j = 0; j < 8; ++j) s1 += v[j];
#pragma unroll
  for (int o = 1; o < 32; o <<= 1) s1 += __shfl_xor(s1, o);
  float mean = s1 * (1.f / 256.f);
  float s2 = 0.f;
#pragma unroll
  for (int j = 0; j < 8; ++j) { v[j] -= mean; s2 += v[j] * v[j]; }
#pragma unroll
  for (int o = 1; o < 32; o <<= 1) s2 += __shfl_xor(s2, o);
  float rs = rsqrtf(s2 * (1.f / 256.f) + 1e-5f);
  float of[8]; short ob[8];
#pragma unroll
  for (int j = 0; j < 8; ++j) {
    float o = g[e0 + j] * v[j] * rs + bta[e0 + j];
    of[j] = o; ob[j] = f2b(o);
  }
  float* op = out + row * 256 + e0;
  *(f32x4*)(op) = *(f32x4*)&of[0];
  *(f32x4*)(op + 4) = *(f32x4*)&of[4];
  *(s8v*)&out_bf[row * 256 + e0] = *(s8v*)ob;
}

// ---------------- fused mean-over-latents + classifier ----------------
__global__ __launch_bounds__(256) void k_meancls(
    const float* __restrict__ z, const float* __restrict__ w,
    const float* __restrict__ bias, float* __restrict__ out)
{
  __shared__ float zms[256];
  int b = blockIdx.y, e = threadIdx.x;
  float s = 0.f;
  for (int l = 0; l < 512; ++l) s += z[((long)b * 512 + l) * 256 + e];
  zms[e] = s * (1.f / 512.f);
  __syncthreads();
  int j = blockIdx.x * 256 + e;
  if (j >= 1000) return;
  float acc = bias[j];
  for (int e2 = 0; e2 < 256; ++e2) acc += zms[e2] * w[e2 * 1000 + j];
  out[b * 1000 + j] = acc;
}

extern "C" void kernel_launch(void* const* d_in, const int* in_sizes, int n_in,
                              void* d_out, int out_size, void* d_ws, size_t ws_size,
                              hipStream_t stream)
{
  (void)in_sizes; (void)n_in; (void)out_size; (void)ws_size;
  const float* x       = (const float*)d_in[0];
  const float* conv_w  = (const float*)d_in[1];
  const float* conv_b  = (const float*)d_in[2];
  const float* pos_emb = (const float*)d_in[3];
  const float* latents = (const float*)d_in[4];
  const float* ca_wq   = (const float*)d_in[5];
  const float* ca_wk   = (const float*)d_in[6];
  const float* ca_wv   = (const float*)d_in[7];
  const float* ca_wu   = (const float*)d_in[8];
  const float* ca_bu   = (const float*)d_in[9];
  const float* ca_ln_g = (const float*)d_in[10];
  const float* ca_ln_b = (const float*)d_in[11];
  const float* blk_wq  = (const float*)d_in[12];
  const float* blk_wk  = (const float*)d_in[13];
  const float* blk_wv  = (const float*)d_in[14];
  const float* blk_wu  = (const float*)d_in[15];
  const float* blk_bu  = (const float*)d_in[16];
  const float* blk_ln1_g = (const float*)d_in[17];
  const float* blk_ln1_b = (const float*)d_in[18];
  const float* blk_w1  = (const float*)d_in[19];
  const float* blk_b1  = (const float*)d_in[20];
  const float* blk_w2  = (const float*)d_in[21];
  const float* blk_b2  = (const float*)d_in[22];
  const float* blk_ln2_g = (const float*)d_in[23];
  const float* blk_ln2_b = (const float*)d_in[24];
  const float* cls_w   = (const float*)d_in[25];
  const float* cls_b   = (const float*)d_in[26];
  float* out = (float*)d_out;

  // ---- workspace layout (bf16 as short) ----
  short* wqT_ca = (short*)d_ws;            // 2048x256 (scaled)
  short* wkT_ca = wqT_ca + 524288;         // 2048x256
  short* wuT_ca = wkT_ca + 524288;         // 256x2048
  short* wv_ca  = wuT_ca + 524288;         // 256x2048
  short* lat_bf = wv_ca + 524288;          // 512x256
  short* wqkT   = lat_bf + 131072;         // 4 x (4096x256)
  short* wvT    = wqkT + 4194304;          // 4 x (2048x256)
  short* wuT_b  = wvT + 2097152;           // 4 x (256x2048)
  short* w1T    = wuT_b + 2097152;         // 4 x (1024x256)
  short* w2T    = w1T + 1048576;           // 4 x (256x1024)
  short* tok_bf = w2T + 1048576;           // 4 x 4096x256
  short* tokT   = tok_bf + 4194304;        // 4 x 256x4096
  short* qCA    = tokT + 4194304;          // 512x2048
  short* qtil   = qCA + 1048576;           // 8 x 512x256
  short* MstT   = qtil + 1048576;          // 256x2048
  short* VtB    = MstT + 524288;           // 32 x 256x512
  short* bufO   = VtB + 4194304;           // (unused)
  short* h1     = bufO + 4194304;          // 2048x1024
  short* z_bf   = h1 + 2097152;            // 2048x256
  float* z      = (float*)(z_bf + 524288); // 2048x256 fp32
  float* zm     = z + 524288;              // spare
  short* Ypart  = (short*)(zm + 1024);     // 8 x 2048x256 bf16 (split-K partials)
  short* Opart  = Ypart + 4194304;         // 4 x (4x8x512x256) bf16 kv-partials
  float* MLp    = (float*)(Opart + 16777216); // 4 x (4x8x512x2) fp32
  short* QKb    = tok_bf;                  // alias: 2048x4096 (after CA)

  const float scale = 0.17677669529663687f; // 1/sqrt(32), folded into Wq
  const int BIG = 1 << 30;

  // ---- prep: weights + tokens in ONE dispatch ----
  TrJobs JB; int nj = 0, base = 0;
  auto addT = [&](const float* s, short* d, int R, int C, long sIn, long sOut,
                  int zc, float sc) {
    int tpz = (C >> 5) * (R >> 5);
    JB.j[nj] = {s, d, R, C, sIn, sOut, 0, tpz, zc, base, sc};
    base += tpz * zc; ++nj;
  };
  auto addC = [&](const float* s, short* d, int nelem) {
    int tpz = nelem >> 13;
    JB.j[nj] = {s, d, 0, 0, 0, 0, 1, tpz, 1, base, 1.f};
    base += tpz; ++nj;
  };
  addT(ca_wq, wqT_ca, 256, 2048, 0, 0, 1, scale);
  addT(ca_wk, wkT_ca, 256, 2048, 0, 0, 1, 1.f);
  addT(ca_wu, wuT_ca, 2048, 256, 0, 0, 1, 1.f);
  addT(blk_wq, wqkT, 256, 2048, 524288, 1048576, 4, scale);
  addT(blk_wk, wqkT + 524288, 256, 2048, 524288, 1048576, 4, 1.f);
  addT(blk_wv, wvT, 256, 2048, 524288, 524288, 4, 1.f);
  addT(blk_wu, wuT_b, 2048, 256, 524288, 524288, 4, 1.f);
  addT(blk_w1, w1T, 256, 1024, 262144, 262144, 4, 1.f);
  addT(blk_w2, w2T, 1024, 256, 262144, 262144, 4, 1.f);
  addC(ca_wv, wv_ca, 524288);
  addC(latents, lat_bf, 131072);
  k_prep<<<base + 512, 256, 0, stream>>>(JB, nj, base, x, conv_w, conv_b,
                                         pos_emb, tok_bf, tokT);

  // ---- CA prep: qCA = latents @ Wq ; MstT_h = Wu_h^T @ Wv_h^T (merged) ----
  k_capre<<<96, 256, 0, stream>>>(lat_bf, wqT_ca, wuT_ca, wv_ca, qCA, MstT);
  // qtilde_h = qCA_h @ Wk_h^T
  k_mgemm<0><<<dim3(2, 4, 8), 256, 0, stream>>>(
      qCA, wkT_ca, qtil, nullptr, 256, 2048, 256, 256, 256, 65536, 131072, 1, 8, 1, 8);
  // CA flash: Q=qtilde(h) [pre-scaled], K=tokens(b), Vt=tokensT(b)
  k_mflash10<<<dim3(16, 8, 4), 256, 0, stream>>>(
      qtil, tok_bf, tokT, Opart, MLp, 4096, 256, 256, 4096,
      131072L, 0L, 0L, 1048576L, 0L, 1048576L);
  // Y = combine(Opart) @ MstT^T, split-K x8 (chunk = head) -> bf16 partials
  k_mgemm_att<<<dim3(2, 16, 8), 256, 0, stream>>>(Opart, MLp, MstT, Ypart, 2048);
  k_bias_res_ln<<<256, 256, 0, stream>>>(Ypart, 8, 524288L, ca_bu, latents, 512,
                                         ca_ln_g, ca_ln_b, z, z_bf);

  // ---- transformer blocks ----
  for (int d = 0; d < 4; ++d) {
    // merged: [Q|K] = z @ wqk  AND  Vt(b,h) = wvT_h @ z_b^T
    k_qkvt<<<768, 256, 0, stream>>>(z_bf, wqkT + (long)d * 1048576,
                                    wvT + (long)d * 524288, QKb, VtB);
    // self flash
    k_mflash10<<<dim3(16, 8, 4), 256, 0, stream>>>(
        QKb, QKb + 2048, VtB, Opart, MLp, 512, 4096, 4096, 512,
        256L, 2097152L, 256L, 2097152L, 131072L, 1048576L);
    // Y = combine(Opart) @ wu^T, split-K x8 (chunk = head) -> bf16 partials
    k_mgemm_att<<<dim3(2, 16, 8), 256, 0, stream>>>(
        Opart, MLp, wuT_b + (long)d * 524288, Ypart, 2048);
    k_bias_res_ln<<<256, 256, 0, stream>>>(Ypart, 8, 524288L, blk_bu + d * 256, z, 2048,
        blk_ln1_g + d * 256, blk_ln1_b + d * 256, z, z_bf);
    // h1 = gelu(z @ w1 + b1)
    k_mgemm<1><<<dim3(8, 16, 1), 256, 0, stream>>>(
        z_bf, w1T + (long)d * 262144, h1, blk_b1 + d * 1024,
        256, 256, 256, 1024, 0, 0, 0, 1, BIG, 1, BIG);
    // Y = h1 @ w2, split-K x8 (Ksub=128) -> bf16 partials
    k_mgemm<0><<<dim3(2, 16, 8), 256, 0, stream>>>(
        h1, w2T + (long)d * 262144, Ypart, nullptr,
        128, 1024, 1024, 256, 128, 128, 524288, 1, 8, 1, 8);
    k_bias_res_ln<<<256, 256, 0, stream>>>(Ypart, 8, 524288L, blk_b2 + d * 256, z, 2048,
        blk_ln2_g + d * 256, blk_ln2_b + d * 256, z, z_bf);
  }

  k_meancls<<<dim3(4, 4), 256, 0, stream>>>(z, cls_w, cls_b, out);
}

// Round 16
// 536.920 us; speedup vs baseline: 1.3120x; 1.0124x over previous
//
#include <hip/hip_runtime.h>
#include <hip/hip_bf16.h>
#include <math.h>

// Perceiver: B=4,C=3,N=4096,E=256,H=8,FFE=1024,L=512,D=4,NCLS=1000,HS=2048
// bf16 MFMA everywhere GEMM-shaped; fp32 accum; fp32 LN/residual spine.
// Split-K partials bf16; attn-out GEMM fuses kv-partial combine; merged
// dispatches; vectorized LN; self-attn kv-split x2 (CA x4).

typedef __attribute__((ext_vector_type(8))) short s8v;    // 8 bf16 = 4 VGPR
typedef __attribute__((ext_vector_type(4))) float f32x4;  // 16x16 MFMA accum
typedef __attribute__((ext_vector_type(16))) float f32x16;// 32x32 MFMA accum
typedef __attribute__((ext_vector_type(4))) unsigned u32x4;

__device__ __forceinline__ short f2b(float f) {
  union { float f; unsigned u; } a; a.f = f;
  unsigned r = a.u + 0x7fff + ((a.u >> 16) & 1);
  return (short)(r >> 16);
}
__device__ __forceinline__ float b2f(short s) {
  union { unsigned u; float f; } a; a.u = ((unsigned)(unsigned short)s) << 16;
  return a.f;
}
__device__ __forceinline__ unsigned cvtpk(float lo, float hi) {
  unsigned r;
  asm("v_cvt_pk_bf16_f32 %0, %1, %2" : "=v"(r) : "v"(lo), "v"(hi));
  return r;
}

// async global->LDS, 16B per lane; LDS dest = uniform base + lane*16
__device__ __forceinline__ void gl16(const void* gp, void* lp) {
  __builtin_amdgcn_global_load_lds(
      (const __attribute__((address_space(1))) unsigned int*)gp,
      (__attribute__((address_space(3))) unsigned int*)lp, 16, 0, 0);
}

// ------ merged prep: weight transposes/converts + tokens (tok & tokT) ----
struct TrJob {
  const float* src; short* dst;
  int R, C; long sIn, sOut;
  int mode, tilesPerZ, z, tileBase;
  float scale;
};
struct TrJobs { TrJob j[11]; };

__global__ __launch_bounds__(256) void k_prep(
    TrJobs jb, int njobs, int trBlocks,
    const float* __restrict__ x, const float* __restrict__ cw,
    const float* __restrict__ cb, const float* __restrict__ pe,
    short* __restrict__ tok, short* __restrict__ tokT)
{
  __shared__ float t[32][33];
  int tb = blockIdx.x;
  if (tb >= trBlocks) {             // ---- tokens job ----
    int local = tb - trBlocks;      // 0..511
    int b = local >> 7, n0 = (local & 127) * 32;
    int e = threadIdx.x;
    float c0 = cw[e * 3], c1 = cw[e * 3 + 1], c2 = cw[e * 3 + 2], cbv = cb[e];
    const float* xb = x + b * 12288 + n0;
    short acc[32];
#pragma unroll
    for (int i = 0; i < 32; ++i) {
      int n = n0 + i;
      float s = cbv + pe[n * 256 + e] + xb[i] * c0 + xb[4096 + i] * c1 + xb[8192 + i] * c2;
      short v = f2b(s);
      tok[((long)b * 4096 + n) * 256 + e] = v;
      acc[i] = v;
    }
    short* tr = tokT + ((long)b * 256 + e) * 4096 + n0;
#pragma unroll
    for (int i = 0; i < 4; ++i)
      *reinterpret_cast<s8v*>(tr + i * 8) = *reinterpret_cast<s8v*>(acc + i * 8);
    return;
  }
  int ji = 0;
#pragma unroll
  for (int k = 1; k < 11; ++k)
    if (k < njobs && tb >= jb.j[k].tileBase) ji = k;
  TrJob J = jb.j[ji];
  int local = tb - J.tileBase;
  if (J.mode == 1) {          // flat fp32 -> bf16 (*scale)
    long o = (long)local * 8192 + threadIdx.x;
#pragma unroll
    for (int k = 0; k < 32; ++k)
      J.dst[o + k * 256] = f2b(J.src[o + k * 256] * J.scale);
    return;
  }
  int zi = local / J.tilesPerZ, ti = local - zi * J.tilesPerZ;
  int ntx = J.C >> 5;
  int tx = ti % ntx, ty = ti / ntx;
  const float* ib = J.src + (long)zi * J.sIn;
  short* ob = J.dst + (long)zi * J.sOut;
  int c0 = tx * 32, r0 = ty * 32;
  int lx = threadIdx.x & 31, ly = threadIdx.x >> 5;
#pragma unroll
  for (int i = 0; i < 4; ++i)
    t[ly * 4 + i][lx] = ib[(long)(r0 + ly * 4 + i) * J.C + c0 + lx];
  __syncthreads();
#pragma unroll
  for (int i = 0; i < 4; ++i)
    ob[(long)(c0 + ly * 4 + i) * J.R + r0 + lx] = f2b(t[lx][ly * 4 + i] * J.scale);
}

// ---------------- shared MFMA BT-GEMM core: C = A(MxK) @ Bt(NxK)^T --------
// 128x128 tile, BK=32, 256 thr, prefetch pipeline. K % 64 == 0.
template<int EPI>
__device__ __forceinline__ void gemm_core(
    const short* __restrict__ Ab, const short* __restrict__ Bb,
    short* __restrict__ Cb, const float* __restrict__ bias,
    int K, int lda, int ldb, int ldc, long row0, long col0,
    char* As, char* Bs)
{
  int t = threadIdx.x;
  int lane = t & 63, w = t >> 6;
  int wr = w >> 1, wc = w & 1;
  int g = lane >> 4, l15 = lane & 15;
  const f32x4 zz = {0.f, 0.f, 0.f, 0.f};
  f32x4 acc[4][4];
#pragma unroll
  for (int m = 0; m < 4; ++m)
#pragma unroll
    for (int n = 0; n < 4; ++n) acc[m][n] = zz;

  auto mload = [&](s8v* aa, s8v* bb, int kk) {
#pragma unroll
    for (int i = 0; i < 2; ++i) {
      int r = i * 64 + (t >> 2), c = t & 3;
      aa[i] = *(const s8v*)&Ab[(row0 + r) * (long)lda + kk + c * 8];
      bb[i] = *(const s8v*)&Bb[(col0 + r) * (long)ldb + kk + c * 8];
    }
  };
  auto mstore = [&](s8v* aa, s8v* bb) {
#pragma unroll
    for (int i = 0; i < 2; ++i) {
      int r = i * 64 + (t >> 2), c = t & 3;
      int off = (r * 64 + c * 16) ^ ((r & 7) << 4);
      *(s8v*)&As[off] = aa[i];
      *(s8v*)&Bs[off] = bb[i];
    }
  };
  auto mcomp = [&]() {
    s8v af[4], bfr[4];
#pragma unroll
    for (int m = 0; m < 4; ++m) {
      int r = wr * 64 + m * 16 + l15;
      af[m] = *(const s8v*)&As[(r * 64 + g * 16) ^ ((r & 7) << 4)];
    }
#pragma unroll
    for (int n = 0; n < 4; ++n) {
      int r = wc * 64 + n * 16 + l15;
      bfr[n] = *(const s8v*)&Bs[(r * 64 + g * 16) ^ ((r & 7) << 4)];
    }
#pragma unroll
    for (int m = 0; m < 4; ++m)
#pragma unroll
      for (int n = 0; n < 4; ++n)
        acc[m][n] = __builtin_amdgcn_mfma_f32_16x16x32_bf16(af[m], bfr[n], acc[m][n], 0, 0, 0);
  };

  s8v a0[2], b0[2], a1[2], b1[2];
  mload(a0, b0, 0);
  for (int k0 = 0; k0 < K; k0 += 64) {
    __syncthreads(); mstore(a0, b0); __syncthreads();
    mload(a1, b1, k0 + 32);
    mcomp();
    __syncthreads(); mstore(a1, b1); __syncthreads();
    if (k0 + 64 < K) mload(a0, b0, k0 + 64);
    mcomp();
  }

#pragma unroll
  for (int m = 0; m < 4; ++m)
#pragma unroll
    for (int n = 0; n < 4; ++n)
#pragma unroll
      for (int r = 0; r < 4; ++r) {
        long rr = row0 + wr * 64 + m * 16 + g * 4 + r;
        long cc = col0 + wc * 64 + n * 16 + l15;
        float v = acc[m][n][r];
        if (EPI == 1) {
          v += bias[cc];
          v = 0.5f * v * (1.f + erff(v * 0.70710678118654752f));
        }
        Cb[rr * ldc + cc] = f2b(v);
      }
}

// generic batched BT-GEMM kernel (qtil, FF1, FF2)
template<int EPI>
__global__ __launch_bounds__(256) void k_mgemm(
    const short* __restrict__ A, const short* __restrict__ Bt,
    short* __restrict__ Cv, const float* __restrict__ bias,
    int K, int lda, int ldb, int ldc,
    long sA, long sB, long sC, int zdA, int zmA, int zdB, int zmB)
{
  __shared__ char As[8192];
  __shared__ char Bs[8192];
  int z = blockIdx.z;
  const short* Ab = A + ((long)((z / zdA) % zmA)) * sA;
  const short* Bb = Bt + ((long)((z / zdB) % zmB)) * sB;
  gemm_core<EPI>(Ab, Bb, Cv + (long)z * sC, bias, K, lda, ldb, ldc,
                 (long)blockIdx.y * 128, (long)blockIdx.x * 128, As, Bs);
}

// merged per-layer dispatch: QK proj (blocks 0..511) + Vt proj (512..767)
__global__ __launch_bounds__(256) void k_qkvt(
    const short* __restrict__ z_bf, const short* __restrict__ wqkT_d,
    const short* __restrict__ wvT_d, short* __restrict__ QKb,
    short* __restrict__ VtB)
{
  __shared__ char As[8192];
  __shared__ char Bs[8192];
  int bid = blockIdx.x;
  if (bid < 512) {          // [Q|K] = z @ wqk: 2048 x 4096, K=256
    int bx = bid & 31, by = bid >> 5;
    gemm_core<0>(z_bf, wqkT_d, QKb, nullptr, 256, 256, 256, 4096,
                 (long)by * 128, (long)bx * 128, As, Bs);
  } else {                  // Vt(b,h) = wvT_h @ z_b^T: 256 x 512, K=256
    int local = bid - 512;
    int bx = local & 3, rest = local >> 2;
    int by = rest & 1, bz = rest >> 1;    // bz = 0..31
    int hh = bz & 7, bb = bz >> 3;
    gemm_core<0>(wvT_d + hh * 65536, z_bf + (long)bb * 131072,
                 VtB + (long)bz * 131072, nullptr, 256, 256, 256, 512,
                 (long)by * 128, (long)bx * 128, As, Bs);
  }
}

// merged CA prep: qCA (blocks 0..63) + MstT (64..95)
__global__ __launch_bounds__(256) void k_capre(
    const short* __restrict__ lat_bf, const short* __restrict__ wqT_ca,
    const short* __restrict__ wuT_ca, const short* __restrict__ wv_ca,
    short* __restrict__ qCA, short* __restrict__ MstT)
{
  __shared__ char As[8192];
  __shared__ char Bs[8192];
  int bid = blockIdx.x;
  if (bid < 64) {           // qCA = latents @ Wq: 512 x 2048, K=256
    int bx = bid & 15, by = bid >> 4;
    gemm_core<0>(lat_bf, wqT_ca, qCA, nullptr, 256, 256, 256, 2048,
                 (long)by * 128, (long)bx * 128, As, Bs);
  } else {                  // MstT_h = Wu_h^T @ Wv_h^T: 256 x 2048(cols h*256)
    int local = bid - 64;
    int bx = local & 1, by = (local >> 1) & 1, hh = local >> 2;
    gemm_core<0>(wuT_ca + hh * 256, wv_ca + hh * 256, MstT + hh * 256,
                 nullptr, 256, 2048, 2048, 2048,
                 (long)by * 128, (long)bx * 128, As, Bs);
  }
}

// -------- attn-out GEMM with fused NKV-way kv-partial combine ----
template<int NKV>
__global__ __launch_bounds__(256) void k_mgemm_att(
    const short* __restrict__ Op,   // [kv][b4][h8][512][256] bf16
    const float* __restrict__ ML,   // [kv][b4][h8][512][2] fp32
    const short* __restrict__ Bt,   // (256 out-cols) x (2048) bf16, NxK
    short* __restrict__ Cv,         // bf16 partials [z][2048][256]
    int ldb)
{
  __shared__ char As[8192];
  __shared__ char Bs[8192];
  int z = blockIdx.z;               // head = K-chunk
  int t = threadIdx.x;
  int lane = t & 63, w = t >> 6;
  int wr = w >> 1, wc = w & 1;
  int g = lane >> 4, l15 = lane & 15;
  long row0 = (long)blockIdx.y * 128, col0 = (long)blockIdx.x * 128;
  const long kvs = 4L * 8 * 512;    // rows per kv slice

  long arow[2]; float wgt[2][NKV];
#pragma unroll
  for (int i = 0; i < 2; ++i) {
    long gr = row0 + i * 64 + (t >> 2);
    int bb = (int)(gr >> 9), q = (int)(gr & 511);
    long base = ((long)bb * 8 + z) * 512 + q;
    arow[i] = base;
    float mm[NKV], ll[NKV], M = -1e30f;
#pragma unroll
    for (int kv = 0; kv < NKV; ++kv) {
      float2 mlv = *(const float2*)&ML[(kv * kvs + base) * 2];
      mm[kv] = mlv.x; ll[kv] = mlv.y;
      M = fmaxf(M, mm[kv]);
    }
    float ls = 0.f;
#pragma unroll
    for (int kv = 0; kv < NKV; ++kv) { mm[kv] = __expf(mm[kv] - M); ls += ll[kv] * mm[kv]; }
    float inv = 1.f / ls;
#pragma unroll
    for (int kv = 0; kv < NKV; ++kv) wgt[i][kv] = mm[kv] * inv;
  }

  const f32x4 zz = {0.f, 0.f, 0.f, 0.f};
  f32x4 acc[4][4];
#pragma unroll
  for (int m = 0; m < 4; ++m)
#pragma unroll
    for (int n = 0; n < 4; ++n) acc[m][n] = zz;

  auto mload = [&](s8v* aa, s8v* bb, int kk) {
    int c = t & 3;
#pragma unroll
    for (int i = 0; i < 2; ++i) {
      float acc8[8];
#pragma unroll
      for (int e = 0; e < 8; ++e) acc8[e] = 0.f;
#pragma unroll
      for (int kv = 0; kv < NKV; ++kv) {
        s8v vv = *(const s8v*)&Op[(kv * kvs + arow[i]) * 256 + kk + c * 8];
#pragma unroll
        for (int e = 0; e < 8; ++e) acc8[e] += wgt[i][kv] * b2f(vv[e]);
      }
      short o[8];
#pragma unroll
      for (int e = 0; e < 8; ++e) o[e] = f2b(acc8[e]);
      aa[i] = *(s8v*)o;
      int r = i * 64 + (t >> 2);
      bb[i] = *(const s8v*)&Bt[(long)z * 256 + (col0 + r) * (long)ldb + kk + c * 8];
    }
  };
  auto mstore = [&](s8v* aa, s8v* bb) {
#pragma unroll
    for (int i = 0; i < 2; ++i) {
      int r = i * 64 + (t >> 2), c = t & 3;
      int off = (r * 64 + c * 16) ^ ((r & 7) << 4);
      *(s8v*)&As[off] = aa[i];
      *(s8v*)&Bs[off] = bb[i];
    }
  };
  auto mcomp = [&]() {
    s8v af[4], bfr[4];
#pragma unroll
    for (int m = 0; m < 4; ++m) {
      int r = wr * 64 + m * 16 + l15;
      af[m] = *(const s8v*)&As[(r * 64 + g * 16) ^ ((r & 7) << 4)];
    }
#pragma unroll
    for (int n = 0; n < 4; ++n) {
      int r = wc * 64 + n * 16 + l15;
      bfr[n] = *(const s8v*)&Bs[(r * 64 + g * 16) ^ ((r & 7) << 4)];
    }
#pragma unroll
    for (int m = 0; m < 4; ++m)
#pragma unroll
      for (int n = 0; n < 4; ++n)
        acc[m][n] = __builtin_amdgcn_mfma_f32_16x16x32_bf16(af[m], bfr[n], acc[m][n], 0, 0, 0);
  };

  s8v a0[2], b0[2], a1[2], b1[2];
  mload(a0, b0, 0);
  for (int k0 = 0; k0 < 256; k0 += 64) {
    __syncthreads(); mstore(a0, b0); __syncthreads();
    mload(a1, b1, k0 + 32);
    mcomp();
    __syncthreads(); mstore(a1, b1); __syncthreads();
    if (k0 + 64 < 256) mload(a0, b0, k0 + 64);
    mcomp();
  }

  long zo = (long)z * 524288;
#pragma unroll
  for (int m = 0; m < 4; ++m)
#pragma unroll
    for (int n = 0; n < 4; ++n)
#pragma unroll
      for (int r = 0; r < 4; ++r) {
        long rr = row0 + wr * 64 + m * 16 + g * 4 + r;
        long cc = col0 + wc * 64 + n * 16 + l15;
        Cv[zo + rr * 256 + cc] = f2b(acc[m][n][r]);
      }
}

// ---------------- MFMA flash attention v10 (head dim 256, 32x32 MFMA) ----
// 4 waves x 32 q-rows = 128 q/block, KVBLK=32, LDS 64KB -> 2 blocks/CU.
// kv-split x nkv (runtime) to partials; coalesced Opart epilogue.
__global__ __launch_bounds__(256, 2) void k_mflash10(
    const short* __restrict__ Qp, const short* __restrict__ Kp,
    const short* __restrict__ Vtp, short* __restrict__ Opart,
    float* __restrict__ MLp,
    int nk, int nkv, int ldq, int ldk, int ldvt,
    long qh, long qb, long kh, long kb, long vh, long vb)
{
  __shared__ char pool[65536];  // 2 x (K 16KB + V 16KB)
  int t = threadIdx.x, lane = t & 63, w = t >> 6;   // w = 0..3
  int l31 = lane & 31, hi = lane >> 5;
  int h = blockIdx.y, b = blockIdx.z;
  int kv = blockIdx.x % nkv, qblk = blockIdx.x / nkv;
  const short* Q  = Qp  + (long)h * qh + (long)b * qb;
  const short* Kg = Kp  + (long)h * kh + (long)b * kb;
  const short* Vg = Vtp + (long)h * vh + (long)b * vb;
  int q0w = qblk * 128 + w * 32;
  int nkq = nk / nkv;
  int NIT = nkq >> 5;           // KVBLK = 32
  long k0 = (long)kv * nkq;

  s8v qf[16];
  {
    const short* Qrow = Q + (long)(q0w + l31) * ldq + hi * 8;
#pragma unroll
    for (int s = 0; s < 16; ++s) qf[s] = *(const s8v*)(Qrow + s * 16);
  }

  const char* KgB = (const char*)Kg;
  const char* VgB = (const char*)Vg;
  unsigned koff[4], voff[4];
#pragma unroll
  for (int c = 0; c < 4; ++c) {
    int r = 8 * w + 2 * c + hi;                 // K tile row 0..31
    koff[c] = (unsigned)((k0 + r) * (long)ldk * 2) + ((l31 ^ r) << 4);
    int rv = 64 * w + 16 * c + (lane >> 2);     // V tile row 0..255
    voff[c] = (unsigned)(((long)rv * ldvt + k0) * 2)
              + (((lane & 3) ^ ((lane >> 3) & 3)) << 4);
  }
  const unsigned kStep = (unsigned)(32 * ldk * 2);

  auto stage = [&](int bsel) {
    char* kd = pool + bsel * 32768 + (w << 12);
    char* vd = kd + 16384;
#pragma unroll
    for (int c = 0; c < 4; ++c) { gl16(KgB + koff[c], kd + c * 1024); koff[c] += kStep; }
#pragma unroll
    for (int c = 0; c < 4; ++c) { gl16(VgB + voff[c], vd + c * 1024); voff[c] += 64; }
  };

  f32x16 accO[8];
#pragma unroll
  for (int n = 0; n < 8; ++n)
#pragma unroll
    for (int i = 0; i < 16; ++i) accO[n][i] = 0.f;
  float mrow = -1e30f, lrow = 0.f;

  stage(0);

  for (int it = 0; it < NIT; ++it) {
    int cur = it & 1;
    asm volatile("s_waitcnt vmcnt(0)" ::: "memory");
    __syncthreads();
    if (it + 1 < NIT) stage(cur ^ 1);
    const char* kls = pool + cur * 32768;
    const char* vls = kls + 16384;

    f32x16 sacc;
#pragma unroll
    for (int i = 0; i < 16; ++i) sacc[i] = 0.f;
    __builtin_amdgcn_s_setprio(1);
#pragma unroll
    for (int s = 0; s < 16; ++s) {
      s8v kf = *(const s8v*)&kls[l31 * 512 + (((2 * s + hi) ^ l31) << 4)];
      sacc = __builtin_amdgcn_mfma_f32_32x32x16_bf16(kf, qf[s], sacc, 0, 0, 0);
    }
    __builtin_amdgcn_s_setprio(0);

    float mt = sacc[0];
#pragma unroll
    for (int i = 1; i < 16; ++i) mt = fmaxf(mt, sacc[i]);
    mt = fmaxf(mt, __shfl_xor(mt, 32));
    if (__any(mt - mrow > 8.f)) {       // defer-max (T13)
      float mn = fmaxf(mrow, mt);
      float al = __expf(mrow - mn);
      mrow = mn; lrow *= al;
#pragma unroll
      for (int r = 0; r < 16; ++r) {
        float alr = __shfl(al, (r & 3) + 8 * (r >> 2) + 4 * hi);
#pragma unroll
        for (int n = 0; n < 8; ++n) accO[n][r] *= alr;
      }
    }
    float ls = 0.f;
#pragma unroll
    for (int i = 0; i < 16; ++i) {
      float p = __expf(sacc[i] - mrow);
      sacc[i] = p; ls += p;
    }
    ls += __shfl_xor(ls, 32);
    lrow += ls;

    s8v pa[2];
#pragma unroll
    for (int s2 = 0; s2 < 2; ++s2) {
      int r0 = s2 * 8;
      unsigned w0 = cvtpk(sacc[r0 + 0], sacc[r0 + 1]);
      unsigned w1 = cvtpk(sacc[r0 + 2], sacc[r0 + 3]);
      unsigned w2 = cvtpk(sacc[r0 + 4], sacc[r0 + 5]);
      unsigned w3 = cvtpk(sacc[r0 + 6], sacc[r0 + 7]);
      unsigned x0 = (unsigned)__shfl_xor((int)w0, 32);
      unsigned x1 = (unsigned)__shfl_xor((int)w1, 32);
      unsigned x2 = (unsigned)__shfl_xor((int)w2, 32);
      unsigned x3 = (unsigned)__shfl_xor((int)w3, 32);
      u32x4 pw;
      pw.x = hi ? x2 : w0;
      pw.y = hi ? x3 : w1;
      pw.z = hi ? w2 : x0;
      pw.w = hi ? w3 : x1;
      pa[s2] = *(s8v*)&pw;
    }

    __builtin_amdgcn_s_setprio(1);
#pragma unroll
    for (int n = 0; n < 8; ++n) {
      int rv = n * 32 + l31;
#pragma unroll
      for (int s2 = 0; s2 < 2; ++s2) {
        s8v vf = *(const s8v*)&vls[rv * 64 + (((2 * s2 + hi) ^ ((l31 >> 1) & 3)) << 4)];
        accO[n] = __builtin_amdgcn_mfma_f32_32x32x16_bf16(pa[s2], vf, accO[n], 0, 0, 0);
      }
    }
    __builtin_amdgcn_s_setprio(0);
  }

  long prow = (((long)kv * 4 + b) * 8 + h) * 512;
  short* Ob = Opart + prow * 256;
  float* MLb = MLp + prow * 2;
  if (lane < 32) {
    MLb[(q0w + l31) * 2] = mrow;
    MLb[(q0w + l31) * 2 + 1] = lrow;
  }
  __syncthreads();                          // loop traffic done; reuse pool
  float* st = (float*)(pool + w * 4096);    // wave-private 4KB
  int orow = lane >> 1, ohalf = lane & 1;
#pragma unroll
  for (int n = 0; n < 8; ++n) {
#pragma unroll
    for (int r = 0; r < 16; ++r) {
      int ql = (r & 3) + 8 * (r >> 2) + 4 * hi;
      st[ql * 32 + l31] = accO[n][r];
    }
    short obuf[16];
#pragma unroll
    for (int jj = 0; jj < 4; ++jj) {
      f32x4 v = *(const f32x4*)&st[orow * 32 + ohalf * 16 + jj * 4];
      obuf[jj * 4 + 0] = f2b(v.x); obuf[jj * 4 + 1] = f2b(v.y);
      obuf[jj * 4 + 2] = f2b(v.z); obuf[jj * 4 + 3] = f2b(v.w);
    }
    short* dst = Ob + (long)(q0w + orow) * 256 + n * 32 + ohalf * 16;
    *(s8v*)(dst) = *(s8v*)&obuf[0];
    *(s8v*)(dst + 8) = *(s8v*)&obuf[8];
  }
}

// ------ z = LN(sum(bf16 Ypart) + bias + res), vectorized 8 rows/block ----
__global__ __launch_bounds__(256) void k_bias_res_ln(
    const short* __restrict__ Yp, int nPart, long pStride,
    const float* __restrict__ bias,
    const float* __restrict__ res, int resMod,
    const float* __restrict__ g, const float* __restrict__ bta,
    float* __restrict__ out, short* __restrict__ out_bf)
{
  int t = threadIdx.x;
  int rloc = t >> 5, l32 = t & 31;
  long row = (long)blockIdx.x * 8 + rloc;
  int e0 = l32 * 8;
  float v[8];
  const float* rp = res + (row % resMod) * 256 + e0;
  const float* bp = bias + e0;
#pragma unroll
  for (int j = 0; j < 8; ++j) v[j] = bp[j] + rp[j];
  for (int s = 0; s < nPart; ++s) {
    s8v yv = *(const s8v*)&Yp[s * pStride + row * 256 + e0];
#pragma unroll
    for (int j = 0; j < 8; ++j) v[j] += b2f(yv[j]);
  }
  float s1 = 0.f;
#pragma unroll
  for (int j = 0; j < 8; ++j) s1 += v[j];
#pragma unroll
  for (int o = 1; o < 32; o <<= 1) s1 += __shfl_xor(s1, o);
  float mean = s1 * (1.f / 256.f);
  float s2 = 0.f;
#pragma unroll
  for (int j = 0; j < 8; ++j) { v[j] -= mean; s2 += v[j] * v[j]; }
#pragma unroll
  for (int o = 1; o < 32; o <<= 1) s2 += __shfl_xor(s2, o);
  float rs = rsqrtf(s2 * (1.f / 256.f) + 1e-5f);
  float of[8]; short ob[8];
#pragma unroll
  for (int j = 0; j < 8; ++j) {
    float o = g[e0 + j] * v[j] * rs + bta[e0 + j];
    of[j] = o; ob[j] = f2b(o);
  }
  float* op = out + row * 256 + e0;
  *(f32x4*)(op) = *(f32x4*)&of[0];
  *(f32x4*)(op + 4) = *(f32x4*)&of[4];
  *(s8v*)&out_bf[row * 256 + e0] = *(s8v*)ob;
}

// ---------------- fused mean-over-latents + classifier ----------------
__global__ __launch_bounds__(256) void k_meancls(
    const float* __restrict__ z, const float* __restrict__ w,
    const float* __restrict__ bias, float* __restrict__ out)
{
  __shared__ float zms[256];
  int b = blockIdx.y, e = threadIdx.x;
  float s = 0.f;
  for (int l = 0; l < 512; ++l) s += z[((long)b * 512 + l) * 256 + e];
  zms[e] = s * (1.f / 512.f);
  __syncthreads();
  int j = blockIdx.x * 256 + e;
  if (j >= 1000) return;
  float acc = bias[j];
  for (int e2 = 0; e2 < 256; ++e2) acc += zms[e2] * w[e2 * 1000 + j];
  out[b * 1000 + j] = acc;
}

extern "C" void kernel_launch(void* const* d_in, const int* in_sizes, int n_in,
                              void* d_out, int out_size, void* d_ws, size_t ws_size,
                              hipStream_t stream)
{
  (void)in_sizes; (void)n_in; (void)out_size; (void)ws_size;
  const float* x       = (const float*)d_in[0];
  const float* conv_w  = (const float*)d_in[1];
  const float* conv_b  = (const float*)d_in[2];
  const float* pos_emb = (const float*)d_in[3];
  const float* latents = (const float*)d_in[4];
  const float* ca_wq   = (const float*)d_in[5];
  const float* ca_wk   = (const float*)d_in[6];
  const float* ca_wv   = (const float*)d_in[7];
  const float* ca_wu   = (const float*)d_in[8];
  const float* ca_bu   = (const float*)d_in[9];
  const float* ca_ln_g = (const float*)d_in[10];
  const float* ca_ln_b = (const float*)d_in[11];
  const float* blk_wq  = (const float*)d_in[12];
  const float* blk_wk  = (const float*)d_in[13];
  const float* blk_wv  = (const float*)d_in[14];
  const float* blk_wu  = (const float*)d_in[15];
  const float* blk_bu  = (const float*)d_in[16];
  const float* blk_ln1_g = (const float*)d_in[17];
  const float* blk_ln1_b = (const float*)d_in[18];
  const float* blk_w1  = (const float*)d_in[19];
  const float* blk_b1  = (const float*)d_in[20];
  const float* blk_w2  = (const float*)d_in[21];
  const float* blk_b2  = (const float*)d_in[22];
  const float* blk_ln2_g = (const float*)d_in[23];
  const float* blk_ln2_b = (const float*)d_in[24];
  const float* cls_w   = (const float*)d_in[25];
  const float* cls_b   = (const float*)d_in[26];
  float* out = (float*)d_out;

  // ---- workspace layout (bf16 as short) ----
  short* wqT_ca = (short*)d_ws;            // 2048x256 (scaled)
  short* wkT_ca = wqT_ca + 524288;         // 2048x256
  short* wuT_ca = wkT_ca + 524288;         // 256x2048
  short* wv_ca  = wuT_ca + 524288;         // 256x2048
  short* lat_bf = wv_ca + 524288;          // 512x256
  short* wqkT   = lat_bf + 131072;         // 4 x (4096x256)
  short* wvT    = wqkT + 4194304;          // 4 x (2048x256)
  short* wuT_b  = wvT + 2097152;           // 4 x (256x2048)
  short* w1T    = wuT_b + 2097152;         // 4 x (1024x256)
  short* w2T    = w1T + 1048576;           // 4 x (256x1024)
  short* tok_bf = w2T + 1048576;           // 4 x 4096x256
  short* tokT   = tok_bf + 4194304;        // 4 x 256x4096
  short* qCA    = tokT + 4194304;          // 512x2048
  short* qtil   = qCA + 1048576;           // 8 x 512x256
  short* MstT   = qtil + 1048576;          // 256x2048
  short* VtB    = MstT + 524288;           // 32 x 256x512
  short* bufO   = VtB + 4194304;           // (unused)
  short* h1     = bufO + 4194304;          // 2048x1024
  short* z_bf   = h1 + 2097152;            // 2048x256
  float* z      = (float*)(z_bf + 524288); // 2048x256 fp32
  float* zm     = z + 524288;              // spare
  short* Ypart  = (short*)(zm + 1024);     // 8 x 2048x256 bf16 (split-K partials)
  short* Opart  = Ypart + 4194304;         // 4 x (4x8x512x256) bf16 kv-partials
  float* MLp    = (float*)(Opart + 16777216); // 4 x (4x8x512x2) fp32
  short* QKb    = tok_bf;                  // alias: 2048x4096 (after CA)

  const float scale = 0.17677669529663687f; // 1/sqrt(32), folded into Wq
  const int BIG = 1 << 30;

  // ---- prep: weights + tokens in ONE dispatch ----
  TrJobs JB; int nj = 0, base = 0;
  auto addT = [&](const float* s, short* d, int R, int C, long sIn, long sOut,
                  int zc, float sc) {
    int tpz = (C >> 5) * (R >> 5);
    JB.j[nj] = {s, d, R, C, sIn, sOut, 0, tpz, zc, base, sc};
    base += tpz * zc; ++nj;
  };
  auto addC = [&](const float* s, short* d, int nelem) {
    int tpz = nelem >> 13;
    JB.j[nj] = {s, d, 0, 0, 0, 0, 1, tpz, 1, base, 1.f};
    base += tpz; ++nj;
  };
  addT(ca_wq, wqT_ca, 256, 2048, 0, 0, 1, scale);
  addT(ca_wk, wkT_ca, 256, 2048, 0, 0, 1, 1.f);
  addT(ca_wu, wuT_ca, 2048, 256, 0, 0, 1, 1.f);
  addT(blk_wq, wqkT, 256, 2048, 524288, 1048576, 4, scale);
  addT(blk_wk, wqkT + 524288, 256, 2048, 524288, 1048576, 4, 1.f);
  addT(blk_wv, wvT, 256, 2048, 524288, 524288, 4, 1.f);
  addT(blk_wu, wuT_b, 2048, 256, 524288, 524288, 4, 1.f);
  addT(blk_w1, w1T, 256, 1024, 262144, 262144, 4, 1.f);
  addT(blk_w2, w2T, 1024, 256, 262144, 262144, 4, 1.f);
  addC(ca_wv, wv_ca, 524288);
  addC(latents, lat_bf, 131072);
  k_prep<<<base + 512, 256, 0, stream>>>(JB, nj, base, x, conv_w, conv_b,
                                         pos_emb, tok_bf, tokT);

  // ---- CA prep: qCA = latents @ Wq ; MstT_h = Wu_h^T @ Wv_h^T (merged) ----
  k_capre<<<96, 256, 0, stream>>>(lat_bf, wqT_ca, wuT_ca, wv_ca, qCA, MstT);
  // qtilde_h = qCA_h @ Wk_h^T
  k_mgemm<0><<<dim3(2, 4, 8), 256, 0, stream>>>(
      qCA, wkT_ca, qtil, nullptr, 256, 2048, 256, 256, 256, 65536, 131072, 1, 8, 1, 8);
  // CA flash: kv-split x4
  k_mflash10<<<dim3(16, 8, 4), 256, 0, stream>>>(
      qtil, tok_bf, tokT, Opart, MLp, 4096, 4, 256, 256, 4096,
      131072L, 0L, 0L, 1048576L, 0L, 1048576L);
  // Y = combine4(Opart) @ MstT^T, split-K x8 (chunk = head) -> bf16 partials
  k_mgemm_att<4><<<dim3(2, 16, 8), 256, 0, stream>>>(Opart, MLp, MstT, Ypart, 2048);
  k_bias_res_ln<<<256, 256, 0, stream>>>(Ypart, 8, 524288L, ca_bu, latents, 512,
                                         ca_ln_g, ca_ln_b, z, z_bf);

  // ---- transformer blocks ----
  for (int d = 0; d < 4; ++d) {
    // merged: [Q|K] = z @ wqk  AND  Vt(b,h) = wvT_h @ z_b^T
    k_qkvt<<<768, 256, 0, stream>>>(z_bf, wqkT + (long)d * 1048576,
                                    wvT + (long)d * 524288, QKb, VtB);
    // self flash: kv-split x2 (NIT=8, 256 blocks = 2/CU)
    k_mflash10<<<dim3(8, 8, 4), 256, 0, stream>>>(
        QKb, QKb + 2048, VtB, Opart, MLp, 512, 2, 4096, 4096, 512,
        256L, 2097152L, 256L, 2097152L, 131072L, 1048576L);
    // Y = combine2(Opart) @ wu^T, split-K x8 (chunk = head) -> bf16 partials
    k_mgemm_att<2><<<dim3(2, 16, 8), 256, 0, stream>>>(
        Opart, MLp, wuT_b + (long)d * 524288, Ypart, 2048);
    k_bias_res_ln<<<256, 256, 0, stream>>>(Ypart, 8, 524288L, blk_bu + d * 256, z, 2048,
        blk_ln1_g + d * 256, blk_ln1_b + d * 256, z, z_bf);
    // h1 = gelu(z @ w1 + b1)
    k_mgemm<1><<<dim3(8, 16, 1), 256, 0, stream>>>(
        z_bf, w1T + (long)d * 262144, h1, blk_b1 + d * 1024,
        256, 256, 256, 1024, 0, 0, 0, 1, BIG, 1, BIG);
    // Y = h1 @ w2, split-K x8 (Ksub=128) -> bf16 partials
    k_mgemm<0><<<dim3(2, 16, 8), 256, 0, stream>>>(
        h1, w2T + (long)d * 262144, Ypart, nullptr,
        128, 1024, 1024, 256, 128, 128, 524288, 1, 8, 1, 8);
    k_bias_res_ln<<<256, 256, 0, stream>>>(Ypart, 8, 524288L, blk_b2 + d * 256, z, 2048,
        blk_ln2_g + d * 256, blk_ln2_b + d * 256, z, z_bf);
  }

  k_meancls<<<dim3(4, 4), 256, 0, stream>>>(z, cls_w, cls_b, out);
}